// Round 1
// baseline (8058.550 us; speedup 1.0000x reference)
//
#include <hip/hip_runtime.h>
#include <math.h>

#define NLEN 12096
#define BB 2

// =====================================================================
// Generic fp32 SGEMM: C[M,N] = A[M,K] @ Bw[K,N] (+bias) (+pos-add on A)
// A,Bw,C row-major. biasMode: 0 none, 1 per-col, 2 per-row. relu flag.
// posAdd: if non-null, A_eff[m][k] = A[m][k] + posAdd[(m%NLEN)*K + k]
// blockIdx.z batches via strides.
// =====================================================================
__global__ __launch_bounds__(256) void sgemm_kernel(
    const float* __restrict__ A, const float* __restrict__ Bw,
    const float* __restrict__ bias, float* __restrict__ C,
    int M, int N, int K,
    long long sAb, long long sBb, long long sCb,
    const float* __restrict__ posAdd,
    int biasMode, int relu)
{
  const int bz = blockIdx.z;
  A += bz * sAb; Bw += bz * sBb; C += bz * sCb;
  const int m0 = blockIdx.y * 64, n0 = blockIdx.x * 64;
  __shared__ float As[16][64];
  __shared__ float Bs[16][64];
  const int t = threadIdx.x;
  const int tr = (t >> 4) * 4;   // 0..60
  const int tc = (t & 15) * 4;   // 0..60
  const int lam = t >> 2, lak = (t & 3) * 4;
  const int lbk = t >> 4, lbn = (t & 15) * 4;
  float acc[4][4] = {};
  for (int k0 = 0; k0 < K; k0 += 16) {
    float4 av = make_float4(0.f, 0.f, 0.f, 0.f);
    {
      int m = m0 + lam;
      if (m < M) {
        av = *(const float4*)(A + (long long)m * K + k0 + lak);
        if (posAdd) {
          float4 pv = *(const float4*)(posAdd + (long long)(m % NLEN) * K + k0 + lak);
          av.x += pv.x; av.y += pv.y; av.z += pv.z; av.w += pv.w;
        }
      }
      As[lak + 0][lam] = av.x; As[lak + 1][lam] = av.y;
      As[lak + 2][lam] = av.z; As[lak + 3][lam] = av.w;
    }
    {
      int n = n0 + lbn;
      float4 bv = make_float4(0.f, 0.f, 0.f, 0.f);
      if (n < N) bv = *(const float4*)(Bw + (long long)(k0 + lbk) * N + n);
      Bs[lbk][lbn + 0] = bv.x; Bs[lbk][lbn + 1] = bv.y;
      Bs[lbk][lbn + 2] = bv.z; Bs[lbk][lbn + 3] = bv.w;
    }
    __syncthreads();
#pragma unroll
    for (int kk = 0; kk < 16; ++kk) {
      float4 a4 = *(const float4*)&As[kk][tr];
      float4 b4 = *(const float4*)&Bs[kk][tc];
      float a[4] = {a4.x, a4.y, a4.z, a4.w};
      float b[4] = {b4.x, b4.y, b4.z, b4.w};
#pragma unroll
      for (int r = 0; r < 4; ++r)
#pragma unroll
        for (int c = 0; c < 4; ++c)
          acc[r][c] = fmaf(a[r], b[c], acc[r][c]);
    }
    __syncthreads();
  }
#pragma unroll
  for (int r = 0; r < 4; ++r) {
    int m = m0 + tr + r;
    if (m >= M) continue;
#pragma unroll
    for (int c = 0; c < 4; ++c) {
      int n = n0 + tc + c;
      if (n >= N) continue;
      float v = acc[r][c];
      if (biasMode == 1) v += bias[n];
      else if (biasMode == 2) v += bias[m];
      if (relu) v = fmaxf(v, 0.f);
      C[(long long)m * N + n] = v;
    }
  }
}

// =====================================================================
// Sine positional embedding + level embed: pos[i][c], i in [0,LEN)
// =====================================================================
__global__ void pos_kernel(float* __restrict__ pos, const float* __restrict__ level_embed)
{
  int i = blockIdx.x, c = threadIdx.x;
  int lvl, Wq, loc;
  if (i < 576)       { lvl = 0; Wq = 24; loc = i; }
  else if (i < 2880) { lvl = 1; Wq = 48; loc = i - 576; }
  else               { lvl = 2; Wq = 96; loc = i - 2880; }
  int h = loc / Wq, w = loc % Wq;
  int cc = c & 127;
  float coord = (c < 128) ? (float)(h + 1) : (float)(w + 1);
  float denom = (float)Wq + 1e-6f;            // H == W for all levels
  float v = coord / denom * 6.28318530717958647692f;
  float tp = powf(10000.0f, (float)(cc & ~1) * (1.0f / 128.0f));
  float ang = v / tp;
  float val = (cc & 1) ? cosf(ang) : sinf(ang);
  pos[(long long)i * 256 + c] = val + level_embed[lvl * 256 + c];
}

// =====================================================================
// GroupNorm stats over contiguous [nPerGroup] chunk per (b,g)
// stats[(b*groups+g)*2] = mean, +1 = rsqrt(var+eps)
// =====================================================================
__global__ __launch_bounds__(256) void gn_stats_kernel(const float* __restrict__ X,
    float* __restrict__ stats, int nPerGroup, long long sBatch, int groups)
{
  int b = blockIdx.x / groups, g = blockIdx.x % groups;
  const float* p = X + b * sBatch + (long long)g * nPerGroup;
  float s = 0.f, s2 = 0.f;
  for (int idx = threadIdx.x; idx < nPerGroup; idx += 256) {
    float v = p[idx];
    s += v; s2 = fmaf(v, v, s2);
  }
#pragma unroll
  for (int o = 32; o > 0; o >>= 1) { s += __shfl_down(s, o); s2 += __shfl_down(s2, o); }
  __shared__ float sh[2][4];
  int lane = threadIdx.x & 63, wv = threadIdx.x >> 6;
  if (lane == 0) { sh[0][wv] = s; sh[1][wv] = s2; }
  __syncthreads();
  if (threadIdx.x == 0) {
    float S = sh[0][0] + sh[0][1] + sh[0][2] + sh[0][3];
    float S2 = sh[1][0] + sh[1][1] + sh[1][2] + sh[1][3];
    float inv = 1.f / (float)nPerGroup;
    float mean = S * inv;
    float var = S2 * inv - mean * mean;
    stats[blockIdx.x * 2] = mean;
    stats[blockIdx.x * 2 + 1] = rsqrtf(var + 1e-5f);
  }
}

// =====================================================================
// Apply GN to conv1x1 output T[b][256][HW] and write transposed into
// src[b][startRow+hw][c]. 32x32 LDS tile. grid (HW/32, 8, B) block (32,8)
// =====================================================================
__global__ void gn_apply_src_kernel(const float* __restrict__ T, const float* __restrict__ stats,
    const float* __restrict__ gs, const float* __restrict__ gb,
    float* __restrict__ src, int HW, int startRow)
{
  __shared__ float tile[32][33];
  int b = blockIdx.z;
  int c0 = blockIdx.y * 32, w0 = blockIdx.x * 32;
  const float* Tb = T + (long long)b * 256 * HW;
#pragma unroll
  for (int j = 0; j < 4; ++j) {
    int cl = threadIdx.y + 8 * j;
    int c = c0 + cl;
    int g = c >> 3;
    float mean = stats[(b * 32 + g) * 2], rstd = stats[(b * 32 + g) * 2 + 1];
    float v = Tb[(long long)c * HW + w0 + threadIdx.x];
    tile[cl][threadIdx.x] = (v - mean) * rstd * gs[c] + gb[c];
  }
  __syncthreads();
#pragma unroll
  for (int j = 0; j < 4; ++j) {
    int wl = threadIdx.y + 8 * j;
    src[((long long)b * NLEN + startRow + w0 + wl) * 256 + c0 + threadIdx.x] = tile[threadIdx.x][wl];
  }
}

// =====================================================================
// src = LayerNorm(src + resid) per row of 256. grid = B*LEN, block 256
// =====================================================================
__global__ __launch_bounds__(256) void ln_kernel(float* __restrict__ src,
    const float* __restrict__ resid, const float* __restrict__ s, const float* __restrict__ bsh)
{
  long long r = blockIdx.x;
  int c = threadIdx.x;
  float v = src[r * 256 + c] + resid[r * 256 + c];
  float sum = v, sq = v * v;
#pragma unroll
  for (int o = 32; o > 0; o >>= 1) { sum += __shfl_down(sum, o); sq += __shfl_down(sq, o); }
  __shared__ float sh[2][4];
  int lane = c & 63, wv = c >> 6;
  if (lane == 0) { sh[0][wv] = sum; sh[1][wv] = sq; }
  __syncthreads();
  float S  = sh[0][0] + sh[0][1] + sh[0][2] + sh[0][3];
  float S2 = sh[1][0] + sh[1][1] + sh[1][2] + sh[1][3];
  float mean = S * (1.f / 256.f);
  float var = S2 * (1.f / 256.f) - mean * mean;
  float rstd = rsqrtf(var + 1e-5f);
  src[r * 256 + c] = (v - mean) * rstd * s[c] + bsh[c];
}

// =====================================================================
// Softmax over 12 (NL*NP) per (b,i,head). aw rows of 96 in place.
// =====================================================================
__global__ void softmax12_kernel(float* __restrict__ aw)
{
  int idx = blockIdx.x * blockDim.x + threadIdx.x;
  if (idx >= BB * NLEN * 8) return;
  int row = idx >> 3, hd = idx & 7;
  float* p = aw + (long long)row * 96 + hd * 12;
  float v[12]; float m = -1e30f;
#pragma unroll
  for (int j = 0; j < 12; ++j) { v[j] = p[j]; m = fmaxf(m, v[j]); }
  float ssum = 0.f;
#pragma unroll
  for (int j = 0; j < 12; ++j) { v[j] = expf(v[j] - m); ssum += v[j]; }
  float inv = 1.f / ssum;
#pragma unroll
  for (int j = 0; j < 12; ++j) p[j] = v[j] * inv;
}

// =====================================================================
// MSDeformAttn bilinear sampling. Block per (b,i); thread per channel.
// =====================================================================
__global__ __launch_bounds__(256) void deform_kernel(const float* __restrict__ value,
    const float* __restrict__ offb, const float* __restrict__ awb, float* __restrict__ out)
{
  int bi = blockIdx.x;            // b*LEN + i
  int i = bi % NLEN;
  int bbase = bi - i;             // b*LEN
  int c = threadIdx.x;
  int head = c >> 5;
  int loc, Wq;
  if (i < 576)       { Wq = 24; loc = i; }
  else if (i < 2880) { Wq = 48; loc = i - 576; }
  else               { Wq = 96; loc = i - 2880; }
  float rx = ((loc % Wq) + 0.5f) / (float)Wq;
  float ry = ((loc / Wq) + 0.5f) / (float)Wq;
  const float* offp = offb + (long long)bi * 192 + head * 24;
  const float* awp  = awb  + (long long)bi * 96  + head * 12;
  float acc = 0.f;
  const int starts[3] = {0, 576, 2880};
  const int Ls[3] = {24, 48, 96};
#pragma unroll
  for (int l = 0; l < 3; ++l) {
    const int Wl = Ls[l];
    const float fW = (float)Wl;
    const long long vbase = (long long)(bbase + starts[l]) * 256 + c;
#pragma unroll
    for (int p = 0; p < 4; ++p) {
      float ox = offp[l * 8 + p * 2], oy = offp[l * 8 + p * 2 + 1];
      float a = awp[l * 4 + p];
      float lx = rx + ox / fW;
      float ly = ry + oy / fW;
      float x = lx * fW - 0.5f;
      float y = ly * fW - 0.5f;
      float x0f = floorf(x), y0f = floorf(y);
      float wx = x - x0f, wy = y - y0f;
      int x0 = (int)x0f, y0 = (int)y0f;
      float g00 = 0.f, g01 = 0.f, g10 = 0.f, g11 = 0.f;
      bool xv0 = (x0 >= 0) && (x0 < Wl);
      bool xv1 = (x0 + 1 >= 0) && (x0 + 1 < Wl);
      bool yv0 = (y0 >= 0) && (y0 < Wl);
      bool yv1 = (y0 + 1 >= 0) && (y0 + 1 < Wl);
      if (yv0 && xv0) g00 = value[vbase + (long long)(y0 * Wl + x0) * 256];
      if (yv0 && xv1) g01 = value[vbase + (long long)(y0 * Wl + x0 + 1) * 256];
      if (yv1 && xv0) g10 = value[vbase + (long long)((y0 + 1) * Wl + x0) * 256];
      if (yv1 && xv1) g11 = value[vbase + (long long)((y0 + 1) * Wl + x0 + 1) * 256];
      float sv = g00 * (1.f - wx) * (1.f - wy) + g01 * wx * (1.f - wy)
               + g10 * (1.f - wx) * wy + g11 * wx * wy;
      acc = fmaf(a, sv, acc);
    }
  }
  out[(long long)bi * 256 + c] = acc;
}

// =====================================================================
// src[b][startRow+hw][c] -> out[b][c][hw]. grid (HW/32, 8, B) block (32,8)
// =====================================================================
__global__ void transpose_out_kernel(const float* __restrict__ src, float* __restrict__ out,
    int HW, int startRow)
{
  __shared__ float tile[32][33];
  int b = blockIdx.z;
  int w0 = blockIdx.x * 32, c0 = blockIdx.y * 32;
#pragma unroll
  for (int j = 0; j < 4; ++j) {
    int wl = threadIdx.y + 8 * j;
    tile[wl][threadIdx.x] = src[((long long)b * NLEN + startRow + w0 + wl) * 256 + c0 + threadIdx.x];
  }
  __syncthreads();
#pragma unroll
  for (int j = 0; j < 4; ++j) {
    int cl = threadIdx.y + 8 * j;
    out[((long long)b * 256 + c0 + cl) * HW + w0 + threadIdx.x] = tile[threadIdx.x][cl];
  }
}

// =====================================================================
// lat = GN(lat)*gs+gb + upsample2x_bilinear(out2). In place on lat.
// lat [B,256,192,192], out2 [B,256,96,96]
// =====================================================================
__global__ void lat_finish_kernel(float* __restrict__ lat, const float* __restrict__ stats,
    const float* __restrict__ gs, const float* __restrict__ gb, const float* __restrict__ out2)
{
  long long idx = (long long)blockIdx.x * 256 + threadIdx.x;
  int ox = (int)(idx % 192); long long t1 = idx / 192;
  int oy = (int)(t1 % 192); long long t2 = t1 / 192;
  int c = (int)(t2 % 256); int b = (int)(t2 / 256);
  int g = c >> 3;
  float v = lat[idx];
  v = (v - stats[(b * 32 + g) * 2]) * stats[(b * 32 + g) * 2 + 1] * gs[c] + gb[c];
  float ys = fmaxf(oy * 0.5f - 0.25f, 0.f);
  float xs = fmaxf(ox * 0.5f - 0.25f, 0.f);
  int y0 = (int)ys; float wy = ys - (float)y0; int y1 = min(y0 + 1, 95);
  int x0 = (int)xs; float wx = xs - (float)x0; int x1 = min(x0 + 1, 95);
  const float* p = out2 + ((long long)b * 256 + c) * 9216;
  float r0 = p[y0 * 96 + x0] * (1.f - wx) + p[y0 * 96 + x1] * wx;
  float r1 = p[y1 * 96 + x0] * (1.f - wx) + p[y1 * 96 + x1] * wx;
  lat[idx] = v + r0 * (1.f - wy) + r1 * wy;
}

// =====================================================================
// 3x3 SAME conv, 256->256, input [B,256,192,192].
// Block: 64 couts x 8x8 pixels. Thread: 1 cout x 4x4 pixels.
// grid (576 pixel tiles, 4 cout tiles, B), block 256.
// =====================================================================
__global__ __launch_bounds__(256) void conv3x3_kernel(const float* __restrict__ X,
    const float* __restrict__ Wt, float* __restrict__ Y)
{
  __shared__ float Xl[8][10][10];
  __shared__ float Wl[8][9][64];
  int b = blockIdx.z;
  int co0 = blockIdx.y * 64;
  int tileId = blockIdx.x;
  int ty0 = (tileId / 24) * 8, tx0 = (tileId % 24) * 8;
  int t = threadIdx.x;
  int co = t & 63, quad = t >> 6;
  int qy = (quad >> 1) * 4, qx = (quad & 1) * 4;
  float acc[4][4] = {};
  for (int ci0 = 0; ci0 < 256; ci0 += 8) {
    for (int idx = t; idx < 800; idx += 256) {
      int ci = idx / 100, rem = idx % 100, iy = rem / 10, ix = rem % 10;
      int gy = ty0 - 1 + iy, gx = tx0 - 1 + ix;
      float v = 0.f;
      if (gy >= 0 && gy < 192 && gx >= 0 && gx < 192)
        v = X[(((long long)b * 256 + ci0 + ci) * 192 + gy) * 192 + gx];
      Xl[ci][iy][ix] = v;
    }
    for (int idx = t; idx < 4608; idx += 256) {
      int ci = idx / 576, rem = idx % 576, k = rem / 64, cc = rem % 64;
      Wl[ci][k][cc] = Wt[((long long)(co0 + cc) * 256 + ci0 + ci) * 9 + k];
    }
    __syncthreads();
#pragma unroll
    for (int ci = 0; ci < 8; ++ci) {
      float xr[6][6];
#pragma unroll
      for (int a = 0; a < 6; ++a)
#pragma unroll
        for (int e = 0; e < 6; ++e)
          xr[a][e] = Xl[ci][qy + a][qx + e];
#pragma unroll
      for (int kh = 0; kh < 3; ++kh)
#pragma unroll
        for (int kw = 0; kw < 3; ++kw) {
          float wv = Wl[ci][kh * 3 + kw][co];
#pragma unroll
          for (int iy = 0; iy < 4; ++iy)
#pragma unroll
            for (int ix = 0; ix < 4; ++ix)
              acc[iy][ix] = fmaf(wv, xr[iy + kh][ix + kw], acc[iy][ix]);
        }
    }
    __syncthreads();
  }
#pragma unroll
  for (int iy = 0; iy < 4; ++iy)
#pragma unroll
    for (int ix = 0; ix < 4; ++ix)
      Y[(((long long)b * 256 + co0 + co) * 192 + ty0 + qy + iy) * 192 + tx0 + qx + ix] = acc[iy][ix];
}

// =====================================================================
// Final GN + ReLU in place on Y [B,256,192,192]
// =====================================================================
__global__ void gn_relu_kernel(float* __restrict__ Y, const float* __restrict__ stats,
    const float* __restrict__ gs, const float* __restrict__ gb)
{
  long long idx = (long long)blockIdx.x * 256 + threadIdx.x;
  int c = (int)((idx / 36864) % 256);
  int b = (int)(idx / (36864LL * 256));
  int g = c >> 3;
  float v = (Y[idx] - stats[(b * 32 + g) * 2]) * stats[(b * 32 + g) * 2 + 1] * gs[c] + gb[c];
  Y[idx] = fmaxf(v, 0.f);
}

// =====================================================================
extern "C" void kernel_launch(void* const* d_in, const int* in_sizes, int n_in,
                              void* d_out, int out_size, void* d_ws, size_t ws_size,
                              hipStream_t stream)
{
  const float* res2 = (const float*)d_in[0];
  const float* res3 = (const float*)d_in[1];
  const float* res4 = (const float*)d_in[2];
  const float* res5 = (const float*)d_in[3];
  const float* pw[3]  = {(const float*)d_in[4],  (const float*)d_in[8],  (const float*)d_in[12]};
  const float* pb[3]  = {(const float*)d_in[5],  (const float*)d_in[9],  (const float*)d_in[13]};
  const float* gss[3] = {(const float*)d_in[6],  (const float*)d_in[10], (const float*)d_in[14]};
  const float* gbb[3] = {(const float*)d_in[7],  (const float*)d_in[11], (const float*)d_in[15]};
  const float* level_embed = (const float*)d_in[16];
  const float* off_w = (const float*)d_in[17];
  const float* off_b = (const float*)d_in[18];
  const float* aw_w  = (const float*)d_in[19];
  const float* aw_b  = (const float*)d_in[20];
  const float* val_w = (const float*)d_in[21];
  const float* val_b = (const float*)d_in[22];
  const float* out_w = (const float*)d_in[23];
  const float* out_b = (const float*)d_in[24];
  const float* ln1_s = (const float*)d_in[25];
  const float* ln1_b = (const float*)d_in[26];
  const float* ffn1_w = (const float*)d_in[27];
  const float* ffn1_b = (const float*)d_in[28];
  const float* ffn2_w = (const float*)d_in[29];
  const float* ffn2_b = (const float*)d_in[30];
  const float* ln2_s = (const float*)d_in[31];
  const float* ln2_b = (const float*)d_in[32];
  const float* lat_w = (const float*)d_in[33];
  const float* lat_gs = (const float*)d_in[34];
  const float* lat_gb = (const float*)d_in[35];
  const float* fpn_w = (const float*)d_in[36];
  const float* fpn_gs = (const float*)d_in[37];
  const float* fpn_gb = (const float*)d_in[38];

  float* W = (float*)d_ws;
  float* src   = W;                     // 6,193,152
  float* pos   = W + 6193152LL;         // 3,096,576
  float* tmp   = W + 9289728LL;         // 6,193,152
  float* U     = W + 15482880LL;        // 24,772,608 (union region)
  float* stats = W + 40255488LL;        // 128
  float* value   = U;
  float* offbuf  = U + 6193152LL;
  float* awbuf   = U + 10838016LL;
  float* sampled = U + 13160448LL;
  float* hbuf    = U;                   // FFN hidden (aliases attn bufs, dead by then)
  float* projtmp = U;                   // projection scratch (pre-layers)
  float* lat     = U;                   // FPN lateral (post-layers)

  float* Yout = (float*)d_out;                 // [B,256,192,192]
  float* out0 = Yout + 18874368LL;             // [B,256,24,24]
  float* out1 = Yout + 19169280LL;             // [B,256,48,48]
  float* out2 = Yout + 20348928LL;             // [B,256,96,96]

  const int M = BB * NLEN;  // 24192

  // ---- positional embedding (incl. level embed) ----
  pos_kernel<<<dim3(NLEN), dim3(256), 0, stream>>>(pos, level_embed);

  // ---- input projections + GN -> src ----
  const float* feats[3] = {res5, res4, res3};
  const int cins[3] = {2048, 1024, 512};
  const int HWs[3] = {576, 2304, 9216};
  const int startsHost[3] = {0, 576, 2880};
  for (int lvl = 0; lvl < 3; ++lvl) {
    int HW = HWs[lvl], cin = cins[lvl];
    sgemm_kernel<<<dim3((HW + 63) / 64, 4, BB), dim3(256), 0, stream>>>(
        pw[lvl], feats[lvl], pb[lvl], projtmp,
        256, HW, cin, 0LL, (long long)cin * HW, (long long)256 * HW,
        nullptr, 2, 0);
    gn_stats_kernel<<<dim3(64), dim3(256), 0, stream>>>(
        projtmp, stats, 8 * HW, (long long)256 * HW, 32);
    gn_apply_src_kernel<<<dim3(HW / 32, 8, BB), dim3(32, 8), 0, stream>>>(
        projtmp, stats, gss[lvl], gbb[lvl], src, HW, startsHost[lvl]);
  }

  // ---- 6 encoder layers ----
  for (int l = 0; l < 6; ++l) {
    sgemm_kernel<<<dim3(4, M / 64, 1), dim3(256), 0, stream>>>(
        src, val_w + (long long)l * 256 * 256, val_b + l * 256, value,
        M, 256, 256, 0LL, 0LL, 0LL, nullptr, 1, 0);
    sgemm_kernel<<<dim3(3, M / 64, 1), dim3(256), 0, stream>>>(
        src, off_w + (long long)l * 256 * 192, off_b + l * 192, offbuf,
        M, 192, 256, 0LL, 0LL, 0LL, pos, 1, 0);
    sgemm_kernel<<<dim3(2, M / 64, 1), dim3(256), 0, stream>>>(
        src, aw_w + (long long)l * 256 * 96, aw_b + l * 96, awbuf,
        M, 96, 256, 0LL, 0LL, 0LL, pos, 1, 0);
    softmax12_kernel<<<dim3((M * 8 + 255) / 256), dim3(256), 0, stream>>>(awbuf);
    deform_kernel<<<dim3(M), dim3(256), 0, stream>>>(value, offbuf, awbuf, sampled);
    sgemm_kernel<<<dim3(4, M / 64, 1), dim3(256), 0, stream>>>(
        sampled, out_w + (long long)l * 256 * 256, out_b + l * 256, tmp,
        M, 256, 256, 0LL, 0LL, 0LL, nullptr, 1, 0);
    ln_kernel<<<dim3(M), dim3(256), 0, stream>>>(src, tmp, ln1_s + l * 256, ln1_b + l * 256);
    sgemm_kernel<<<dim3(16, M / 64, 1), dim3(256), 0, stream>>>(
        src, ffn1_w + (long long)l * 256 * 1024, ffn1_b + l * 1024, hbuf,
        M, 1024, 256, 0LL, 0LL, 0LL, nullptr, 1, 1);
    sgemm_kernel<<<dim3(4, M / 64, 1), dim3(256), 0, stream>>>(
        hbuf, ffn2_w + (long long)l * 1024 * 256, ffn2_b + l * 256, tmp,
        M, 256, 1024, 0LL, 0LL, 0LL, nullptr, 1, 0);
    ln_kernel<<<dim3(M), dim3(256), 0, stream>>>(src, tmp, ln2_s + l * 256, ln2_b + l * 256);
  }

  // ---- output transposes ----
  float* outsPtr[3] = {out0, out1, out2};
  for (int lvl = 0; lvl < 3; ++lvl) {
    transpose_out_kernel<<<dim3(HWs[lvl] / 32, 8, BB), dim3(32, 8), 0, stream>>>(
        src, outsPtr[lvl], HWs[lvl], startsHost[lvl]);
  }

  // ---- FPN ----
  sgemm_kernel<<<dim3(576, 4, BB), dim3(256), 0, stream>>>(
      lat_w, res2, nullptr, lat,
      256, 36864, 256, 0LL, (long long)256 * 36864, (long long)256 * 36864,
      nullptr, 0, 0);
  gn_stats_kernel<<<dim3(64), dim3(256), 0, stream>>>(
      lat, stats, 8 * 36864, (long long)256 * 36864, 32);
  lat_finish_kernel<<<dim3(73728), dim3(256), 0, stream>>>(lat, stats, lat_gs, lat_gb, out2);
  conv3x3_kernel<<<dim3(576, 4, BB), dim3(256), 0, stream>>>(lat, fpn_w, Yout);
  gn_stats_kernel<<<dim3(64), dim3(256), 0, stream>>>(
      Yout, stats, 8 * 36864, (long long)256 * 36864, 32);
  gn_relu_kernel<<<dim3(73728), dim3(256), 0, stream>>>(Yout, stats, fpn_gs, fpn_gb);
}

// Round 2
// 5141.647 us; speedup vs baseline: 1.5673x; 1.5673x over previous
//
#include <hip/hip_runtime.h>
#include <math.h>

#define NLEN 12096
#define BB 2

typedef __bf16 bhalf;
typedef bhalf bh8 __attribute__((ext_vector_type(8)));
typedef float f32x4 __attribute__((ext_vector_type(4)));

// =====================================================================
// bf16 MFMA GEMM: C[M,N] = A[M,K] @ Bt[N,K]^T  (+bias[n]) (+relu)
// A, Bt bf16 row-major. C fp32 or bf16. blockIdx.z batches via strides
// (element strides). Tile 128x128, BK=32, 4 waves (2x2), 16x16x32 MFMA.
// =====================================================================
__global__ __launch_bounds__(256) void bgemm_kernel(
    const bhalf* __restrict__ A, const bhalf* __restrict__ Bt,
    const float* __restrict__ bias, void* __restrict__ Cout,
    int M, int N, int K, long long sA, long long sB, long long sC,
    int outBf16, int relu)
{
  const int bz = blockIdx.z;
  A += bz * sA; Bt += bz * sB;
  const int m0 = blockIdx.y * 128, n0 = blockIdx.x * 128;
  __shared__ __align__(16) bhalf As[128 * 32];
  __shared__ __align__(16) bhalf Bs[128 * 32];
  const int t = threadIdx.x;
  const int lane = t & 63;
  const int w = t >> 6;
  const int wm = (w >> 1) * 64, wn = (w & 1) * 64;
  const int fr = lane & 15, fg = lane >> 4;
  f32x4 acc[4][4] = {};
  for (int k0 = 0; k0 < K; k0 += 32) {
#pragma unroll
    for (int j = 0; j < 2; ++j) {
      int id = t + j * 256;
      int row = id >> 2, kc = (id & 3) * 8;
      uint4 av = make_uint4(0u, 0u, 0u, 0u);
      int m = m0 + row;
      if (m < M) av = *(const uint4*)(A + (long long)m * K + k0 + kc);
      *(uint4*)(As + row * 32 + kc) = av;
      uint4 bv = make_uint4(0u, 0u, 0u, 0u);
      int n = n0 + row;
      if (n < N) bv = *(const uint4*)(Bt + (long long)n * K + k0 + kc);
      *(uint4*)(Bs + row * 32 + kc) = bv;
    }
    __syncthreads();
    bh8 af[4], bf[4];
#pragma unroll
    for (int mi = 0; mi < 4; ++mi)
      af[mi] = *(const bh8*)(As + (wm + mi * 16 + fr) * 32 + fg * 8);
#pragma unroll
    for (int ni = 0; ni < 4; ++ni)
      bf[ni] = *(const bh8*)(Bs + (wn + ni * 16 + fr) * 32 + fg * 8);
#pragma unroll
    for (int mi = 0; mi < 4; ++mi)
#pragma unroll
      for (int ni = 0; ni < 4; ++ni)
        acc[mi][ni] = __builtin_amdgcn_mfma_f32_16x16x32_bf16(af[mi], bf[ni], acc[mi][ni], 0, 0, 0);
    __syncthreads();
  }
  float* Cf = (float*)Cout + bz * sC;
  bhalf* Cb = (bhalf*)Cout + bz * sC;
#pragma unroll
  for (int mi = 0; mi < 4; ++mi) {
#pragma unroll
    for (int r = 0; r < 4; ++r) {
      int m = m0 + wm + mi * 16 + fg * 4 + r;
      if (m >= M) continue;
#pragma unroll
      for (int ni = 0; ni < 4; ++ni) {
        int n = n0 + wn + ni * 16 + fr;
        if (n >= N) continue;
        float v = acc[mi][ni][r];
        if (bias) v += bias[n];
        if (relu) v = fmaxf(v, 0.f);
        if (outBf16) Cb[(long long)m * N + n] = (bhalf)v;
        else         Cf[(long long)m * N + n] = v;
      }
    }
  }
}

// =====================================================================
// Implicit-GEMM 3x3 conv: C[M=36864,N=256] per batch, K = 9*256.
// A row m (pixel y,x): k=(tap*256+ci) -> latb[b][(y+ty)*194 + x+tx][ci],
// latb zero-padded [B][194*194][256] bf16. Bt = fpnT[256][2304].
// =====================================================================
__global__ __launch_bounds__(256) void bgemm_conv_kernel(
    const bhalf* __restrict__ Ab, const bhalf* __restrict__ Bt,
    bhalf* __restrict__ Cout)
{
  const int bz = blockIdx.z;
  const bhalf* Apad = Ab + (long long)bz * 37636 * 256;
  const int m0 = blockIdx.y * 128, n0 = blockIdx.x * 128;
  __shared__ __align__(16) bhalf As[128 * 32];
  __shared__ __align__(16) bhalf Bs[128 * 32];
  const int t = threadIdx.x;
  const int lane = t & 63;
  const int w = t >> 6;
  const int wm = (w >> 1) * 64, wn = (w & 1) * 64;
  const int fr = lane & 15, fg = lane >> 4;
  // precompute pixel coords for this thread's two staging rows
  int rowA[2], py[2], px[2];
#pragma unroll
  for (int j = 0; j < 2; ++j) {
    int id = t + j * 256;
    rowA[j] = id >> 2;
    int m = m0 + rowA[j];
    py[j] = m / 192; px[j] = m % 192;
  }
  f32x4 acc[4][4] = {};
  for (int k0 = 0; k0 < 2304; k0 += 32) {
    int tap = k0 >> 8;
    int ty = tap / 3, tx = tap % 3;
    int cik = k0 & 255;
#pragma unroll
    for (int j = 0; j < 2; ++j) {
      int id = t + j * 256;
      int kc = (id & 3) * 8;
      uint4 av = *(const uint4*)(Apad + ((long long)(py[j] + ty) * 194 + px[j] + tx) * 256 + cik + kc);
      *(uint4*)(As + rowA[j] * 32 + kc) = av;
      uint4 bv = *(const uint4*)(Bt + (long long)(n0 + rowA[j]) * 2304 + k0 + kc);
      *(uint4*)(Bs + rowA[j] * 32 + kc) = bv;
    }
    __syncthreads();
    bh8 af[4], bf[4];
#pragma unroll
    for (int mi = 0; mi < 4; ++mi)
      af[mi] = *(const bh8*)(As + (wm + mi * 16 + fr) * 32 + fg * 8);
#pragma unroll
    for (int ni = 0; ni < 4; ++ni)
      bf[ni] = *(const bh8*)(Bs + (wn + ni * 16 + fr) * 32 + fg * 8);
#pragma unroll
    for (int mi = 0; mi < 4; ++mi)
#pragma unroll
      for (int ni = 0; ni < 4; ++ni)
        acc[mi][ni] = __builtin_amdgcn_mfma_f32_16x16x32_bf16(af[mi], bf[ni], acc[mi][ni], 0, 0, 0);
    __syncthreads();
  }
  bhalf* Cb = Cout + (long long)bz * 36864 * 256;
#pragma unroll
  for (int mi = 0; mi < 4; ++mi)
#pragma unroll
    for (int r = 0; r < 4; ++r) {
      int m = m0 + wm + mi * 16 + fg * 4 + r;
#pragma unroll
      for (int ni = 0; ni < 4; ++ni) {
        int n = n0 + wn + ni * 16 + fr;
        Cb[(long long)m * 256 + n] = (bhalf)acc[mi][ni][r];
      }
    }
}

// =====================================================================
// Weight transpose+convert: W [z][Kd][Nd] fp32 -> out [z][Nd][Kd] bf16
// grid (Nd/32, Kd/32, z), block (32,8)
// =====================================================================
__global__ void twcvt_kernel(const float* __restrict__ Wsrc, bhalf* __restrict__ out,
                             int Kd, int Nd)
{
  __shared__ float tile[32][33];
  long long zo = (long long)blockIdx.z * Kd * Nd;
  int n0 = blockIdx.x * 32, k0 = blockIdx.y * 32;
#pragma unroll
  for (int j = 0; j < 4; ++j) {
    int kk = threadIdx.y + 8 * j;
    tile[kk][threadIdx.x] = Wsrc[zo + (long long)(k0 + kk) * Nd + n0 + threadIdx.x];
  }
  __syncthreads();
#pragma unroll
  for (int j = 0; j < 4; ++j) {
    int nn = threadIdx.y + 8 * j;
    out[zo + (long long)(n0 + nn) * Kd + k0 + threadIdx.x] = (bhalf)tile[threadIdx.x][nn];
  }
}

// feat [z][Ci][HW] fp32 -> [z][HW][Ci] bf16
__global__ void tfeat_kernel(const float* __restrict__ Fsrc, bhalf* __restrict__ out,
                             int Ci, int HW)
{
  __shared__ float tile[32][33];
  long long zo = (long long)blockIdx.z * Ci * HW;
  int hw0 = blockIdx.x * 32, c0 = blockIdx.y * 32;
#pragma unroll
  for (int j = 0; j < 4; ++j) {
    int cc = threadIdx.y + 8 * j;
    tile[cc][threadIdx.x] = Fsrc[zo + (long long)(c0 + cc) * HW + hw0 + threadIdx.x];
  }
  __syncthreads();
#pragma unroll
  for (int j = 0; j < 4; ++j) {
    int hh = threadIdx.y + 8 * j;
    out[zo + (long long)(hw0 + hh) * Ci + c0 + threadIdx.x] = (bhalf)tile[threadIdx.x][hh];
  }
}

// elementwise fp32->bf16
__global__ void cvt_kernel(const float* __restrict__ in, bhalf* __restrict__ out, int n)
{
  int i = blockIdx.x * 256 + threadIdx.x;
  if (i < n) out[i] = (bhalf)in[i];
}

// fpn_w [co][ci][9] -> fpnT[co][tap*256+ci] bf16
__global__ void fpnw_kernel(const float* __restrict__ Wsrc, bhalf* __restrict__ out)
{
  int o = blockIdx.x * 256 + threadIdx.x;
  if (o >= 256 * 2304) return;
  int co = o / 2304, r = o % 2304, tap = r >> 8, ci = r & 255;
  out[o] = (bhalf)Wsrc[(co * 256 + ci) * 9 + tap];
}

// zero fill (16B units)
__global__ void zero16_kernel(uint4* __restrict__ p, long long n16)
{
  long long i = (long long)blockIdx.x * 256 + threadIdx.x;
  if (i < n16) p[i] = make_uint4(0u, 0u, 0u, 0u);
}

// =====================================================================
// Sine positional embedding + level embed
// =====================================================================
__global__ void pos_kernel(float* __restrict__ pos, const float* __restrict__ level_embed)
{
  int i = blockIdx.x, c = threadIdx.x;
  int lvl, Wq, loc;
  if (i < 576)       { lvl = 0; Wq = 24; loc = i; }
  else if (i < 2880) { lvl = 1; Wq = 48; loc = i - 576; }
  else               { lvl = 2; Wq = 96; loc = i - 2880; }
  int h = loc / Wq, wcol = loc % Wq;
  int cc = c & 127;
  float coord = (c < 128) ? (float)(h + 1) : (float)(wcol + 1);
  float denom = (float)Wq + 1e-6f;
  float v = coord / denom * 6.28318530717958647692f;
  float tp = powf(10000.0f, (float)(cc & ~1) * (1.0f / 128.0f));
  float ang = v / tp;
  float val = (cc & 1) ? cosf(ang) : sinf(ang);
  pos[(long long)i * 256 + c] = val + level_embed[lvl * 256 + c];
}

// =====================================================================
// GroupNorm stats over row-major [Bb][HW][256]; block = b*32+g
// =====================================================================
__global__ __launch_bounds__(256) void gn_stats_rm_kernel(const void* __restrict__ X,
    float* __restrict__ stats, int HW, int isBf16)
{
  int b = blockIdx.x >> 5, g = blockIdx.x & 31;
  int c = (g << 3) + (threadIdx.x & 7);
  int hw0 = threadIdx.x >> 3;
  float s = 0.f, s2 = 0.f;
  if (isBf16) {
    const bhalf* p = (const bhalf*)X + (long long)b * HW * 256;
    for (int hw = hw0; hw < HW; hw += 32) {
      float v = (float)p[(long long)hw * 256 + c];
      s += v; s2 = fmaf(v, v, s2);
    }
  } else {
    const float* p = (const float*)X + (long long)b * HW * 256;
    for (int hw = hw0; hw < HW; hw += 32) {
      float v = p[(long long)hw * 256 + c];
      s += v; s2 = fmaf(v, v, s2);
    }
  }
#pragma unroll
  for (int o = 32; o > 0; o >>= 1) { s += __shfl_down(s, o); s2 += __shfl_down(s2, o); }
  __shared__ float sh[2][4];
  int lane = threadIdx.x & 63, wv = threadIdx.x >> 6;
  if (lane == 0) { sh[0][wv] = s; sh[1][wv] = s2; }
  __syncthreads();
  if (threadIdx.x == 0) {
    float S = sh[0][0] + sh[0][1] + sh[0][2] + sh[0][3];
    float S2 = sh[1][0] + sh[1][1] + sh[1][2] + sh[1][3];
    float inv = 1.f / (float)(HW * 8);
    float mean = S * inv;
    float var = S2 * inv - mean * mean;
    stats[blockIdx.x * 2] = mean;
    stats[blockIdx.x * 2 + 1] = rsqrtf(var + 1e-5f);
  }
}

// =====================================================================
// GN apply on tmp [B][HW][256] fp32 -> src rows [startRow..] fp32 + srcb bf16
// =====================================================================
__global__ void gn_apply_rm_kernel(const float* __restrict__ T, const float* __restrict__ stats,
    const float* __restrict__ gs, const float* __restrict__ gb,
    float* __restrict__ src, bhalf* __restrict__ srcb, int HW, int startRow)
{
  long long idx = (long long)blockIdx.x * 256 + threadIdx.x;
  int c = threadIdx.x & 255;  // blockDim 256 -> c == threadIdx.x
  long long row = idx >> 8;
  int b = (int)(row / HW);
  long long hw = row - (long long)b * HW;
  int g = c >> 3;
  float v = T[idx];
  v = (v - stats[(b * 32 + g) * 2]) * stats[(b * 32 + g) * 2 + 1] * gs[c] + gb[c];
  long long o = ((long long)b * NLEN + startRow + hw) * 256 + c;
  src[o] = v;
  srcb[o] = (bhalf)v;
}

// qb = bf16(src + pos)
__global__ void qb_kernel(const float* __restrict__ src, const float* __restrict__ pos,
                          bhalf* __restrict__ qb)
{
  long long idx = (long long)blockIdx.x * 256 + threadIdx.x;
  long long row = idx >> 8;
  int pr = (int)(row % NLEN);
  qb[idx] = (bhalf)(src[idx] + pos[(long long)pr * 256 + (idx & 255)]);
}

// =====================================================================
// src = LayerNorm(src + resid); also writes srcb bf16
// =====================================================================
__global__ __launch_bounds__(256) void ln_kernel(float* __restrict__ src,
    const float* __restrict__ resid, const float* __restrict__ s, const float* __restrict__ bsh,
    bhalf* __restrict__ srcb)
{
  long long r = blockIdx.x;
  int c = threadIdx.x;
  float v = src[r * 256 + c] + resid[r * 256 + c];
  float sum = v, sq = v * v;
#pragma unroll
  for (int o = 32; o > 0; o >>= 1) { sum += __shfl_down(sum, o); sq += __shfl_down(sq, o); }
  __shared__ float sh[2][4];
  int lane = c & 63, wv = c >> 6;
  if (lane == 0) { sh[0][wv] = sum; sh[1][wv] = sq; }
  __syncthreads();
  float S  = sh[0][0] + sh[0][1] + sh[0][2] + sh[0][3];
  float S2 = sh[1][0] + sh[1][1] + sh[1][2] + sh[1][3];
  float mean = S * (1.f / 256.f);
  float var = S2 * (1.f / 256.f) - mean * mean;
  float rstd = rsqrtf(var + 1e-5f);
  float y = (v - mean) * rstd * s[c] + bsh[c];
  src[r * 256 + c] = y;
  srcb[r * 256 + c] = (bhalf)y;
}

// =====================================================================
// Softmax over 12 per (b,i,head)
// =====================================================================
__global__ void softmax12_kernel(float* __restrict__ aw)
{
  int idx = blockIdx.x * blockDim.x + threadIdx.x;
  if (idx >= BB * NLEN * 8) return;
  int row = idx >> 3, hd = idx & 7;
  float* p = aw + (long long)row * 96 + hd * 12;
  float v[12]; float m = -1e30f;
#pragma unroll
  for (int j = 0; j < 12; ++j) { v[j] = p[j]; m = fmaxf(m, v[j]); }
  float ssum = 0.f;
#pragma unroll
  for (int j = 0; j < 12; ++j) { v[j] = expf(v[j] - m); ssum += v[j]; }
  float inv = 1.f / ssum;
#pragma unroll
  for (int j = 0; j < 12; ++j) p[j] = v[j] * inv;
}

// =====================================================================
// MSDeformAttn bilinear sampling (bf16 value -> bf16 sampled)
// =====================================================================
__global__ __launch_bounds__(256) void deform_kernel(const bhalf* __restrict__ value,
    const float* __restrict__ offb, const float* __restrict__ awb, bhalf* __restrict__ out)
{
  int bi = blockIdx.x;
  int i = bi % NLEN;
  int bbase = bi - i;
  int c = threadIdx.x;
  int head = c >> 5;
  int loc, Wq;
  if (i < 576)       { Wq = 24; loc = i; }
  else if (i < 2880) { Wq = 48; loc = i - 576; }
  else               { Wq = 96; loc = i - 2880; }
  float rx = ((loc % Wq) + 0.5f) / (float)Wq;
  float ry = ((loc / Wq) + 0.5f) / (float)Wq;
  const float* offp = offb + (long long)bi * 192 + head * 24;
  const float* awp  = awb  + (long long)bi * 96  + head * 12;
  float acc = 0.f;
  const int starts[3] = {0, 576, 2880};
  const int Ls[3] = {24, 48, 96};
#pragma unroll
  for (int l = 0; l < 3; ++l) {
    const int Wl = Ls[l];
    const float fW = (float)Wl;
    const long long vbase = (long long)(bbase + starts[l]) * 256 + c;
#pragma unroll
    for (int p = 0; p < 4; ++p) {
      float ox = offp[l * 8 + p * 2], oy = offp[l * 8 + p * 2 + 1];
      float a = awp[l * 4 + p];
      float x = (rx + ox / fW) * fW - 0.5f;
      float y = (ry + oy / fW) * fW - 0.5f;
      float x0f = floorf(x), y0f = floorf(y);
      float wx = x - x0f, wy = y - y0f;
      int x0 = (int)x0f, y0 = (int)y0f;
      float g00 = 0.f, g01 = 0.f, g10 = 0.f, g11 = 0.f;
      bool xv0 = (x0 >= 0) && (x0 < Wl);
      bool xv1 = (x0 + 1 >= 0) && (x0 + 1 < Wl);
      bool yv0 = (y0 >= 0) && (y0 < Wl);
      bool yv1 = (y0 + 1 >= 0) && (y0 + 1 < Wl);
      if (yv0 && xv0) g00 = (float)value[vbase + (long long)(y0 * Wl + x0) * 256];
      if (yv0 && xv1) g01 = (float)value[vbase + (long long)(y0 * Wl + x0 + 1) * 256];
      if (yv1 && xv0) g10 = (float)value[vbase + (long long)((y0 + 1) * Wl + x0) * 256];
      if (yv1 && xv1) g11 = (float)value[vbase + (long long)((y0 + 1) * Wl + x0 + 1) * 256];
      float sv = g00 * (1.f - wx) * (1.f - wy) + g01 * wx * (1.f - wy)
               + g10 * (1.f - wx) * wy + g11 * wx * wy;
      acc = fmaf(a, sv, acc);
    }
  }
  out[(long long)bi * 256 + c] = (bhalf)acc;
}

// =====================================================================
// src[b][startRow+hw][c] -> out[b][c][hw]
// =====================================================================
__global__ void transpose_out_kernel(const float* __restrict__ src, float* __restrict__ out,
    int HW, int startRow)
{
  __shared__ float tile[32][33];
  int b = blockIdx.z;
  int w0 = blockIdx.x * 32, c0 = blockIdx.y * 32;
#pragma unroll
  for (int j = 0; j < 4; ++j) {
    int wl = threadIdx.y + 8 * j;
    tile[wl][threadIdx.x] = src[((long long)b * NLEN + startRow + w0 + wl) * 256 + c0 + threadIdx.x];
  }
  __syncthreads();
#pragma unroll
  for (int j = 0; j < 4; ++j) {
    int cl = threadIdx.y + 8 * j;
    out[((long long)b * 256 + c0 + cl) * HW + w0 + threadIdx.x] = tile[threadIdx.x][cl];
  }
}

// =====================================================================
// latb[b][(y+1)*194+(x+1)][c] = GN(lat[b][hw][c]) + upsample2x(src lvl2)
// lat bf16 [B][36864][256]; src fp32 rows 2880.. (96x96)
// =====================================================================
__global__ void lat_finish_rm_kernel(const bhalf* __restrict__ lat, const float* __restrict__ stats,
    const float* __restrict__ gs, const float* __restrict__ gb,
    const float* __restrict__ src, bhalf* __restrict__ latb)
{
  long long idx = (long long)blockIdx.x * 256 + threadIdx.x;
  int c = threadIdx.x & 255;
  long long row = idx >> 8;
  int b = (int)(row / 36864);
  int p = (int)(row - (long long)b * 36864);
  int y = p / 192, x = p % 192;
  int g = c >> 3;
  float v = (float)lat[idx];
  v = (v - stats[(b * 32 + g) * 2]) * stats[(b * 32 + g) * 2 + 1] * gs[c] + gb[c];
  float ys = fmaxf(y * 0.5f - 0.25f, 0.f);
  float xs = fmaxf(x * 0.5f - 0.25f, 0.f);
  int y0 = (int)ys; float wy = ys - (float)y0; int y1 = min(y0 + 1, 95);
  int x0 = (int)xs; float wx = xs - (float)x0; int x1 = min(x0 + 1, 95);
  const float* sp = src + ((long long)b * NLEN + 2880) * 256 + c;
  float r0 = sp[(long long)(y0 * 96 + x0) * 256] * (1.f - wx) + sp[(long long)(y0 * 96 + x1) * 256] * wx;
  float r1 = sp[(long long)(y1 * 96 + x0) * 256] * (1.f - wx) + sp[(long long)(y1 * 96 + x1) * 256] * wx;
  latb[((long long)b * 37636 + (long long)(y + 1) * 194 + (x + 1)) * 256 + c]
      = (bhalf)(v + r0 * (1.f - wy) + r1 * wy);
}

// =====================================================================
// Final GN+ReLU+transpose: convC bf16 [b][hw][c] -> Y fp32 [b][c][hw]
// grid (1152, 8, B), block (32,8)
// =====================================================================
__global__ void gn_relu_tr_kernel(const bhalf* __restrict__ convC, const float* __restrict__ stats,
    const float* __restrict__ gs, const float* __restrict__ gb, float* __restrict__ Y)
{
  __shared__ float tile[32][33];
  int b = blockIdx.z;
  int hw0 = blockIdx.x * 32, c0 = blockIdx.y * 32;
#pragma unroll
  for (int j = 0; j < 4; ++j) {
    int hwl = threadIdx.y + 8 * j;
    int c = c0 + threadIdx.x;
    int g = c >> 3;
    float v = (float)convC[((long long)b * 36864 + hw0 + hwl) * 256 + c];
    v = (v - stats[(b * 32 + g) * 2]) * stats[(b * 32 + g) * 2 + 1] * gs[c] + gb[c];
    tile[hwl][threadIdx.x] = fmaxf(v, 0.f);
  }
  __syncthreads();
#pragma unroll
  for (int j = 0; j < 4; ++j) {
    int cl = threadIdx.y + 8 * j;
    Y[((long long)b * 256 + c0 + cl) * 36864 + hw0 + threadIdx.x] = tile[threadIdx.x][cl];
  }
}

// =====================================================================
extern "C" void kernel_launch(void* const* d_in, const int* in_sizes, int n_in,
                              void* d_out, int out_size, void* d_ws, size_t ws_size,
                              hipStream_t stream)
{
  const float* res2 = (const float*)d_in[0];
  const float* res3 = (const float*)d_in[1];
  const float* res4 = (const float*)d_in[2];
  const float* res5 = (const float*)d_in[3];
  const float* pw[3]  = {(const float*)d_in[4],  (const float*)d_in[8],  (const float*)d_in[12]};
  const float* pb[3]  = {(const float*)d_in[5],  (const float*)d_in[9],  (const float*)d_in[13]};
  const float* gss[3] = {(const float*)d_in[6],  (const float*)d_in[10], (const float*)d_in[14]};
  const float* gbb[3] = {(const float*)d_in[7],  (const float*)d_in[11], (const float*)d_in[15]};
  const float* level_embed = (const float*)d_in[16];
  const float* off_w = (const float*)d_in[17];
  const float* off_b = (const float*)d_in[18];
  const float* aw_w  = (const float*)d_in[19];
  const float* aw_b  = (const float*)d_in[20];
  const float* val_w = (const float*)d_in[21];
  const float* val_b = (const float*)d_in[22];
  const float* out_w = (const float*)d_in[23];
  const float* out_b = (const float*)d_in[24];
  const float* ln1_s = (const float*)d_in[25];
  const float* ln1_b = (const float*)d_in[26];
  const float* ffn1_w = (const float*)d_in[27];
  const float* ffn1_b = (const float*)d_in[28];
  const float* ffn2_w = (const float*)d_in[29];
  const float* ffn2_b = (const float*)d_in[30];
  const float* ln2_s = (const float*)d_in[31];
  const float* ln2_b = (const float*)d_in[32];
  const float* lat_w = (const float*)d_in[33];
  const float* lat_gs = (const float*)d_in[34];
  const float* lat_gb = (const float*)d_in[35];
  const float* fpn_w = (const float*)d_in[36];
  const float* fpn_gs = (const float*)d_in[37];
  const float* fpn_gb = (const float*)d_in[38];

  char* W = (char*)d_ws;
  float* src   = (float*)(W + 0);              // 24,772,608 B
  float* pos   = (float*)(W + 24772608LL);     // 12,386,304
  float* tmp   = (float*)(W + 37158912LL);     // 24,772,608
  bhalf* srcb  = (bhalf*)(W + 61931520LL);     // 12,386,304
  bhalf* wreg  = (bhalf*)(W + 74317824LL);     // 11,894,784
  float* stats = (float*)(W + 86212608LL);     // 512
  char*  U     = W + 86213120LL;               // 114,573,312

  // weight-region layout (bf16 elements)
  bhalf* valT  = wreg + 0;
  bhalf* offT  = wreg + 393216;
  bhalf* awT   = wreg + 688128;
  bhalf* outT  = wreg + 835584;
  bhalf* f1T   = wreg + 1228800;
  bhalf* f2T   = wreg + 2801664;
  bhalf* pwb5  = wreg + 4374528;
  bhalf* pwb4  = wreg + 4898816;
  bhalf* pwb3  = wreg + 5160960;
  bhalf* latwb = wreg + 5292032;
  bhalf* fpnT  = wreg + 5357568;

  // union region — encoder phase
  bhalf* qb      = (bhalf*)(U + 0);
  bhalf* valueb  = (bhalf*)(U + 12386304LL);
  bhalf* sampb   = (bhalf*)(U + 24772608LL);
  float* offbuf  = (float*)(U + 37158912LL);
  float* awbuf   = (float*)(U + 55738368LL);
  bhalf* hbuf    = (bhalf*)(U + 65028096LL);
  // union region — proj phase
  bhalf* featT   = (bhalf*)(U + 0);
  // union region — FPN phase
  bhalf* res2T   = (bhalf*)(U + 0);
  bhalf* latbf   = (bhalf*)(U + 37748736LL);   // lat, then convC (aliased)
  bhalf* latb    = (bhalf*)(U + 75497472LL);   // padded [B][194*194][256]

  float* Yout = (float*)d_out;
  float* out0 = Yout + 18874368LL;
  float* out1 = Yout + 19169280LL;
  float* out2 = Yout + 20348928LL;

  const int M = BB * NLEN;  // 24192

  // ---- weight prep ----
  twcvt_kernel<<<dim3(8, 8, 6), dim3(32, 8), 0, stream>>>(val_w, valT, 256, 256);
  twcvt_kernel<<<dim3(6, 8, 6), dim3(32, 8), 0, stream>>>(off_w, offT, 256, 192);
  twcvt_kernel<<<dim3(3, 8, 6), dim3(32, 8), 0, stream>>>(aw_w, awT, 256, 96);
  twcvt_kernel<<<dim3(8, 8, 6), dim3(32, 8), 0, stream>>>(out_w, outT, 256, 256);
  twcvt_kernel<<<dim3(32, 8, 6), dim3(32, 8), 0, stream>>>(ffn1_w, f1T, 256, 1024);
  twcvt_kernel<<<dim3(8, 32, 6), dim3(32, 8), 0, stream>>>(ffn2_w, f2T, 1024, 256);
  cvt_kernel<<<dim3(2048), dim3(256), 0, stream>>>(pw[0], pwb5, 524288);
  cvt_kernel<<<dim3(1024), dim3(256), 0, stream>>>(pw[1], pwb4, 262144);
  cvt_kernel<<<dim3(512),  dim3(256), 0, stream>>>(pw[2], pwb3, 131072);
  cvt_kernel<<<dim3(256),  dim3(256), 0, stream>>>(lat_w, latwb, 65536);
  fpnw_kernel<<<dim3(2304), dim3(256), 0, stream>>>(fpn_w, fpnT);

  // ---- positional embedding ----
  pos_kernel<<<dim3(NLEN), dim3(256), 0, stream>>>(pos, level_embed);

  // ---- input projections + GN -> src/srcb ----
  const float* feats[3] = {res5, res4, res3};
  const bhalf* pwbs[3] = {pwb5, pwb4, pwb3};
  const int cins[3] = {2048, 1024, 512};
  const int HWs[3] = {576, 2304, 9216};
  const int startsHost[3] = {0, 576, 2880};
  for (int lvl = 0; lvl < 3; ++lvl) {
    int HW = HWs[lvl], cin = cins[lvl];
    tfeat_kernel<<<dim3(HW / 32, cin / 32, BB), dim3(32, 8), 0, stream>>>(feats[lvl], featT, cin, HW);
    bgemm_kernel<<<dim3(2, (HW + 127) / 128, BB), dim3(256), 0, stream>>>(
        featT, pwbs[lvl], pb[lvl], tmp, HW, 256, cin,
        (long long)HW * cin, 0LL, (long long)HW * 256, 0, 0);
    gn_stats_rm_kernel<<<dim3(64), dim3(256), 0, stream>>>(tmp, stats, HW, 0);
    gn_apply_rm_kernel<<<dim3(BB * HW), dim3(256), 0, stream>>>(
        tmp, stats, gss[lvl], gbb[lvl], src, srcb, HW, startsHost[lvl]);
  }

  // ---- 6 encoder layers ----
  for (int l = 0; l < 6; ++l) {
    qb_kernel<<<dim3(M), dim3(256), 0, stream>>>(src, pos, qb);
    bgemm_kernel<<<dim3(2, M / 128, 1), dim3(256), 0, stream>>>(
        srcb, valT + (long long)l * 65536, val_b + l * 256, valueb,
        M, 256, 256, 0LL, 0LL, 0LL, 1, 0);
    bgemm_kernel<<<dim3(2, M / 128, 1), dim3(256), 0, stream>>>(
        qb, offT + (long long)l * 49152, off_b + l * 192, offbuf,
        M, 192, 256, 0LL, 0LL, 0LL, 0, 0);
    bgemm_kernel<<<dim3(1, M / 128, 1), dim3(256), 0, stream>>>(
        qb, awT + (long long)l * 24576, aw_b + l * 96, awbuf,
        M, 96, 256, 0LL, 0LL, 0LL, 0, 0);
    softmax12_kernel<<<dim3((M * 8 + 255) / 256), dim3(256), 0, stream>>>(awbuf);
    deform_kernel<<<dim3(M), dim3(256), 0, stream>>>(valueb, offbuf, awbuf, sampb);
    bgemm_kernel<<<dim3(2, M / 128, 1), dim3(256), 0, stream>>>(
        sampb, outT + (long long)l * 65536, out_b + l * 256, tmp,
        M, 256, 256, 0LL, 0LL, 0LL, 0, 0);
    ln_kernel<<<dim3(M), dim3(256), 0, stream>>>(src, tmp, ln1_s + l * 256, ln1_b + l * 256, srcb);
    bgemm_kernel<<<dim3(8, M / 128, 1), dim3(256), 0, stream>>>(
        srcb, f1T + (long long)l * 262144, ffn1_b + l * 1024, hbuf,
        M, 1024, 256, 0LL, 0LL, 0LL, 1, 1);
    bgemm_kernel<<<dim3(2, M / 128, 1), dim3(256), 0, stream>>>(
        hbuf, f2T + (long long)l * 262144, ffn2_b + l * 256, tmp,
        M, 256, 1024, 0LL, 0LL, 0LL, 0, 0);
    ln_kernel<<<dim3(M), dim3(256), 0, stream>>>(src, tmp, ln2_s + l * 256, ln2_b + l * 256, srcb);
  }

  // ---- output transposes ----
  float* outsPtr[3] = {out0, out1, out2};
  for (int lvl = 0; lvl < 3; ++lvl) {
    transpose_out_kernel<<<dim3(HWs[lvl] / 32, 8, BB), dim3(32, 8), 0, stream>>>(
        src, outsPtr[lvl], HWs[lvl], startsHost[lvl]);
  }

  // ---- FPN ----
  tfeat_kernel<<<dim3(1152, 8, BB), dim3(32, 8), 0, stream>>>(res2, res2T, 256, 36864);
  bgemm_kernel<<<dim3(2, 288, BB), dim3(256), 0, stream>>>(
      res2T, latwb, nullptr, latbf, 36864, 256, 256,
      36864LL * 256, 0LL, 36864LL * 256, 1, 0);
  gn_stats_rm_kernel<<<dim3(64), dim3(256), 0, stream>>>(latbf, stats, 36864, 1);
  zero16_kernel<<<dim3(9410), dim3(256), 0, stream>>>((uint4*)latb, 2408704LL);
  lat_finish_rm_kernel<<<dim3(73728), dim3(256), 0, stream>>>(latbf, stats, lat_gs, lat_gb, src, latb);
  bgemm_conv_kernel<<<dim3(2, 288, BB), dim3(256), 0, stream>>>(latb, fpnT, latbf);
  gn_stats_rm_kernel<<<dim3(64), dim3(256), 0, stream>>>(latbf, stats, 36864, 1);
  gn_relu_tr_kernel<<<dim3(1152, 8, BB), dim3(32, 8), 0, stream>>>(latbf, stats, fpn_gs, fpn_gb, Yout);
}

// Round 3
// 3255.048 us; speedup vs baseline: 2.4757x; 1.5796x over previous
//
#include <hip/hip_runtime.h>
#include <math.h>

#define NLEN 12096
#define BB 2

typedef __bf16 bhalf;
typedef bhalf bh8 __attribute__((ext_vector_type(8)));
typedef bhalf bh4 __attribute__((ext_vector_type(4)));
typedef float f32x4 __attribute__((ext_vector_type(4)));

// =====================================================================
// bf16 MFMA GEMM: C[M,N] = A[M,K] @ Bt[N,K]^T  (+bias[n]) (+relu)
// A, Bt bf16 row-major. C fp32 or bf16. blockIdx.z batches via strides
// (element strides). Tile 128x128, BK=32, 4 waves (2x2), 16x16x32 MFMA.
// =====================================================================
__global__ __launch_bounds__(256) void bgemm_kernel(
    const bhalf* __restrict__ A, const bhalf* __restrict__ Bt,
    const float* __restrict__ bias, void* __restrict__ Cout,
    int M, int N, int K, long long sA, long long sB, long long sC,
    int outBf16, int relu)
{
  const int bz = blockIdx.z;
  A += bz * sA; Bt += bz * sB;
  const int m0 = blockIdx.y * 128, n0 = blockIdx.x * 128;
  __shared__ __align__(16) bhalf As[128 * 32];
  __shared__ __align__(16) bhalf Bs[128 * 32];
  const int t = threadIdx.x;
  const int lane = t & 63;
  const int w = t >> 6;
  const int wm = (w >> 1) * 64, wn = (w & 1) * 64;
  const int fr = lane & 15, fg = lane >> 4;
  f32x4 acc[4][4] = {};
  for (int k0 = 0; k0 < K; k0 += 32) {
#pragma unroll
    for (int j = 0; j < 2; ++j) {
      int id = t + j * 256;
      int row = id >> 2, kc = (id & 3) * 8;
      uint4 av = make_uint4(0u, 0u, 0u, 0u);
      int m = m0 + row;
      if (m < M) av = *(const uint4*)(A + (long long)m * K + k0 + kc);
      *(uint4*)(As + row * 32 + kc) = av;
      uint4 bv = make_uint4(0u, 0u, 0u, 0u);
      int n = n0 + row;
      if (n < N) bv = *(const uint4*)(Bt + (long long)n * K + k0 + kc);
      *(uint4*)(Bs + row * 32 + kc) = bv;
    }
    __syncthreads();
    bh8 af[4], bf[4];
#pragma unroll
    for (int mi = 0; mi < 4; ++mi)
      af[mi] = *(const bh8*)(As + (wm + mi * 16 + fr) * 32 + fg * 8);
#pragma unroll
    for (int ni = 0; ni < 4; ++ni)
      bf[ni] = *(const bh8*)(Bs + (wn + ni * 16 + fr) * 32 + fg * 8);
#pragma unroll
    for (int mi = 0; mi < 4; ++mi)
#pragma unroll
      for (int ni = 0; ni < 4; ++ni)
        acc[mi][ni] = __builtin_amdgcn_mfma_f32_16x16x32_bf16(af[mi], bf[ni], acc[mi][ni], 0, 0, 0);
    __syncthreads();
  }
  float* Cf = (float*)Cout + bz * sC;
  bhalf* Cb = (bhalf*)Cout + bz * sC;
#pragma unroll
  for (int mi = 0; mi < 4; ++mi) {
#pragma unroll
    for (int r = 0; r < 4; ++r) {
      int m = m0 + wm + mi * 16 + fg * 4 + r;
      if (m >= M) continue;
#pragma unroll
      for (int ni = 0; ni < 4; ++ni) {
        int n = n0 + wn + ni * 16 + fr;
        if (n >= N) continue;
        float v = acc[mi][ni][r];
        if (bias) v += bias[n];
        if (relu) v = fmaxf(v, 0.f);
        if (outBf16) Cb[(long long)m * N + n] = (bhalf)v;
        else         Cf[(long long)m * N + n] = v;
      }
    }
  }
}

// =====================================================================
// Implicit-GEMM 3x3 conv: C[M=36864,N=256] per batch, K = 9*256.
// =====================================================================
__global__ __launch_bounds__(256) void bgemm_conv_kernel(
    const bhalf* __restrict__ Ab, const bhalf* __restrict__ Bt,
    bhalf* __restrict__ Cout)
{
  const int bz = blockIdx.z;
  const bhalf* Apad = Ab + (long long)bz * 37636 * 256;
  const int m0 = blockIdx.y * 128, n0 = blockIdx.x * 128;
  __shared__ __align__(16) bhalf As[128 * 32];
  __shared__ __align__(16) bhalf Bs[128 * 32];
  const int t = threadIdx.x;
  const int lane = t & 63;
  const int w = t >> 6;
  const int wm = (w >> 1) * 64, wn = (w & 1) * 64;
  const int fr = lane & 15, fg = lane >> 4;
  int rowA[2], py[2], px[2];
#pragma unroll
  for (int j = 0; j < 2; ++j) {
    int id = t + j * 256;
    rowA[j] = id >> 2;
    int m = m0 + rowA[j];
    py[j] = m / 192; px[j] = m % 192;
  }
  f32x4 acc[4][4] = {};
  for (int k0 = 0; k0 < 2304; k0 += 32) {
    int tap = k0 >> 8;
    int ty = tap / 3, tx = tap % 3;
    int cik = k0 & 255;
#pragma unroll
    for (int j = 0; j < 2; ++j) {
      int id = t + j * 256;
      int kc = (id & 3) * 8;
      uint4 av = *(const uint4*)(Apad + ((long long)(py[j] + ty) * 194 + px[j] + tx) * 256 + cik + kc);
      *(uint4*)(As + rowA[j] * 32 + kc) = av;
      uint4 bv = *(const uint4*)(Bt + (long long)(n0 + rowA[j]) * 2304 + k0 + kc);
      *(uint4*)(Bs + rowA[j] * 32 + kc) = bv;
    }
    __syncthreads();
    bh8 af[4], bf[4];
#pragma unroll
    for (int mi = 0; mi < 4; ++mi)
      af[mi] = *(const bh8*)(As + (wm + mi * 16 + fr) * 32 + fg * 8);
#pragma unroll
    for (int ni = 0; ni < 4; ++ni)
      bf[ni] = *(const bh8*)(Bs + (wn + ni * 16 + fr) * 32 + fg * 8);
#pragma unroll
    for (int mi = 0; mi < 4; ++mi)
#pragma unroll
      for (int ni = 0; ni < 4; ++ni)
        acc[mi][ni] = __builtin_amdgcn_mfma_f32_16x16x32_bf16(af[mi], bf[ni], acc[mi][ni], 0, 0, 0);
    __syncthreads();
  }
  bhalf* Cb = Cout + (long long)bz * 36864 * 256;
#pragma unroll
  for (int mi = 0; mi < 4; ++mi)
#pragma unroll
    for (int r = 0; r < 4; ++r) {
      int m = m0 + wm + mi * 16 + fg * 4 + r;
#pragma unroll
      for (int ni = 0; ni < 4; ++ni) {
        int n = n0 + wn + ni * 16 + fr;
        Cb[(long long)m * 256 + n] = (bhalf)acc[mi][ni][r];
      }
    }
}

// =====================================================================
// Weight transpose+convert: W [z][Kd][Nd] fp32 -> out [z][Nd][Kd] bf16
// =====================================================================
__global__ void twcvt_kernel(const float* __restrict__ Wsrc, bhalf* __restrict__ out,
                             int Kd, int Nd)
{
  __shared__ float tile[32][33];
  long long zo = (long long)blockIdx.z * Kd * Nd;
  int n0 = blockIdx.x * 32, k0 = blockIdx.y * 32;
#pragma unroll
  for (int j = 0; j < 4; ++j) {
    int kk = threadIdx.y + 8 * j;
    tile[kk][threadIdx.x] = Wsrc[zo + (long long)(k0 + kk) * Nd + n0 + threadIdx.x];
  }
  __syncthreads();
#pragma unroll
  for (int j = 0; j < 4; ++j) {
    int nn = threadIdx.y + 8 * j;
    out[zo + (long long)(n0 + nn) * Kd + k0 + threadIdx.x] = (bhalf)tile[threadIdx.x][nn];
  }
}

// feat [z][Ci][HW] fp32 -> [z][HW][Ci] bf16
__global__ void tfeat_kernel(const float* __restrict__ Fsrc, bhalf* __restrict__ out,
                             int Ci, int HW)
{
  __shared__ float tile[32][33];
  long long zo = (long long)blockIdx.z * Ci * HW;
  int hw0 = blockIdx.x * 32, c0 = blockIdx.y * 32;
#pragma unroll
  for (int j = 0; j < 4; ++j) {
    int cc = threadIdx.y + 8 * j;
    tile[cc][threadIdx.x] = Fsrc[zo + (long long)(c0 + cc) * HW + hw0 + threadIdx.x];
  }
  __syncthreads();
#pragma unroll
  for (int j = 0; j < 4; ++j) {
    int hh = threadIdx.y + 8 * j;
    out[zo + (long long)(hw0 + hh) * Ci + c0 + threadIdx.x] = (bhalf)tile[threadIdx.x][hh];
  }
}

__global__ void cvt_kernel(const float* __restrict__ in, bhalf* __restrict__ out, int n)
{
  int i = blockIdx.x * 256 + threadIdx.x;
  if (i < n) out[i] = (bhalf)in[i];
}

__global__ void fpnw_kernel(const float* __restrict__ Wsrc, bhalf* __restrict__ out)
{
  int o = blockIdx.x * 256 + threadIdx.x;
  if (o >= 256 * 2304) return;
  int co = o / 2304, r = o % 2304, tap = r >> 8, ci = r & 255;
  out[o] = (bhalf)Wsrc[(co * 256 + ci) * 9 + tap];
}

__global__ void zero16_kernel(uint4* __restrict__ p, long long n16)
{
  long long i = (long long)blockIdx.x * 256 + threadIdx.x;
  if (i < n16) p[i] = make_uint4(0u, 0u, 0u, 0u);
}

// =====================================================================
// Sine positional embedding + level embed
// =====================================================================
__global__ void pos_kernel(float* __restrict__ pos, const float* __restrict__ level_embed)
{
  int i = blockIdx.x, c = threadIdx.x;
  int lvl, Wq, loc;
  if (i < 576)       { lvl = 0; Wq = 24; loc = i; }
  else if (i < 2880) { lvl = 1; Wq = 48; loc = i - 576; }
  else               { lvl = 2; Wq = 96; loc = i - 2880; }
  int h = loc / Wq, wcol = loc % Wq;
  int cc = c & 127;
  float coord = (c < 128) ? (float)(h + 1) : (float)(wcol + 1);
  float denom = (float)Wq + 1e-6f;
  float v = coord / denom * 6.28318530717958647692f;
  float tp = powf(10000.0f, (float)(cc & ~1) * (1.0f / 128.0f));
  float ang = v / tp;
  float val = (cc & 1) ? cosf(ang) : sinf(ang);
  pos[(long long)i * 256 + c] = val + level_embed[lvl * 256 + c];
}

// =====================================================================
// GroupNorm stats over row-major [Bb][HW][256]; block = b*32+g
// =====================================================================
__global__ __launch_bounds__(256) void gn_stats_rm_kernel(const void* __restrict__ X,
    float* __restrict__ stats, int HW, int isBf16)
{
  int b = blockIdx.x >> 5, g = blockIdx.x & 31;
  int c = (g << 3) + (threadIdx.x & 7);
  int hw0 = threadIdx.x >> 3;
  float s = 0.f, s2 = 0.f;
  if (isBf16) {
    const bhalf* p = (const bhalf*)X + (long long)b * HW * 256;
    for (int hw = hw0; hw < HW; hw += 32) {
      float v = (float)p[(long long)hw * 256 + c];
      s += v; s2 = fmaf(v, v, s2);
    }
  } else {
    const float* p = (const float*)X + (long long)b * HW * 256;
    for (int hw = hw0; hw < HW; hw += 32) {
      float v = p[(long long)hw * 256 + c];
      s += v; s2 = fmaf(v, v, s2);
    }
  }
#pragma unroll
  for (int o = 32; o > 0; o >>= 1) { s += __shfl_down(s, o); s2 += __shfl_down(s2, o); }
  __shared__ float sh[2][4];
  int lane = threadIdx.x & 63, wv = threadIdx.x >> 6;
  if (lane == 0) { sh[0][wv] = s; sh[1][wv] = s2; }
  __syncthreads();
  if (threadIdx.x == 0) {
    float S = sh[0][0] + sh[0][1] + sh[0][2] + sh[0][3];
    float S2 = sh[1][0] + sh[1][1] + sh[1][2] + sh[1][3];
    float inv = 1.f / (float)(HW * 8);
    float mean = S * inv;
    float var = S2 * inv - mean * mean;
    stats[blockIdx.x * 2] = mean;
    stats[blockIdx.x * 2 + 1] = rsqrtf(var + 1e-5f);
  }
}

// =====================================================================
// GN apply on tmp [B][HW][256] fp32 -> src rows fp32 + srcb bf16
// =====================================================================
__global__ void gn_apply_rm_kernel(const float* __restrict__ T, const float* __restrict__ stats,
    const float* __restrict__ gs, const float* __restrict__ gb,
    float* __restrict__ src, bhalf* __restrict__ srcb, int HW, int startRow)
{
  long long idx = (long long)blockIdx.x * 256 + threadIdx.x;
  int c = threadIdx.x & 255;
  long long row = idx >> 8;
  int b = (int)(row / HW);
  long long hw = row - (long long)b * HW;
  int g = c >> 3;
  float v = T[idx];
  v = (v - stats[(b * 32 + g) * 2]) * stats[(b * 32 + g) * 2 + 1] * gs[c] + gb[c];
  long long o = ((long long)b * NLEN + startRow + hw) * 256 + c;
  src[o] = v;
  srcb[o] = (bhalf)v;
}

// qb = bf16(src + pos)
__global__ void qb_kernel(const float* __restrict__ src, const float* __restrict__ pos,
                          bhalf* __restrict__ qb)
{
  long long idx = (long long)blockIdx.x * 256 + threadIdx.x;
  long long row = idx >> 8;
  int pr = (int)(row % NLEN);
  qb[idx] = (bhalf)(src[idx] + pos[(long long)pr * 256 + (idx & 255)]);
}

// =====================================================================
// src = LayerNorm(src + resid); also writes srcb bf16
// =====================================================================
__global__ __launch_bounds__(256) void ln_kernel(float* __restrict__ src,
    const float* __restrict__ resid, const float* __restrict__ s, const float* __restrict__ bsh,
    bhalf* __restrict__ srcb)
{
  long long r = blockIdx.x;
  int c = threadIdx.x;
  float v = src[r * 256 + c] + resid[r * 256 + c];
  float sum = v, sq = v * v;
#pragma unroll
  for (int o = 32; o > 0; o >>= 1) { sum += __shfl_down(sum, o); sq += __shfl_down(sq, o); }
  __shared__ float sh[2][4];
  int lane = c & 63, wv = c >> 6;
  if (lane == 0) { sh[0][wv] = sum; sh[1][wv] = sq; }
  __syncthreads();
  float S  = sh[0][0] + sh[0][1] + sh[0][2] + sh[0][3];
  float S2 = sh[1][0] + sh[1][1] + sh[1][2] + sh[1][3];
  float mean = S * (1.f / 256.f);
  float var = S2 * (1.f / 256.f) - mean * mean;
  float rstd = rsqrtf(var + 1e-5f);
  float y = (v - mean) * rstd * s[c] + bsh[c];
  src[r * 256 + c] = y;
  srcb[r * 256 + c] = (bhalf)y;
}

// =====================================================================
// MSDeformAttn sampling, wave-per-query, 4 channels/lane, fused softmax.
// value bf16 [B*LEN][256]; offb fp32 raw offsets; awb fp32 raw logits
// (bias added); out bf16 [B*LEN][256]. Grid M/4 blocks x 256 thr.
// =====================================================================
__global__ __launch_bounds__(256) void deform_kernel(const bhalf* __restrict__ value,
    const float* __restrict__ offb, const float* __restrict__ awb, bhalf* __restrict__ out)
{
  const int wv = threadIdx.x >> 6;
  const int lane = threadIdx.x & 63;
  const int bi = blockIdx.x * 4 + wv;      // b*LEN + i
  const int i = bi % NLEN;
  const int bbase = bi - i;
  const int c0 = lane * 4;
  const int head = lane >> 3;
  int loc, Wq;
  if (i < 576)       { Wq = 24; loc = i; }
  else if (i < 2880) { Wq = 48; loc = i - 576; }
  else               { Wq = 96; loc = i - 2880; }
  const float rx = ((loc % Wq) + 0.5f) / (float)Wq;
  const float ry = ((loc / Wq) + 0.5f) / (float)Wq;
  const float* offp = offb + (long long)bi * 192 + head * 24;
  const float* awp  = awb  + (long long)bi * 96  + head * 12;
  // inline softmax over the 12 logits of this head
  float aw[12]; float mx = -1e30f;
#pragma unroll
  for (int j = 0; j < 12; ++j) { aw[j] = awp[j]; mx = fmaxf(mx, aw[j]); }
  float ssum = 0.f;
#pragma unroll
  for (int j = 0; j < 12; ++j) { aw[j] = __expf(aw[j] - mx); ssum += aw[j]; }
  const float sinv = 1.f / ssum;
  float acc0 = 0.f, acc1 = 0.f, acc2 = 0.f, acc3 = 0.f;
  const int starts[3] = {0, 576, 2880};
  const int Ls[3] = {24, 48, 96};
#pragma unroll
  for (int l = 0; l < 3; ++l) {
    const int Wl = Ls[l];
    const float fW = (float)Wl;
    const bhalf* vb = value + (long long)(bbase + starts[l]) * 256 + c0;
#pragma unroll
    for (int p = 0; p < 4; ++p) {
      const float ox = offp[l * 8 + p * 2], oy = offp[l * 8 + p * 2 + 1];
      const float a = aw[l * 4 + p] * sinv;
      const float x = (rx + ox / fW) * fW - 0.5f;
      const float y = (ry + oy / fW) * fW - 0.5f;
      const float x0f = floorf(x), y0f = floorf(y);
      const float wx = x - x0f, wy = y - y0f;
      const int x0 = (int)x0f, y0 = (int)y0f;
      const int x1 = x0 + 1, y1 = y0 + 1;
      const bool xv0 = (x0 >= 0) & (x0 < Wl);
      const bool xv1 = (x1 >= 0) & (x1 < Wl);
      const bool yv0 = (y0 >= 0) & (y0 < Wl);
      const bool yv1 = (y1 >= 0) & (y1 < Wl);
      const int cx0 = min(max(x0, 0), Wl - 1), cx1 = min(max(x1, 0), Wl - 1);
      const int cy0 = min(max(y0, 0), Wl - 1), cy1 = min(max(y1, 0), Wl - 1);
      const float w00 = (xv0 && yv0) ? (1.f - wx) * (1.f - wy) * a : 0.f;
      const float w01 = (xv1 && yv0) ? wx * (1.f - wy) * a : 0.f;
      const float w10 = (xv0 && yv1) ? (1.f - wx) * wy * a : 0.f;
      const float w11 = (xv1 && yv1) ? wx * wy * a : 0.f;
      const bh4 g00 = *(const bh4*)(vb + (cy0 * Wl + cx0) * 256);
      const bh4 g01 = *(const bh4*)(vb + (cy0 * Wl + cx1) * 256);
      const bh4 g10 = *(const bh4*)(vb + (cy1 * Wl + cx0) * 256);
      const bh4 g11 = *(const bh4*)(vb + (cy1 * Wl + cx1) * 256);
      acc0 = fmaf(w00, (float)g00[0], fmaf(w01, (float)g01[0], fmaf(w10, (float)g10[0], fmaf(w11, (float)g11[0], acc0))));
      acc1 = fmaf(w00, (float)g00[1], fmaf(w01, (float)g01[1], fmaf(w10, (float)g10[1], fmaf(w11, (float)g11[1], acc1))));
      acc2 = fmaf(w00, (float)g00[2], fmaf(w01, (float)g01[2], fmaf(w10, (float)g10[2], fmaf(w11, (float)g11[2], acc2))));
      acc3 = fmaf(w00, (float)g00[3], fmaf(w01, (float)g01[3], fmaf(w10, (float)g10[3], fmaf(w11, (float)g11[3], acc3))));
    }
  }
  bh4 o;
  o[0] = (bhalf)acc0; o[1] = (bhalf)acc1; o[2] = (bhalf)acc2; o[3] = (bhalf)acc3;
  *(bh4*)(out + (long long)bi * 256 + c0) = o;
}

// =====================================================================
// src[b][startRow+hw][c] -> out[b][c][hw]
// =====================================================================
__global__ void transpose_out_kernel(const float* __restrict__ src, float* __restrict__ out,
    int HW, int startRow)
{
  __shared__ float tile[32][33];
  int b = blockIdx.z;
  int w0 = blockIdx.x * 32, c0 = blockIdx.y * 32;
#pragma unroll
  for (int j = 0; j < 4; ++j) {
    int wl = threadIdx.y + 8 * j;
    tile[wl][threadIdx.x] = src[((long long)b * NLEN + startRow + w0 + wl) * 256 + c0 + threadIdx.x];
  }
  __syncthreads();
#pragma unroll
  for (int j = 0; j < 4; ++j) {
    int cl = threadIdx.y + 8 * j;
    out[((long long)b * 256 + c0 + cl) * HW + w0 + threadIdx.x] = tile[threadIdx.x][cl];
  }
}

// =====================================================================
// latb = GN(lat) + upsample2x(src lvl2), zero-padded layout
// =====================================================================
__global__ void lat_finish_rm_kernel(const bhalf* __restrict__ lat, const float* __restrict__ stats,
    const float* __restrict__ gs, const float* __restrict__ gb,
    const float* __restrict__ src, bhalf* __restrict__ latb)
{
  long long idx = (long long)blockIdx.x * 256 + threadIdx.x;
  int c = threadIdx.x & 255;
  long long row = idx >> 8;
  int b = (int)(row / 36864);
  int p = (int)(row - (long long)b * 36864);
  int y = p / 192, x = p % 192;
  int g = c >> 3;
  float v = (float)lat[idx];
  v = (v - stats[(b * 32 + g) * 2]) * stats[(b * 32 + g) * 2 + 1] * gs[c] + gb[c];
  float ys = fmaxf(y * 0.5f - 0.25f, 0.f);
  float xs = fmaxf(x * 0.5f - 0.25f, 0.f);
  int y0 = (int)ys; float wy = ys - (float)y0; int y1 = min(y0 + 1, 95);
  int x0 = (int)xs; float wx = xs - (float)x0; int x1 = min(x0 + 1, 95);
  const float* sp = src + ((long long)b * NLEN + 2880) * 256 + c;
  float r0 = sp[(long long)(y0 * 96 + x0) * 256] * (1.f - wx) + sp[(long long)(y0 * 96 + x1) * 256] * wx;
  float r1 = sp[(long long)(y1 * 96 + x0) * 256] * (1.f - wx) + sp[(long long)(y1 * 96 + x1) * 256] * wx;
  latb[((long long)b * 37636 + (long long)(y + 1) * 194 + (x + 1)) * 256 + c]
      = (bhalf)(v + r0 * (1.f - wy) + r1 * wy);
}

// =====================================================================
// Final GN+ReLU+transpose: convC bf16 [b][hw][c] -> Y fp32 [b][c][hw]
// =====================================================================
__global__ void gn_relu_tr_kernel(const bhalf* __restrict__ convC, const float* __restrict__ stats,
    const float* __restrict__ gs, const float* __restrict__ gb, float* __restrict__ Y)
{
  __shared__ float tile[32][33];
  int b = blockIdx.z;
  int hw0 = blockIdx.x * 32, c0 = blockIdx.y * 32;
#pragma unroll
  for (int j = 0; j < 4; ++j) {
    int hwl = threadIdx.y + 8 * j;
    int c = c0 + threadIdx.x;
    int g = c >> 3;
    float v = (float)convC[((long long)b * 36864 + hw0 + hwl) * 256 + c];
    v = (v - stats[(b * 32 + g) * 2]) * stats[(b * 32 + g) * 2 + 1] * gs[c] + gb[c];
    tile[hwl][threadIdx.x] = fmaxf(v, 0.f);
  }
  __syncthreads();
#pragma unroll
  for (int j = 0; j < 4; ++j) {
    int cl = threadIdx.y + 8 * j;
    Y[((long long)b * 256 + c0 + cl) * 36864 + hw0 + threadIdx.x] = tile[threadIdx.x][cl];
  }
}

// =====================================================================
extern "C" void kernel_launch(void* const* d_in, const int* in_sizes, int n_in,
                              void* d_out, int out_size, void* d_ws, size_t ws_size,
                              hipStream_t stream)
{
  const float* res2 = (const float*)d_in[0];
  const float* res3 = (const float*)d_in[1];
  const float* res4 = (const float*)d_in[2];
  const float* res5 = (const float*)d_in[3];
  const float* pw[3]  = {(const float*)d_in[4],  (const float*)d_in[8],  (const float*)d_in[12]};
  const float* pb[3]  = {(const float*)d_in[5],  (const float*)d_in[9],  (const float*)d_in[13]};
  const float* gss[3] = {(const float*)d_in[6],  (const float*)d_in[10], (const float*)d_in[14]};
  const float* gbb[3] = {(const float*)d_in[7],  (const float*)d_in[11], (const float*)d_in[15]};
  const float* level_embed = (const float*)d_in[16];
  const float* off_w = (const float*)d_in[17];
  const float* off_b = (const float*)d_in[18];
  const float* aw_w  = (const float*)d_in[19];
  const float* aw_b  = (const float*)d_in[20];
  const float* val_w = (const float*)d_in[21];
  const float* val_b = (const float*)d_in[22];
  const float* out_w = (const float*)d_in[23];
  const float* out_b = (const float*)d_in[24];
  const float* ln1_s = (const float*)d_in[25];
  const float* ln1_b = (const float*)d_in[26];
  const float* ffn1_w = (const float*)d_in[27];
  const float* ffn1_b = (const float*)d_in[28];
  const float* ffn2_w = (const float*)d_in[29];
  const float* ffn2_b = (const float*)d_in[30];
  const float* ln2_s = (const float*)d_in[31];
  const float* ln2_b = (const float*)d_in[32];
  const float* lat_w = (const float*)d_in[33];
  const float* lat_gs = (const float*)d_in[34];
  const float* lat_gb = (const float*)d_in[35];
  const float* fpn_w = (const float*)d_in[36];
  const float* fpn_gs = (const float*)d_in[37];
  const float* fpn_gb = (const float*)d_in[38];

  char* W = (char*)d_ws;
  float* src   = (float*)(W + 0);
  float* pos   = (float*)(W + 24772608LL);
  float* tmp   = (float*)(W + 37158912LL);
  bhalf* srcb  = (bhalf*)(W + 61931520LL);
  bhalf* wreg  = (bhalf*)(W + 74317824LL);
  float* stats = (float*)(W + 86212608LL);
  char*  U     = W + 86213120LL;

  bhalf* valT  = wreg + 0;
  bhalf* offT  = wreg + 393216;
  bhalf* awT   = wreg + 688128;
  bhalf* outT  = wreg + 835584;
  bhalf* f1T   = wreg + 1228800;
  bhalf* f2T   = wreg + 2801664;
  bhalf* pwb5  = wreg + 4374528;
  bhalf* pwb4  = wreg + 4898816;
  bhalf* pwb3  = wreg + 5160960;
  bhalf* latwb = wreg + 5292032;
  bhalf* fpnT  = wreg + 5357568;

  bhalf* qb      = (bhalf*)(U + 0);
  bhalf* valueb  = (bhalf*)(U + 12386304LL);
  bhalf* sampb   = (bhalf*)(U + 24772608LL);
  float* offbuf  = (float*)(U + 37158912LL);
  float* awbuf   = (float*)(U + 55738368LL);
  bhalf* hbuf    = (bhalf*)(U + 65028096LL);
  bhalf* featT   = (bhalf*)(U + 0);
  bhalf* res2T   = (bhalf*)(U + 0);
  bhalf* latbf   = (bhalf*)(U + 37748736LL);
  bhalf* latb    = (bhalf*)(U + 75497472LL);

  float* Yout = (float*)d_out;
  float* out0 = Yout + 18874368LL;
  float* out1 = Yout + 19169280LL;
  float* out2 = Yout + 20348928LL;

  const int M = BB * NLEN;  // 24192

  // ---- weight prep ----
  twcvt_kernel<<<dim3(8, 8, 6), dim3(32, 8), 0, stream>>>(val_w, valT, 256, 256);
  twcvt_kernel<<<dim3(6, 8, 6), dim3(32, 8), 0, stream>>>(off_w, offT, 256, 192);
  twcvt_kernel<<<dim3(3, 8, 6), dim3(32, 8), 0, stream>>>(aw_w, awT, 256, 96);
  twcvt_kernel<<<dim3(8, 8, 6), dim3(32, 8), 0, stream>>>(out_w, outT, 256, 256);
  twcvt_kernel<<<dim3(32, 8, 6), dim3(32, 8), 0, stream>>>(ffn1_w, f1T, 256, 1024);
  twcvt_kernel<<<dim3(8, 32, 6), dim3(32, 8), 0, stream>>>(ffn2_w, f2T, 1024, 256);
  cvt_kernel<<<dim3(2048), dim3(256), 0, stream>>>(pw[0], pwb5, 524288);
  cvt_kernel<<<dim3(1024), dim3(256), 0, stream>>>(pw[1], pwb4, 262144);
  cvt_kernel<<<dim3(512),  dim3(256), 0, stream>>>(pw[2], pwb3, 131072);
  cvt_kernel<<<dim3(256),  dim3(256), 0, stream>>>(lat_w, latwb, 65536);
  fpnw_kernel<<<dim3(2304), dim3(256), 0, stream>>>(fpn_w, fpnT);

  // ---- positional embedding ----
  pos_kernel<<<dim3(NLEN), dim3(256), 0, stream>>>(pos, level_embed);

  // ---- input projections + GN -> src/srcb ----
  const float* feats[3] = {res5, res4, res3};
  const bhalf* pwbs[3] = {pwb5, pwb4, pwb3};
  const int cins[3] = {2048, 1024, 512};
  const int HWs[3] = {576, 2304, 9216};
  const int startsHost[3] = {0, 576, 2880};
  for (int lvl = 0; lvl < 3; ++lvl) {
    int HW = HWs[lvl], cin = cins[lvl];
    tfeat_kernel<<<dim3(HW / 32, cin / 32, BB), dim3(32, 8), 0, stream>>>(feats[lvl], featT, cin, HW);
    bgemm_kernel<<<dim3(2, (HW + 127) / 128, BB), dim3(256), 0, stream>>>(
        featT, pwbs[lvl], pb[lvl], tmp, HW, 256, cin,
        (long long)HW * cin, 0LL, (long long)HW * 256, 0, 0);
    gn_stats_rm_kernel<<<dim3(64), dim3(256), 0, stream>>>(tmp, stats, HW, 0);
    gn_apply_rm_kernel<<<dim3(BB * HW), dim3(256), 0, stream>>>(
        tmp, stats, gss[lvl], gbb[lvl], src, srcb, HW, startsHost[lvl]);
  }

  // ---- 6 encoder layers ----
  for (int l = 0; l < 6; ++l) {
    qb_kernel<<<dim3(M), dim3(256), 0, stream>>>(src, pos, qb);
    bgemm_kernel<<<dim3(2, M / 128, 1), dim3(256), 0, stream>>>(
        srcb, valT + (long long)l * 65536, val_b + l * 256, valueb,
        M, 256, 256, 0LL, 0LL, 0LL, 1, 0);
    bgemm_kernel<<<dim3(2, M / 128, 1), dim3(256), 0, stream>>>(
        qb, offT + (long long)l * 49152, off_b + l * 192, offbuf,
        M, 192, 256, 0LL, 0LL, 0LL, 0, 0);
    bgemm_kernel<<<dim3(1, M / 128, 1), dim3(256), 0, stream>>>(
        qb, awT + (long long)l * 24576, aw_b + l * 96, awbuf,
        M, 96, 256, 0LL, 0LL, 0LL, 0, 0);
    deform_kernel<<<dim3(M / 4), dim3(256), 0, stream>>>(valueb, offbuf, awbuf, sampb);
    bgemm_kernel<<<dim3(2, M / 128, 1), dim3(256), 0, stream>>>(
        sampb, outT + (long long)l * 65536, out_b + l * 256, tmp,
        M, 256, 256, 0LL, 0LL, 0LL, 0, 0);
    ln_kernel<<<dim3(M), dim3(256), 0, stream>>>(src, tmp, ln1_s + l * 256, ln1_b + l * 256, srcb);
    bgemm_kernel<<<dim3(8, M / 128, 1), dim3(256), 0, stream>>>(
        srcb, f1T + (long long)l * 262144, ffn1_b + l * 1024, hbuf,
        M, 1024, 256, 0LL, 0LL, 0LL, 1, 1);
    bgemm_kernel<<<dim3(2, M / 128, 1), dim3(256), 0, stream>>>(
        hbuf, f2T + (long long)l * 262144, ffn2_b + l * 256, tmp,
        M, 256, 1024, 0LL, 0LL, 0LL, 0, 0);
    ln_kernel<<<dim3(M), dim3(256), 0, stream>>>(src, tmp, ln2_s + l * 256, ln2_b + l * 256, srcb);
  }

  // ---- output transposes ----
  float* outsPtr[3] = {out0, out1, out2};
  for (int lvl = 0; lvl < 3; ++lvl) {
    transpose_out_kernel<<<dim3(HWs[lvl] / 32, 8, BB), dim3(32, 8), 0, stream>>>(
        src, outsPtr[lvl], HWs[lvl], startsHost[lvl]);
  }

  // ---- FPN ----
  tfeat_kernel<<<dim3(1152, 8, BB), dim3(32, 8), 0, stream>>>(res2, res2T, 256, 36864);
  bgemm_kernel<<<dim3(2, 288, BB), dim3(256), 0, stream>>>(
      res2T, latwb, nullptr, latbf, 36864, 256, 256,
      36864LL * 256, 0LL, 36864LL * 256, 1, 0);
  gn_stats_rm_kernel<<<dim3(64), dim3(256), 0, stream>>>(latbf, stats, 36864, 1);
  zero16_kernel<<<dim3(9410), dim3(256), 0, stream>>>((uint4*)latb, 2408704LL);
  lat_finish_rm_kernel<<<dim3(73728), dim3(256), 0, stream>>>(latbf, stats, lat_gs, lat_gb, src, latb);
  bgemm_conv_kernel<<<dim3(2, 288, BB), dim3(256), 0, stream>>>(latb, fpnT, latbf);
  gn_stats_rm_kernel<<<dim3(64), dim3(256), 0, stream>>>(latbf, stats, 36864, 1);
  gn_relu_tr_kernel<<<dim3(1152, 8, BB), dim3(32, 8), 0, stream>>>(latbf, stats, fpn_gs, fpn_gb, Yout);
}

// Round 4
// 2519.171 us; speedup vs baseline: 3.1989x; 1.2921x over previous
//
#include <hip/hip_runtime.h>
#include <math.h>

#define NLEN 12096
#define BB 2

typedef __bf16 bhalf;
typedef bhalf bh8 __attribute__((ext_vector_type(8)));
typedef bhalf bh4 __attribute__((ext_vector_type(4)));
typedef float f32x4 __attribute__((ext_vector_type(4)));

// =====================================================================
// bf16 MFMA GEMM: C[M,N] = A[M,K] @ Bt[N,K]^T  (+bias[n]) (+relu)
// =====================================================================
__global__ __launch_bounds__(256) void bgemm_kernel(
    const bhalf* __restrict__ A, const bhalf* __restrict__ Bt,
    const float* __restrict__ bias, void* __restrict__ Cout,
    int M, int N, int K, long long sA, long long sB, long long sC,
    int outBf16, int relu)
{
  const int bz = blockIdx.z;
  A += bz * sA; Bt += bz * sB;
  const int m0 = blockIdx.y * 128, n0 = blockIdx.x * 128;
  __shared__ __align__(16) bhalf As[128 * 32];
  __shared__ __align__(16) bhalf Bs[128 * 32];
  const int t = threadIdx.x;
  const int lane = t & 63;
  const int w = t >> 6;
  const int wm = (w >> 1) * 64, wn = (w & 1) * 64;
  const int fr = lane & 15, fg = lane >> 4;
  f32x4 acc[4][4] = {};
  for (int k0 = 0; k0 < K; k0 += 32) {
#pragma unroll
    for (int j = 0; j < 2; ++j) {
      int id = t + j * 256;
      int row = id >> 2, kc = (id & 3) * 8;
      uint4 av = make_uint4(0u, 0u, 0u, 0u);
      int m = m0 + row;
      if (m < M) av = *(const uint4*)(A + (long long)m * K + k0 + kc);
      *(uint4*)(As + row * 32 + kc) = av;
      uint4 bv = make_uint4(0u, 0u, 0u, 0u);
      int n = n0 + row;
      if (n < N) bv = *(const uint4*)(Bt + (long long)n * K + k0 + kc);
      *(uint4*)(Bs + row * 32 + kc) = bv;
    }
    __syncthreads();
    bh8 af[4], bf[4];
#pragma unroll
    for (int mi = 0; mi < 4; ++mi)
      af[mi] = *(const bh8*)(As + (wm + mi * 16 + fr) * 32 + fg * 8);
#pragma unroll
    for (int ni = 0; ni < 4; ++ni)
      bf[ni] = *(const bh8*)(Bs + (wn + ni * 16 + fr) * 32 + fg * 8);
#pragma unroll
    for (int mi = 0; mi < 4; ++mi)
#pragma unroll
      for (int ni = 0; ni < 4; ++ni)
        acc[mi][ni] = __builtin_amdgcn_mfma_f32_16x16x32_bf16(af[mi], bf[ni], acc[mi][ni], 0, 0, 0);
    __syncthreads();
  }
  float* Cf = (float*)Cout + bz * sC;
  bhalf* Cb = (bhalf*)Cout + bz * sC;
#pragma unroll
  for (int mi = 0; mi < 4; ++mi) {
#pragma unroll
    for (int r = 0; r < 4; ++r) {
      int m = m0 + wm + mi * 16 + fg * 4 + r;
      if (m >= M) continue;
#pragma unroll
      for (int ni = 0; ni < 4; ++ni) {
        int n = n0 + wn + ni * 16 + fr;
        if (n >= N) continue;
        float v = acc[mi][ni][r];
        if (bias) v += bias[n];
        if (relu) v = fmaxf(v, 0.f);
        if (outBf16) Cb[(long long)m * N + n] = (bhalf)v;
        else         Cf[(long long)m * N + n] = v;
      }
    }
  }
}

// =====================================================================
// Implicit-GEMM 3x3 conv: C[M=36864,N=256] per batch, K = 9*256.
// =====================================================================
__global__ __launch_bounds__(256) void bgemm_conv_kernel(
    const bhalf* __restrict__ Ab, const bhalf* __restrict__ Bt,
    bhalf* __restrict__ Cout)
{
  const int bz = blockIdx.z;
  const bhalf* Apad = Ab + (long long)bz * 37636 * 256;
  const int m0 = blockIdx.y * 128, n0 = blockIdx.x * 128;
  __shared__ __align__(16) bhalf As[128 * 32];
  __shared__ __align__(16) bhalf Bs[128 * 32];
  const int t = threadIdx.x;
  const int lane = t & 63;
  const int w = t >> 6;
  const int wm = (w >> 1) * 64, wn = (w & 1) * 64;
  const int fr = lane & 15, fg = lane >> 4;
  int rowA[2], py[2], px[2];
#pragma unroll
  for (int j = 0; j < 2; ++j) {
    int id = t + j * 256;
    rowA[j] = id >> 2;
    int m = m0 + rowA[j];
    py[j] = m / 192; px[j] = m % 192;
  }
  f32x4 acc[4][4] = {};
  for (int k0 = 0; k0 < 2304; k0 += 32) {
    int tap = k0 >> 8;
    int ty = tap / 3, tx = tap % 3;
    int cik = k0 & 255;
#pragma unroll
    for (int j = 0; j < 2; ++j) {
      int id = t + j * 256;
      int kc = (id & 3) * 8;
      uint4 av = *(const uint4*)(Apad + ((long long)(py[j] + ty) * 194 + px[j] + tx) * 256 + cik + kc);
      *(uint4*)(As + rowA[j] * 32 + kc) = av;
      uint4 bv = *(const uint4*)(Bt + (long long)(n0 + rowA[j]) * 2304 + k0 + kc);
      *(uint4*)(Bs + rowA[j] * 32 + kc) = bv;
    }
    __syncthreads();
    bh8 af[4], bf[4];
#pragma unroll
    for (int mi = 0; mi < 4; ++mi)
      af[mi] = *(const bh8*)(As + (wm + mi * 16 + fr) * 32 + fg * 8);
#pragma unroll
    for (int ni = 0; ni < 4; ++ni)
      bf[ni] = *(const bh8*)(Bs + (wn + ni * 16 + fr) * 32 + fg * 8);
#pragma unroll
    for (int mi = 0; mi < 4; ++mi)
#pragma unroll
      for (int ni = 0; ni < 4; ++ni)
        acc[mi][ni] = __builtin_amdgcn_mfma_f32_16x16x32_bf16(af[mi], bf[ni], acc[mi][ni], 0, 0, 0);
    __syncthreads();
  }
  bhalf* Cb = Cout + (long long)bz * 36864 * 256;
#pragma unroll
  for (int mi = 0; mi < 4; ++mi)
#pragma unroll
    for (int r = 0; r < 4; ++r) {
      int m = m0 + wm + mi * 16 + fg * 4 + r;
#pragma unroll
      for (int ni = 0; ni < 4; ++ni) {
        int n = n0 + wn + ni * 16 + fr;
        Cb[(long long)m * 256 + n] = (bhalf)acc[mi][ni][r];
      }
    }
}

// =====================================================================
// Weight transpose+convert
// =====================================================================
__global__ void twcvt_kernel(const float* __restrict__ Wsrc, bhalf* __restrict__ out,
                             int Kd, int Nd)
{
  __shared__ float tile[32][33];
  long long zo = (long long)blockIdx.z * Kd * Nd;
  int n0 = blockIdx.x * 32, k0 = blockIdx.y * 32;
#pragma unroll
  for (int j = 0; j < 4; ++j) {
    int kk = threadIdx.y + 8 * j;
    tile[kk][threadIdx.x] = Wsrc[zo + (long long)(k0 + kk) * Nd + n0 + threadIdx.x];
  }
  __syncthreads();
#pragma unroll
  for (int j = 0; j < 4; ++j) {
    int nn = threadIdx.y + 8 * j;
    out[zo + (long long)(n0 + nn) * Kd + k0 + threadIdx.x] = (bhalf)tile[threadIdx.x][nn];
  }
}

__global__ void tfeat_kernel(const float* __restrict__ Fsrc, bhalf* __restrict__ out,
                             int Ci, int HW)
{
  __shared__ float tile[32][33];
  long long zo = (long long)blockIdx.z * Ci * HW;
  int hw0 = blockIdx.x * 32, c0 = blockIdx.y * 32;
#pragma unroll
  for (int j = 0; j < 4; ++j) {
    int cc = threadIdx.y + 8 * j;
    tile[cc][threadIdx.x] = Fsrc[zo + (long long)(c0 + cc) * HW + hw0 + threadIdx.x];
  }
  __syncthreads();
#pragma unroll
  for (int j = 0; j < 4; ++j) {
    int hh = threadIdx.y + 8 * j;
    out[zo + (long long)(hw0 + hh) * Ci + c0 + threadIdx.x] = (bhalf)tile[threadIdx.x][hh];
  }
}

__global__ void cvt_kernel(const float* __restrict__ in, bhalf* __restrict__ out, int n)
{
  int i = blockIdx.x * 256 + threadIdx.x;
  if (i < n) out[i] = (bhalf)in[i];
}

__global__ void fpnw_kernel(const float* __restrict__ Wsrc, bhalf* __restrict__ out)
{
  int o = blockIdx.x * 256 + threadIdx.x;
  if (o >= 256 * 2304) return;
  int co = o / 2304, r = o % 2304, tap = r >> 8, ci = r & 255;
  out[o] = (bhalf)Wsrc[(co * 256 + ci) * 9 + tap];
}

__global__ void zero16_kernel(uint4* __restrict__ p, long long n16)
{
  long long i = (long long)blockIdx.x * 256 + threadIdx.x;
  if (i < n16) p[i] = make_uint4(0u, 0u, 0u, 0u);
}

// =====================================================================
// Sine positional embedding + level embed
// =====================================================================
__global__ void pos_kernel(float* __restrict__ pos, const float* __restrict__ level_embed)
{
  int i = blockIdx.x, c = threadIdx.x;
  int lvl, Wq, loc;
  if (i < 576)       { lvl = 0; Wq = 24; loc = i; }
  else if (i < 2880) { lvl = 1; Wq = 48; loc = i - 576; }
  else               { lvl = 2; Wq = 96; loc = i - 2880; }
  int h = loc / Wq, wcol = loc % Wq;
  int cc = c & 127;
  float coord = (c < 128) ? (float)(h + 1) : (float)(wcol + 1);
  float denom = (float)Wq + 1e-6f;
  float v = coord / denom * 6.28318530717958647692f;
  float tp = powf(10000.0f, (float)(cc & ~1) * (1.0f / 128.0f));
  float ang = v / tp;
  float val = (cc & 1) ? cosf(ang) : sinf(ang);
  pos[(long long)i * 256 + c] = val + level_embed[lvl * 256 + c];
}

// =====================================================================
// GN stats, two-pass, coalesced. X row-major [B][HW][256].
// Pass 1: grid (nch, B), block 256. Lane covers one 8-ch group,
// 32 B contiguous per lane -> fully coalesced row streams.
// part[(b*32+g)*nch + ch] = {sum, sumsq} over chunk rows x 8 ch.
// =====================================================================
__global__ __launch_bounds__(256) void gn_part_kernel(const void* __restrict__ X,
    float* __restrict__ part, int HW, int isBf16, int nch)
{
  const int b = blockIdx.y, ch = blockIdx.x;
  const int rows = (HW + nch - 1) / nch;
  const int r0 = ch * rows;
  const int r1 = min(r0 + rows, HW);
  const int cg = threadIdx.x & 31;   // channel group 0..31
  const int ro = threadIdx.x >> 5;   // row offset 0..7
  float s = 0.f, s2 = 0.f;
  if (isBf16) {
    const bhalf* p = (const bhalf*)X + (long long)b * HW * 256 + cg * 8;
    for (int r = r0 + ro; r < r1; r += 8) {
      bh8 v = *(const bh8*)(p + (long long)r * 256);
#pragma unroll
      for (int j = 0; j < 8; ++j) { float f = (float)v[j]; s += f; s2 = fmaf(f, f, s2); }
    }
  } else {
    const float* p = (const float*)X + (long long)b * HW * 256 + cg * 8;
    for (int r = r0 + ro; r < r1; r += 8) {
      f32x4 v0 = *(const f32x4*)(p + (long long)r * 256);
      f32x4 v1 = *(const f32x4*)(p + (long long)r * 256 + 4);
#pragma unroll
      for (int j = 0; j < 4; ++j) { s += v0[j]; s2 = fmaf(v0[j], v0[j], s2); }
#pragma unroll
      for (int j = 0; j < 4; ++j) { s += v1[j]; s2 = fmaf(v1[j], v1[j], s2); }
    }
  }
  __shared__ float sh[2][8][32];
  sh[0][ro][cg] = s; sh[1][ro][cg] = s2;
  __syncthreads();
  if (threadIdx.x < 32) {
    float S = 0.f, S2 = 0.f;
#pragma unroll
    for (int k = 0; k < 8; ++k) { S += sh[0][k][threadIdx.x]; S2 += sh[1][k][threadIdx.x]; }
    long long o = ((long long)(b * 32 + threadIdx.x) * nch + ch) * 2;
    part[o] = S; part[o + 1] = S2;
  }
}

// Pass 2: grid 64 (b*32+g), block 64. Reduce nch partials -> mean/rstd.
__global__ __launch_bounds__(64) void gn_fin_kernel(const float* __restrict__ part,
    float* __restrict__ stats, int nch, int HW)
{
  const int bg = blockIdx.x;
  float s = 0.f, s2 = 0.f;
  for (int i = threadIdx.x; i < nch; i += 64) {
    long long o = ((long long)bg * nch + i) * 2;
    s += part[o]; s2 += part[o + 1];
  }
#pragma unroll
  for (int o = 32; o > 0; o >>= 1) { s += __shfl_down(s, o); s2 += __shfl_down(s2, o); }
  if (threadIdx.x == 0) {
    float inv = 1.f / (float)(HW * 8);
    float mean = s * inv;
    float var = s2 * inv - mean * mean;
    stats[bg * 2] = mean;
    stats[bg * 2 + 1] = rsqrtf(var + 1e-5f);
  }
}

// =====================================================================
// GN apply on tmp [B][HW][256] fp32 -> src rows fp32 + srcb bf16
// =====================================================================
__global__ void gn_apply_rm_kernel(const float* __restrict__ T, const float* __restrict__ stats,
    const float* __restrict__ gs, const float* __restrict__ gb,
    float* __restrict__ src, bhalf* __restrict__ srcb, int HW, int startRow)
{
  long long idx = (long long)blockIdx.x * 256 + threadIdx.x;
  int c = threadIdx.x & 255;
  long long row = idx >> 8;
  int b = (int)(row / HW);
  long long hw = row - (long long)b * HW;
  int g = c >> 3;
  float v = T[idx];
  v = (v - stats[(b * 32 + g) * 2]) * stats[(b * 32 + g) * 2 + 1] * gs[c] + gb[c];
  long long o = ((long long)b * NLEN + startRow + hw) * 256 + c;
  src[o] = v;
  srcb[o] = (bhalf)v;
}

// qb = bf16(src + pos)
__global__ void qb_kernel(const float* __restrict__ src, const float* __restrict__ pos,
                          bhalf* __restrict__ qb)
{
  long long idx = (long long)blockIdx.x * 256 + threadIdx.x;
  long long row = idx >> 8;
  int pr = (int)(row % NLEN);
  qb[idx] = (bhalf)(src[idx] + pos[(long long)pr * 256 + (idx & 255)]);
}

// =====================================================================
// src = LayerNorm(src + resid); also writes srcb bf16
// =====================================================================
__global__ __launch_bounds__(256) void ln_kernel(float* __restrict__ src,
    const float* __restrict__ resid, const float* __restrict__ s, const float* __restrict__ bsh,
    bhalf* __restrict__ srcb)
{
  long long r = blockIdx.x;
  int c = threadIdx.x;
  float v = src[r * 256 + c] + resid[r * 256 + c];
  float sum = v, sq = v * v;
#pragma unroll
  for (int o = 32; o > 0; o >>= 1) { sum += __shfl_down(sum, o); sq += __shfl_down(sq, o); }
  __shared__ float sh[2][4];
  int lane = c & 63, wv = c >> 6;
  if (lane == 0) { sh[0][wv] = sum; sh[1][wv] = sq; }
  __syncthreads();
  float S  = sh[0][0] + sh[0][1] + sh[0][2] + sh[0][3];
  float S2 = sh[1][0] + sh[1][1] + sh[1][2] + sh[1][3];
  float mean = S * (1.f / 256.f);
  float var = S2 * (1.f / 256.f) - mean * mean;
  float rstd = rsqrtf(var + 1e-5f);
  float y = (v - mean) * rstd * s[c] + bsh[c];
  src[r * 256 + c] = y;
  srcb[r * 256 + c] = (bhalf)y;
}

// =====================================================================
// MSDeformAttn sampling, wave-per-query, 4 channels/lane, fused softmax.
// =====================================================================
__global__ __launch_bounds__(256) void deform_kernel(const bhalf* __restrict__ value,
    const float* __restrict__ offb, const float* __restrict__ awb, bhalf* __restrict__ out)
{
  const int wv = threadIdx.x >> 6;
  const int lane = threadIdx.x & 63;
  const int bi = blockIdx.x * 4 + wv;
  const int i = bi % NLEN;
  const int bbase = bi - i;
  const int c0 = lane * 4;
  const int head = lane >> 3;
  int loc, Wq;
  if (i < 576)       { Wq = 24; loc = i; }
  else if (i < 2880) { Wq = 48; loc = i - 576; }
  else               { Wq = 96; loc = i - 2880; }
  const float rx = ((loc % Wq) + 0.5f) / (float)Wq;
  const float ry = ((loc / Wq) + 0.5f) / (float)Wq;
  const float* offp = offb + (long long)bi * 192 + head * 24;
  const float* awp  = awb  + (long long)bi * 96  + head * 12;
  float aw[12]; float mx = -1e30f;
#pragma unroll
  for (int j = 0; j < 12; ++j) { aw[j] = awp[j]; mx = fmaxf(mx, aw[j]); }
  float ssum = 0.f;
#pragma unroll
  for (int j = 0; j < 12; ++j) { aw[j] = __expf(aw[j] - mx); ssum += aw[j]; }
  const float sinv = 1.f / ssum;
  float acc0 = 0.f, acc1 = 0.f, acc2 = 0.f, acc3 = 0.f;
  const int starts[3] = {0, 576, 2880};
  const int Ls[3] = {24, 48, 96};
#pragma unroll
  for (int l = 0; l < 3; ++l) {
    const int Wl = Ls[l];
    const float fW = (float)Wl;
    const bhalf* vb = value + (long long)(bbase + starts[l]) * 256 + c0;
#pragma unroll
    for (int p = 0; p < 4; ++p) {
      const float ox = offp[l * 8 + p * 2], oy = offp[l * 8 + p * 2 + 1];
      const float a = aw[l * 4 + p] * sinv;
      const float x = (rx + ox / fW) * fW - 0.5f;
      const float y = (ry + oy / fW) * fW - 0.5f;
      const float x0f = floorf(x), y0f = floorf(y);
      const float wx = x - x0f, wy = y - y0f;
      const int x0 = (int)x0f, y0 = (int)y0f;
      const int x1 = x0 + 1, y1 = y0 + 1;
      const bool xv0 = (x0 >= 0) & (x0 < Wl);
      const bool xv1 = (x1 >= 0) & (x1 < Wl);
      const bool yv0 = (y0 >= 0) & (y0 < Wl);
      const bool yv1 = (y1 >= 0) & (y1 < Wl);
      const int cx0 = min(max(x0, 0), Wl - 1), cx1 = min(max(x1, 0), Wl - 1);
      const int cy0 = min(max(y0, 0), Wl - 1), cy1 = min(max(y1, 0), Wl - 1);
      const float w00 = (xv0 && yv0) ? (1.f - wx) * (1.f - wy) * a : 0.f;
      const float w01 = (xv1 && yv0) ? wx * (1.f - wy) * a : 0.f;
      const float w10 = (xv0 && yv1) ? (1.f - wx) * wy * a : 0.f;
      const float w11 = (xv1 && yv1) ? wx * wy * a : 0.f;
      const bh4 g00 = *(const bh4*)(vb + (cy0 * Wl + cx0) * 256);
      const bh4 g01 = *(const bh4*)(vb + (cy0 * Wl + cx1) * 256);
      const bh4 g10 = *(const bh4*)(vb + (cy1 * Wl + cx0) * 256);
      const bh4 g11 = *(const bh4*)(vb + (cy1 * Wl + cx1) * 256);
      acc0 = fmaf(w00, (float)g00[0], fmaf(w01, (float)g01[0], fmaf(w10, (float)g10[0], fmaf(w11, (float)g11[0], acc0))));
      acc1 = fmaf(w00, (float)g00[1], fmaf(w01, (float)g01[1], fmaf(w10, (float)g10[1], fmaf(w11, (float)g11[1], acc1))));
      acc2 = fmaf(w00, (float)g00[2], fmaf(w01, (float)g01[2], fmaf(w10, (float)g10[2], fmaf(w11, (float)g11[2], acc2))));
      acc3 = fmaf(w00, (float)g00[3], fmaf(w01, (float)g01[3], fmaf(w10, (float)g10[3], fmaf(w11, (float)g11[3], acc3))));
    }
  }
  bh4 o;
  o[0] = (bhalf)acc0; o[1] = (bhalf)acc1; o[2] = (bhalf)acc2; o[3] = (bhalf)acc3;
  *(bh4*)(out + (long long)bi * 256 + c0) = o;
}

// =====================================================================
// src[b][startRow+hw][c] -> out[b][c][hw]
// =====================================================================
__global__ void transpose_out_kernel(const float* __restrict__ src, float* __restrict__ out,
    int HW, int startRow)
{
  __shared__ float tile[32][33];
  int b = blockIdx.z;
  int w0 = blockIdx.x * 32, c0 = blockIdx.y * 32;
#pragma unroll
  for (int j = 0; j < 4; ++j) {
    int wl = threadIdx.y + 8 * j;
    tile[wl][threadIdx.x] = src[((long long)b * NLEN + startRow + w0 + wl) * 256 + c0 + threadIdx.x];
  }
  __syncthreads();
#pragma unroll
  for (int j = 0; j < 4; ++j) {
    int cl = threadIdx.y + 8 * j;
    out[((long long)b * 256 + c0 + cl) * HW + w0 + threadIdx.x] = tile[threadIdx.x][cl];
  }
}

// =====================================================================
// latb = GN(lat) + upsample2x(src lvl2), zero-padded layout
// =====================================================================
__global__ void lat_finish_rm_kernel(const bhalf* __restrict__ lat, const float* __restrict__ stats,
    const float* __restrict__ gs, const float* __restrict__ gb,
    const float* __restrict__ src, bhalf* __restrict__ latb)
{
  long long idx = (long long)blockIdx.x * 256 + threadIdx.x;
  int c = threadIdx.x & 255;
  long long row = idx >> 8;
  int b = (int)(row / 36864);
  int p = (int)(row - (long long)b * 36864);
  int y = p / 192, x = p % 192;
  int g = c >> 3;
  float v = (float)lat[idx];
  v = (v - stats[(b * 32 + g) * 2]) * stats[(b * 32 + g) * 2 + 1] * gs[c] + gb[c];
  float ys = fmaxf(y * 0.5f - 0.25f, 0.f);
  float xs = fmaxf(x * 0.5f - 0.25f, 0.f);
  int y0 = (int)ys; float wy = ys - (float)y0; int y1 = min(y0 + 1, 95);
  int x0 = (int)xs; float wx = xs - (float)x0; int x1 = min(x0 + 1, 95);
  const float* sp = src + ((long long)b * NLEN + 2880) * 256 + c;
  float r0 = sp[(long long)(y0 * 96 + x0) * 256] * (1.f - wx) + sp[(long long)(y0 * 96 + x1) * 256] * wx;
  float r1 = sp[(long long)(y1 * 96 + x0) * 256] * (1.f - wx) + sp[(long long)(y1 * 96 + x1) * 256] * wx;
  latb[((long long)b * 37636 + (long long)(y + 1) * 194 + (x + 1)) * 256 + c]
      = (bhalf)(v + r0 * (1.f - wy) + r1 * wy);
}

// =====================================================================
// Final GN+ReLU+transpose: convC bf16 [b][hw][c] -> Y fp32 [b][c][hw]
// =====================================================================
__global__ void gn_relu_tr_kernel(const bhalf* __restrict__ convC, const float* __restrict__ stats,
    const float* __restrict__ gs, const float* __restrict__ gb, float* __restrict__ Y)
{
  __shared__ float tile[32][33];
  int b = blockIdx.z;
  int hw0 = blockIdx.x * 32, c0 = blockIdx.y * 32;
#pragma unroll
  for (int j = 0; j < 4; ++j) {
    int hwl = threadIdx.y + 8 * j;
    int c = c0 + threadIdx.x;
    int g = c >> 3;
    float v = (float)convC[((long long)b * 36864 + hw0 + hwl) * 256 + c];
    v = (v - stats[(b * 32 + g) * 2]) * stats[(b * 32 + g) * 2 + 1] * gs[c] + gb[c];
    tile[hwl][threadIdx.x] = fmaxf(v, 0.f);
  }
  __syncthreads();
#pragma unroll
  for (int j = 0; j < 4; ++j) {
    int cl = threadIdx.y + 8 * j;
    Y[((long long)b * 256 + c0 + cl) * 36864 + hw0 + threadIdx.x] = tile[threadIdx.x][cl];
  }
}

// =====================================================================
extern "C" void kernel_launch(void* const* d_in, const int* in_sizes, int n_in,
                              void* d_out, int out_size, void* d_ws, size_t ws_size,
                              hipStream_t stream)
{
  const float* res2 = (const float*)d_in[0];
  const float* res3 = (const float*)d_in[1];
  const float* res4 = (const float*)d_in[2];
  const float* res5 = (const float*)d_in[3];
  const float* pw[3]  = {(const float*)d_in[4],  (const float*)d_in[8],  (const float*)d_in[12]};
  const float* pb[3]  = {(const float*)d_in[5],  (const float*)d_in[9],  (const float*)d_in[13]};
  const float* gss[3] = {(const float*)d_in[6],  (const float*)d_in[10], (const float*)d_in[14]};
  const float* gbb[3] = {(const float*)d_in[7],  (const float*)d_in[11], (const float*)d_in[15]};
  const float* level_embed = (const float*)d_in[16];
  const float* off_w = (const float*)d_in[17];
  const float* off_b = (const float*)d_in[18];
  const float* aw_w  = (const float*)d_in[19];
  const float* aw_b  = (const float*)d_in[20];
  const float* val_w = (const float*)d_in[21];
  const float* val_b = (const float*)d_in[22];
  const float* out_w = (const float*)d_in[23];
  const float* out_b = (const float*)d_in[24];
  const float* ln1_s = (const float*)d_in[25];
  const float* ln1_b = (const float*)d_in[26];
  const float* ffn1_w = (const float*)d_in[27];
  const float* ffn1_b = (const float*)d_in[28];
  const float* ffn2_w = (const float*)d_in[29];
  const float* ffn2_b = (const float*)d_in[30];
  const float* ln2_s = (const float*)d_in[31];
  const float* ln2_b = (const float*)d_in[32];
  const float* lat_w = (const float*)d_in[33];
  const float* lat_gs = (const float*)d_in[34];
  const float* lat_gb = (const float*)d_in[35];
  const float* fpn_w = (const float*)d_in[36];
  const float* fpn_gs = (const float*)d_in[37];
  const float* fpn_gb = (const float*)d_in[38];

  char* W = (char*)d_ws;
  float* src   = (float*)(W + 0);
  float* pos   = (float*)(W + 24772608LL);
  float* tmp   = (float*)(W + 37158912LL);
  bhalf* srcb  = (bhalf*)(W + 61931520LL);
  bhalf* wreg  = (bhalf*)(W + 74317824LL);
  float* stats = (float*)(W + 86212608LL);     // 512 B
  float* part  = (float*)(W + 86213120LL);     // 64*128*2*4 = 64 KiB
  char*  U     = W + 86278656LL;

  bhalf* valT  = wreg + 0;
  bhalf* offT  = wreg + 393216;
  bhalf* awT   = wreg + 688128;
  bhalf* outT  = wreg + 835584;
  bhalf* f1T   = wreg + 1228800;
  bhalf* f2T   = wreg + 2801664;
  bhalf* pwb5  = wreg + 4374528;
  bhalf* pwb4  = wreg + 4898816;
  bhalf* pwb3  = wreg + 5160960;
  bhalf* latwb = wreg + 5292032;
  bhalf* fpnT  = wreg + 5357568;

  bhalf* qb      = (bhalf*)(U + 0);
  bhalf* valueb  = (bhalf*)(U + 12386304LL);
  bhalf* sampb   = (bhalf*)(U + 24772608LL);
  float* offbuf  = (float*)(U + 37158912LL);
  float* awbuf   = (float*)(U + 55738368LL);
  bhalf* hbuf    = (bhalf*)(U + 65028096LL);
  bhalf* featT   = (bhalf*)(U + 0);
  bhalf* res2T   = (bhalf*)(U + 0);
  bhalf* latbf   = (bhalf*)(U + 37748736LL);
  bhalf* latb    = (bhalf*)(U + 75497472LL);

  float* Yout = (float*)d_out;
  float* out0 = Yout + 18874368LL;
  float* out1 = Yout + 19169280LL;
  float* out2 = Yout + 20348928LL;

  const int M = BB * NLEN;  // 24192

  // ---- weight prep ----
  twcvt_kernel<<<dim3(8, 8, 6), dim3(32, 8), 0, stream>>>(val_w, valT, 256, 256);
  twcvt_kernel<<<dim3(6, 8, 6), dim3(32, 8), 0, stream>>>(off_w, offT, 256, 192);
  twcvt_kernel<<<dim3(3, 8, 6), dim3(32, 8), 0, stream>>>(aw_w, awT, 256, 96);
  twcvt_kernel<<<dim3(8, 8, 6), dim3(32, 8), 0, stream>>>(out_w, outT, 256, 256);
  twcvt_kernel<<<dim3(32, 8, 6), dim3(32, 8), 0, stream>>>(ffn1_w, f1T, 256, 1024);
  twcvt_kernel<<<dim3(8, 32, 6), dim3(32, 8), 0, stream>>>(ffn2_w, f2T, 1024, 256);
  cvt_kernel<<<dim3(2048), dim3(256), 0, stream>>>(pw[0], pwb5, 524288);
  cvt_kernel<<<dim3(1024), dim3(256), 0, stream>>>(pw[1], pwb4, 262144);
  cvt_kernel<<<dim3(512),  dim3(256), 0, stream>>>(pw[2], pwb3, 131072);
  cvt_kernel<<<dim3(256),  dim3(256), 0, stream>>>(lat_w, latwb, 65536);
  fpnw_kernel<<<dim3(2304), dim3(256), 0, stream>>>(fpn_w, fpnT);

  // ---- positional embedding ----
  pos_kernel<<<dim3(NLEN), dim3(256), 0, stream>>>(pos, level_embed);

  // ---- input projections + GN -> src/srcb ----
  const float* feats[3] = {res5, res4, res3};
  const bhalf* pwbs[3] = {pwb5, pwb4, pwb3};
  const int cins[3] = {2048, 1024, 512};
  const int HWs[3] = {576, 2304, 9216};
  const int startsHost[3] = {0, 576, 2880};
  const int nchs[3] = {16, 64, 128};
  for (int lvl = 0; lvl < 3; ++lvl) {
    int HW = HWs[lvl], cin = cins[lvl], nch = nchs[lvl];
    tfeat_kernel<<<dim3(HW / 32, cin / 32, BB), dim3(32, 8), 0, stream>>>(feats[lvl], featT, cin, HW);
    bgemm_kernel<<<dim3(2, (HW + 127) / 128, BB), dim3(256), 0, stream>>>(
        featT, pwbs[lvl], pb[lvl], tmp, HW, 256, cin,
        (long long)HW * cin, 0LL, (long long)HW * 256, 0, 0);
    gn_part_kernel<<<dim3(nch, BB), dim3(256), 0, stream>>>(tmp, part, HW, 0, nch);
    gn_fin_kernel<<<dim3(64), dim3(64), 0, stream>>>(part, stats, nch, HW);
    gn_apply_rm_kernel<<<dim3(BB * HW), dim3(256), 0, stream>>>(
        tmp, stats, gss[lvl], gbb[lvl], src, srcb, HW, startsHost[lvl]);
  }

  // ---- 6 encoder layers ----
  for (int l = 0; l < 6; ++l) {
    qb_kernel<<<dim3(M), dim3(256), 0, stream>>>(src, pos, qb);
    bgemm_kernel<<<dim3(2, M / 128, 1), dim3(256), 0, stream>>>(
        srcb, valT + (long long)l * 65536, val_b + l * 256, valueb,
        M, 256, 256, 0LL, 0LL, 0LL, 1, 0);
    bgemm_kernel<<<dim3(2, M / 128, 1), dim3(256), 0, stream>>>(
        qb, offT + (long long)l * 49152, off_b + l * 192, offbuf,
        M, 192, 256, 0LL, 0LL, 0LL, 0, 0);
    bgemm_kernel<<<dim3(1, M / 128, 1), dim3(256), 0, stream>>>(
        qb, awT + (long long)l * 24576, aw_b + l * 96, awbuf,
        M, 96, 256, 0LL, 0LL, 0LL, 0, 0);
    deform_kernel<<<dim3(M / 4), dim3(256), 0, stream>>>(valueb, offbuf, awbuf, sampb);
    bgemm_kernel<<<dim3(2, M / 128, 1), dim3(256), 0, stream>>>(
        sampb, outT + (long long)l * 65536, out_b + l * 256, tmp,
        M, 256, 256, 0LL, 0LL, 0LL, 0, 0);
    ln_kernel<<<dim3(M), dim3(256), 0, stream>>>(src, tmp, ln1_s + l * 256, ln1_b + l * 256, srcb);
    bgemm_kernel<<<dim3(8, M / 128, 1), dim3(256), 0, stream>>>(
        srcb, f1T + (long long)l * 262144, ffn1_b + l * 1024, hbuf,
        M, 1024, 256, 0LL, 0LL, 0LL, 1, 1);
    bgemm_kernel<<<dim3(2, M / 128, 1), dim3(256), 0, stream>>>(
        hbuf, f2T + (long long)l * 262144, ffn2_b + l * 256, tmp,
        M, 256, 1024, 0LL, 0LL, 0LL, 0, 0);
    ln_kernel<<<dim3(M), dim3(256), 0, stream>>>(src, tmp, ln2_s + l * 256, ln2_b + l * 256, srcb);
  }

  // ---- output transposes ----
  float* outsPtr[3] = {out0, out1, out2};
  for (int lvl = 0; lvl < 3; ++lvl) {
    transpose_out_kernel<<<dim3(HWs[lvl] / 32, 8, BB), dim3(32, 8), 0, stream>>>(
        src, outsPtr[lvl], HWs[lvl], startsHost[lvl]);
  }

  // ---- FPN ----
  tfeat_kernel<<<dim3(1152, 8, BB), dim3(32, 8), 0, stream>>>(res2, res2T, 256, 36864);
  bgemm_kernel<<<dim3(2, 288, BB), dim3(256), 0, stream>>>(
      res2T, latwb, nullptr, latbf, 36864, 256, 256,
      36864LL * 256, 0LL, 36864LL * 256, 1, 0);
  gn_part_kernel<<<dim3(128, BB), dim3(256), 0, stream>>>(latbf, part, 36864, 1, 128);
  gn_fin_kernel<<<dim3(64), dim3(64), 0, stream>>>(part, stats, 128, 36864);
  zero16_kernel<<<dim3(9410), dim3(256), 0, stream>>>((uint4*)latb, 2408704LL);
  lat_finish_rm_kernel<<<dim3(73728), dim3(256), 0, stream>>>(latbf, stats, lat_gs, lat_gb, src, latb);
  bgemm_conv_kernel<<<dim3(2, 288, BB), dim3(256), 0, stream>>>(latb, fpnT, latbf);
  gn_part_kernel<<<dim3(128, BB), dim3(256), 0, stream>>>(latbf, part, 36864, 1, 128);
  gn_fin_kernel<<<dim3(64), dim3(64), 0, stream>>>(part, stats, 128, 36864);
  gn_relu_tr_kernel<<<dim3(1152, 8, BB), dim3(32, 8), 0, stream>>>(latbf, stats, fpn_gs, fpn_gb, Yout);
}

// Round 7
// 2324.841 us; speedup vs baseline: 3.4663x; 1.0836x over previous
//
#include <hip/hip_runtime.h>
#include <math.h>

#define NLEN 12096
#define BB 2

typedef __bf16 bhalf;
typedef bhalf bh8 __attribute__((ext_vector_type(8)));
typedef bhalf bh4 __attribute__((ext_vector_type(4)));
typedef float f32x4 __attribute__((ext_vector_type(4)));

// perm for LDS 16B-unit swizzle within 64B rows: spreads 16-row frag reads
// across all 8 bank-groups (2-way residual = free). Same involution applied
// at staging (global kc) and read (fg) side; LDS layout stays linear.
__device__ __forceinline__ int swz(int row) { return (row + (row >> 2)) & 3; }

// =====================================================================
// bf16 MFMA GEMM: C[M,N] = A[M,K] @ Bt[N,K]^T  (+bias[n]) (+relu)
// Tile 128x128, BK=32, 4 waves (2x2), 16x16x32 MFMA, swizzled LDS.
// =====================================================================
__global__ __launch_bounds__(256) void bgemm_kernel(
    const bhalf* __restrict__ A, const bhalf* __restrict__ Bt,
    const float* __restrict__ bias, void* __restrict__ Cout,
    int M, int N, int K, long long sA, long long sB, long long sC,
    int outBf16, int relu)
{
  const int bz = blockIdx.z;
  A += bz * sA; Bt += bz * sB;
  const int m0 = blockIdx.y * 128, n0 = blockIdx.x * 128;
  __shared__ __align__(16) bhalf As[128 * 32];
  __shared__ __align__(16) bhalf Bs[128 * 32];
  const int t = threadIdx.x;
  const int lane = t & 63;
  const int w = t >> 6;
  const int wm = (w >> 1) * 64, wn = (w & 1) * 64;
  const int fr = lane & 15, fg = lane >> 4;
  f32x4 acc[4][4] = {};
  for (int k0 = 0; k0 < K; k0 += 32) {
#pragma unroll
    for (int j = 0; j < 2; ++j) {
      int id = t + j * 256;
      int row = id >> 2, up = id & 3;
      int kcg = ((up ^ swz(row)) * 8);
      uint4 av = make_uint4(0u, 0u, 0u, 0u);
      int m = m0 + row;
      if (m < M) av = *(const uint4*)(A + (long long)m * K + k0 + kcg);
      *(uint4*)(As + row * 32 + up * 8) = av;
      uint4 bv = make_uint4(0u, 0u, 0u, 0u);
      int n = n0 + row;
      if (n < N) bv = *(const uint4*)(Bt + (long long)n * K + k0 + kcg);
      *(uint4*)(Bs + row * 32 + up * 8) = bv;
    }
    __syncthreads();
    bh8 af[4], bf[4];
#pragma unroll
    for (int mi = 0; mi < 4; ++mi) {
      int r = wm + mi * 16 + fr;
      af[mi] = *(const bh8*)(As + r * 32 + ((fg ^ swz(r)) * 8));
    }
#pragma unroll
    for (int ni = 0; ni < 4; ++ni) {
      int r = wn + ni * 16 + fr;
      bf[ni] = *(const bh8*)(Bs + r * 32 + ((fg ^ swz(r)) * 8));
    }
#pragma unroll
    for (int mi = 0; mi < 4; ++mi)
#pragma unroll
      for (int ni = 0; ni < 4; ++ni)
        acc[mi][ni] = __builtin_amdgcn_mfma_f32_16x16x32_bf16(af[mi], bf[ni], acc[mi][ni], 0, 0, 0);
    __syncthreads();
  }
  float* Cf = (float*)Cout + bz * sC;
  bhalf* Cb = (bhalf*)Cout + bz * sC;
#pragma unroll
  for (int mi = 0; mi < 4; ++mi) {
#pragma unroll
    for (int r = 0; r < 4; ++r) {
      int m = m0 + wm + mi * 16 + fg * 4 + r;
      if (m >= M) continue;
#pragma unroll
      for (int ni = 0; ni < 4; ++ni) {
        int n = n0 + wn + ni * 16 + fr;
        if (n >= N) continue;
        float v = acc[mi][ni][r];
        if (bias) v += bias[n];
        if (relu) v = fmaxf(v, 0.f);
        if (outBf16) Cb[(long long)m * N + n] = (bhalf)v;
        else         Cf[(long long)m * N + n] = v;
      }
    }
  }
}

// =====================================================================
// Implicit-GEMM 3x3 conv, K reordered ci_block-major / tap-inner.
// K-step s: cib = s/9, tap = s%9. Bt laid out to match (fpnw_kernel).
// =====================================================================
__global__ __launch_bounds__(256) void bgemm_conv_kernel(
    const bhalf* __restrict__ Ab, const bhalf* __restrict__ Bt,
    bhalf* __restrict__ Cout)
{
  const int bz = blockIdx.z;
  const bhalf* Apad = Ab + (long long)bz * 37636 * 256;
  const int m0 = blockIdx.y * 128, n0 = blockIdx.x * 128;
  __shared__ __align__(16) bhalf As[128 * 32];
  __shared__ __align__(16) bhalf Bs[128 * 32];
  const int t = threadIdx.x;
  const int lane = t & 63;
  const int w = t >> 6;
  const int wm = (w >> 1) * 64, wn = (w & 1) * 64;
  const int fr = lane & 15, fg = lane >> 4;
  int rowA[2], py[2], px[2];
#pragma unroll
  for (int j = 0; j < 2; ++j) {
    int id = t + j * 256;
    rowA[j] = id >> 2;
    int m = m0 + rowA[j];
    py[j] = m / 192; px[j] = m % 192;
  }
  f32x4 acc[4][4] = {};
  for (int s = 0; s < 72; ++s) {
    const int cib = s / 9, tap = s % 9;
    const int ty = tap / 3, tx = tap % 3;
#pragma unroll
    for (int j = 0; j < 2; ++j) {
      int id = t + j * 256;
      int row = rowA[j], up = id & 3;
      int kcg = ((up ^ swz(row)) * 8);
      uint4 av = *(const uint4*)(Apad + ((long long)(py[j] + ty) * 194 + px[j] + tx) * 256 + cib * 32 + kcg);
      *(uint4*)(As + row * 32 + up * 8) = av;
      uint4 bv = *(const uint4*)(Bt + (long long)(n0 + row) * 2304 + s * 32 + kcg);
      *(uint4*)(Bs + row * 32 + up * 8) = bv;
    }
    __syncthreads();
    bh8 af[4], bf[4];
#pragma unroll
    for (int mi = 0; mi < 4; ++mi) {
      int r = wm + mi * 16 + fr;
      af[mi] = *(const bh8*)(As + r * 32 + ((fg ^ swz(r)) * 8));
    }
#pragma unroll
    for (int ni = 0; ni < 4; ++ni) {
      int r = wn + ni * 16 + fr;
      bf[ni] = *(const bh8*)(Bs + r * 32 + ((fg ^ swz(r)) * 8));
    }
#pragma unroll
    for (int mi = 0; mi < 4; ++mi)
#pragma unroll
      for (int ni = 0; ni < 4; ++ni)
        acc[mi][ni] = __builtin_amdgcn_mfma_f32_16x16x32_bf16(af[mi], bf[ni], acc[mi][ni], 0, 0, 0);
    __syncthreads();
  }
  bhalf* Cb = Cout + (long long)bz * 36864 * 256;
#pragma unroll
  for (int mi = 0; mi < 4; ++mi)
#pragma unroll
    for (int r = 0; r < 4; ++r) {
      int m = m0 + wm + mi * 16 + fg * 4 + r;
#pragma unroll
      for (int ni = 0; ni < 4; ++ni) {
        int n = n0 + wn + ni * 16 + fr;
        Cb[(long long)m * 256 + n] = (bhalf)acc[mi][ni][r];
      }
    }
}

// =====================================================================
// Weight transpose+convert: W [z][Kd][Nd] fp32 -> out [z (zdst stride)][Nd][Kd] bf16
// =====================================================================
__global__ void twcvt_kernel(const float* __restrict__ Wsrc, bhalf* __restrict__ out,
                             int Kd, int Nd, long long zdst)
{
  __shared__ float tile[32][33];
  long long zi = (long long)blockIdx.z * Kd * Nd;
  long long zo = (long long)blockIdx.z * zdst;
  int n0 = blockIdx.x * 32, k0 = blockIdx.y * 32;
#pragma unroll
  for (int j = 0; j < 4; ++j) {
    int kk = threadIdx.y + 8 * j;
    tile[kk][threadIdx.x] = Wsrc[zi + (long long)(k0 + kk) * Nd + n0 + threadIdx.x];
  }
  __syncthreads();
#pragma unroll
  for (int j = 0; j < 4; ++j) {
    int nn = threadIdx.y + 8 * j;
    out[zo + (long long)(n0 + nn) * Kd + k0 + threadIdx.x] = (bhalf)tile[threadIdx.x][nn];
  }
}

__global__ void tfeat_kernel(const float* __restrict__ Fsrc, bhalf* __restrict__ out,
                             int Ci, int HW)
{
  __shared__ float tile[32][33];
  long long zo = (long long)blockIdx.z * Ci * HW;
  int hw0 = blockIdx.x * 32, c0 = blockIdx.y * 32;
#pragma unroll
  for (int j = 0; j < 4; ++j) {
    int cc = threadIdx.y + 8 * j;
    tile[cc][threadIdx.x] = Fsrc[zo + (long long)(c0 + cc) * HW + hw0 + threadIdx.x];
  }
  __syncthreads();
#pragma unroll
  for (int j = 0; j < 4; ++j) {
    int hh = threadIdx.y + 8 * j;
    out[zo + (long long)(hw0 + hh) * Ci + c0 + threadIdx.x] = (bhalf)tile[threadIdx.x][hh];
  }
}

__global__ void cvt_kernel(const float* __restrict__ in, bhalf* __restrict__ out, int n)
{
  int i = blockIdx.x * 256 + threadIdx.x;
  if (i < n) out[i] = (bhalf)in[i];
}

// fpn_w [co][ci][9] -> fpnT[co][cib*288 + tap*32 + cil]
__global__ void fpnw_kernel(const float* __restrict__ Wsrc, bhalf* __restrict__ out)
{
  int o = blockIdx.x * 256 + threadIdx.x;
  if (o >= 256 * 2304) return;
  int co = o / 2304, r = o % 2304;
  int cib = r / 288, rr = r % 288, tap = rr >> 5, cil = rr & 31;
  int ci = cib * 32 + cil;
  out[o] = (bhalf)Wsrc[(co * 256 + ci) * 9 + tap];
}

// concat off/aw biases -> [l][288]
__global__ void biascat_kernel(const float* __restrict__ ob, const float* __restrict__ ab,
                               float* __restrict__ out)
{
  int l = blockIdx.x, t = threadIdx.x;
  if (t < 288) out[l * 288 + t] = (t < 192) ? ob[l * 192 + t] : ab[l * 96 + t - 192];
}

__global__ void zero16_kernel(uint4* __restrict__ p, long long n16)
{
  long long i = (long long)blockIdx.x * 256 + threadIdx.x;
  if (i < n16) p[i] = make_uint4(0u, 0u, 0u, 0u);
}

// =====================================================================
// Sine positional embedding + level embed
// =====================================================================
__global__ void pos_kernel(float* __restrict__ pos, const float* __restrict__ level_embed)
{
  int i = blockIdx.x, c = threadIdx.x;
  int lvl, Wq, loc;
  if (i < 576)       { lvl = 0; Wq = 24; loc = i; }
  else if (i < 2880) { lvl = 1; Wq = 48; loc = i - 576; }
  else               { lvl = 2; Wq = 96; loc = i - 2880; }
  int h = loc / Wq, wcol = loc % Wq;
  int cc = c & 127;
  float coord = (c < 128) ? (float)(h + 1) : (float)(wcol + 1);
  float denom = (float)Wq + 1e-6f;
  float v = coord / denom * 6.28318530717958647692f;
  float tp = powf(10000.0f, (float)(cc & ~1) * (1.0f / 128.0f));
  float ang = v / tp;
  float val = (cc & 1) ? cosf(ang) : sinf(ang);
  pos[(long long)i * 256 + c] = val + level_embed[lvl * 256 + c];
}

// =====================================================================
// GN stats, two-pass, coalesced.
// =====================================================================
__global__ __launch_bounds__(256) void gn_part_kernel(const void* __restrict__ X,
    float* __restrict__ part, int HW, int isBf16, int nch)
{
  const int b = blockIdx.y, ch = blockIdx.x;
  const int rows = (HW + nch - 1) / nch;
  const int r0 = ch * rows;
  const int r1 = min(r0 + rows, HW);
  const int cg = threadIdx.x & 31;
  const int ro = threadIdx.x >> 5;
  float s = 0.f, s2 = 0.f;
  if (isBf16) {
    const bhalf* p = (const bhalf*)X + (long long)b * HW * 256 + cg * 8;
    for (int r = r0 + ro; r < r1; r += 8) {
      bh8 v = *(const bh8*)(p + (long long)r * 256);
#pragma unroll
      for (int j = 0; j < 8; ++j) { float f = (float)v[j]; s += f; s2 = fmaf(f, f, s2); }
    }
  } else {
    const float* p = (const float*)X + (long long)b * HW * 256 + cg * 8;
    for (int r = r0 + ro; r < r1; r += 8) {
      f32x4 v0 = *(const f32x4*)(p + (long long)r * 256);
      f32x4 v1 = *(const f32x4*)(p + (long long)r * 256 + 4);
#pragma unroll
      for (int j = 0; j < 4; ++j) { s += v0[j]; s2 = fmaf(v0[j], v0[j], s2); }
#pragma unroll
      for (int j = 0; j < 4; ++j) { s += v1[j]; s2 = fmaf(v1[j], v1[j], s2); }
    }
  }
  __shared__ float sh[2][8][32];
  sh[0][ro][cg] = s; sh[1][ro][cg] = s2;
  __syncthreads();
  if (threadIdx.x < 32) {
    float S = 0.f, S2 = 0.f;
#pragma unroll
    for (int k = 0; k < 8; ++k) { S += sh[0][k][threadIdx.x]; S2 += sh[1][k][threadIdx.x]; }
    long long o = ((long long)(b * 32 + threadIdx.x) * nch + ch) * 2;
    part[o] = S; part[o + 1] = S2;
  }
}

__global__ __launch_bounds__(64) void gn_fin_kernel(const float* __restrict__ part,
    float* __restrict__ stats, int nch, int HW)
{
  const int bg = blockIdx.x;
  float s = 0.f, s2 = 0.f;
  for (int i = threadIdx.x; i < nch; i += 64) {
    long long o = ((long long)bg * nch + i) * 2;
    s += part[o]; s2 += part[o + 1];
  }
#pragma unroll
  for (int o = 32; o > 0; o >>= 1) { s += __shfl_down(s, o); s2 += __shfl_down(s2, o); }
  if (threadIdx.x == 0) {
    float inv = 1.f / (float)(HW * 8);
    float mean = s * inv;
    float var = s2 * inv - mean * mean;
    stats[bg * 2] = mean;
    stats[bg * 2 + 1] = rsqrtf(var + 1e-5f);
  }
}

// =====================================================================
// GN apply -> src fp32 + srcb bf16 + qb bf16 (src+pos)
// =====================================================================
__global__ void gn_apply_rm_kernel(const float* __restrict__ T, const float* __restrict__ stats,
    const float* __restrict__ gs, const float* __restrict__ gb,
    float* __restrict__ src, bhalf* __restrict__ srcb, bhalf* __restrict__ qb,
    const float* __restrict__ pos, int HW, int startRow)
{
  long long idx = (long long)blockIdx.x * 256 + threadIdx.x;
  int c = threadIdx.x & 255;
  long long row = idx >> 8;
  int b = (int)(row / HW);
  long long hw = row - (long long)b * HW;
  int g = c >> 3;
  float v = T[idx];
  v = (v - stats[(b * 32 + g) * 2]) * stats[(b * 32 + g) * 2 + 1] * gs[c] + gb[c];
  long long pr = (startRow + hw) * 256 + c;
  long long o = (long long)b * NLEN * 256 + pr;
  src[o] = v;
  srcb[o] = (bhalf)v;
  qb[o] = (bhalf)(v + pos[pr]);
}

// =====================================================================
// src = LayerNorm(src + resid); writes srcb bf16, optional qb=y+pos
// =====================================================================
__global__ __launch_bounds__(256) void ln_kernel(float* __restrict__ src,
    const float* __restrict__ resid, const float* __restrict__ s, const float* __restrict__ bsh,
    bhalf* __restrict__ srcb, bhalf* __restrict__ qbOut, const float* __restrict__ pos)
{
  long long r = blockIdx.x;
  int c = threadIdx.x;
  float v = src[r * 256 + c] + resid[r * 256 + c];
  float sum = v, sq = v * v;
#pragma unroll
  for (int o = 32; o > 0; o >>= 1) { sum += __shfl_down(sum, o); sq += __shfl_down(sq, o); }
  __shared__ float sh[2][4];
  int lane = c & 63, wv = c >> 6;
  if (lane == 0) { sh[0][wv] = sum; sh[1][wv] = sq; }
  __syncthreads();
  float S  = sh[0][0] + sh[0][1] + sh[0][2] + sh[0][3];
  float S2 = sh[1][0] + sh[1][1] + sh[1][2] + sh[1][3];
  float mean = S * (1.f / 256.f);
  float var = S2 * (1.f / 256.f) - mean * mean;
  float rstd = rsqrtf(var + 1e-5f);
  float y = (v - mean) * rstd * s[c] + bsh[c];
  src[r * 256 + c] = y;
  srcb[r * 256 + c] = (bhalf)y;
  if (qbOut) {
    int pr = (int)(r % NLEN);
    qbOut[r * 256 + c] = (bhalf)(y + pos[(long long)pr * 256 + c]);
  }
}

// =====================================================================
// MSDeformAttn sampling, wave-per-query, 4 ch/lane, fused softmax.
// offaw fp32 [B*LEN][288]: cols 0..191 offsets, 192..287 aw logits.
// =====================================================================
__global__ __launch_bounds__(256) void deform_kernel(const bhalf* __restrict__ value,
    const float* __restrict__ offaw, bhalf* __restrict__ out)
{
  const int wv = threadIdx.x >> 6;
  const int lane = threadIdx.x & 63;
  const int bi = blockIdx.x * 4 + wv;
  const int i = bi % NLEN;
  const int bbase = bi - i;
  const int c0 = lane * 4;
  const int head = lane >> 3;
  int loc, Wq;
  if (i < 576)       { Wq = 24; loc = i; }
  else if (i < 2880) { Wq = 48; loc = i - 576; }
  else               { Wq = 96; loc = i - 2880; }
  const float rx = ((loc % Wq) + 0.5f) / (float)Wq;
  const float ry = ((loc / Wq) + 0.5f) / (float)Wq;
  const float* offp = offaw + (long long)bi * 288 + head * 24;
  const float* awp  = offaw + (long long)bi * 288 + 192 + head * 12;
  float aw[12]; float mx = -1e30f;
#pragma unroll
  for (int j = 0; j < 12; ++j) { aw[j] = awp[j]; mx = fmaxf(mx, aw[j]); }
  float ssum = 0.f;
#pragma unroll
  for (int j = 0; j < 12; ++j) { aw[j] = __expf(aw[j] - mx); ssum += aw[j]; }
  const float sinv = 1.f / ssum;
  float acc0 = 0.f, acc1 = 0.f, acc2 = 0.f, acc3 = 0.f;
  const int starts[3] = {0, 576, 2880};
  const int Ls[3] = {24, 48, 96};
#pragma unroll
  for (int l = 0; l < 3; ++l) {
    const int Wl = Ls[l];
    const float fW = (float)Wl;
    const bhalf* vb = value + (long long)(bbase + starts[l]) * 256 + c0;
#pragma unroll
    for (int p = 0; p < 4; ++p) {
      const float ox = offp[l * 8 + p * 2], oy = offp[l * 8 + p * 2 + 1];
      const float a = aw[l * 4 + p] * sinv;
      const float x = (rx + ox / fW) * fW - 0.5f;
      const float y = (ry + oy / fW) * fW - 0.5f;
      const float x0f = floorf(x), y0f = floorf(y);
      const float wx = x - x0f, wy = y - y0f;
      const int x0 = (int)x0f, y0 = (int)y0f;
      const int x1 = x0 + 1, y1 = y0 + 1;
      const bool xv0 = (x0 >= 0) & (x0 < Wl);
      const bool xv1 = (x1 >= 0) & (x1 < Wl);
      const bool yv0 = (y0 >= 0) & (y0 < Wl);
      const bool yv1 = (y1 >= 0) & (y1 < Wl);
      const int cx0 = min(max(x0, 0), Wl - 1), cx1 = min(max(x1, 0), Wl - 1);
      const int cy0 = min(max(y0, 0), Wl - 1), cy1 = min(max(y1, 0), Wl - 1);
      const float w00 = (xv0 && yv0) ? (1.f - wx) * (1.f - wy) * a : 0.f;
      const float w01 = (xv1 && yv0) ? wx * (1.f - wy) * a : 0.f;
      const float w10 = (xv0 && yv1) ? (1.f - wx) * wy * a : 0.f;
      const float w11 = (xv1 && yv1) ? wx * wy * a : 0.f;
      const bh4 g00 = *(const bh4*)(vb + (cy0 * Wl + cx0) * 256);
      const bh4 g01 = *(const bh4*)(vb + (cy0 * Wl + cx1) * 256);
      const bh4 g10 = *(const bh4*)(vb + (cy1 * Wl + cx0) * 256);
      const bh4 g11 = *(const bh4*)(vb + (cy1 * Wl + cx1) * 256);
      acc0 = fmaf(w00, (float)g00[0], fmaf(w01, (float)g01[0], fmaf(w10, (float)g10[0], fmaf(w11, (float)g11[0], acc0))));
      acc1 = fmaf(w00, (float)g00[1], fmaf(w01, (float)g01[1], fmaf(w10, (float)g10[1], fmaf(w11, (float)g11[1], acc1))));
      acc2 = fmaf(w00, (float)g00[2], fmaf(w01, (float)g01[2], fmaf(w10, (float)g10[2], fmaf(w11, (float)g11[2], acc2))));
      acc3 = fmaf(w00, (float)g00[3], fmaf(w01, (float)g01[3], fmaf(w10, (float)g10[3], fmaf(w11, (float)g11[3], acc3))));
    }
  }
  bh4 o;
  o[0] = (bhalf)acc0; o[1] = (bhalf)acc1; o[2] = (bhalf)acc2; o[3] = (bhalf)acc3;
  *(bh4*)(out + (long long)bi * 256 + c0) = o;
}

// =====================================================================
// src[b][startRow+hw][c] -> out[b][c][hw]
// =====================================================================
__global__ void transpose_out_kernel(const float* __restrict__ src, float* __restrict__ out,
    int HW, int startRow)
{
  __shared__ float tile[32][33];
  int b = blockIdx.z;
  int w0 = blockIdx.x * 32, c0 = blockIdx.y * 32;
#pragma unroll
  for (int j = 0; j < 4; ++j) {
    int wl = threadIdx.y + 8 * j;
    tile[wl][threadIdx.x] = src[((long long)b * NLEN + startRow + w0 + wl) * 256 + c0 + threadIdx.x];
  }
  __syncthreads();
#pragma unroll
  for (int j = 0; j < 4; ++j) {
    int cl = threadIdx.y + 8 * j;
    out[((long long)b * 256 + c0 + cl) * HW + w0 + threadIdx.x] = tile[threadIdx.x][cl];
  }
}

// =====================================================================
// latb = GN(lat) + upsample2x(src lvl2), zero-padded layout
// =====================================================================
__global__ void lat_finish_rm_kernel(const bhalf* __restrict__ lat, const float* __restrict__ stats,
    const float* __restrict__ gs, const float* __restrict__ gb,
    const float* __restrict__ src, bhalf* __restrict__ latb)
{
  long long idx = (long long)blockIdx.x * 256 + threadIdx.x;
  int c = threadIdx.x & 255;
  long long row = idx >> 8;
  int b = (int)(row / 36864);
  int p = (int)(row - (long long)b * 36864);
  int y = p / 192, x = p % 192;
  int g = c >> 3;
  float v = (float)lat[idx];
  v = (v - stats[(b * 32 + g) * 2]) * stats[(b * 32 + g) * 2 + 1] * gs[c] + gb[c];
  float ys = fmaxf(y * 0.5f - 0.25f, 0.f);
  float xs = fmaxf(x * 0.5f - 0.25f, 0.f);
  int y0 = (int)ys; float wy = ys - (float)y0; int y1 = min(y0 + 1, 95);
  int x0 = (int)xs; float wx = xs - (float)x0; int x1 = min(x0 + 1, 95);
  const float* sp = src + ((long long)b * NLEN + 2880) * 256 + c;
  float r0 = sp[(long long)(y0 * 96 + x0) * 256] * (1.f - wx) + sp[(long long)(y0 * 96 + x1) * 256] * wx;
  float r1 = sp[(long long)(y1 * 96 + x0) * 256] * (1.f - wx) + sp[(long long)(y1 * 96 + x1) * 256] * wx;
  latb[((long long)b * 37636 + (long long)(y + 1) * 194 + (x + 1)) * 256 + c]
      = (bhalf)(v + r0 * (1.f - wy) + r1 * wy);
}

// =====================================================================
// Final GN+ReLU+transpose: convC bf16 [b][hw][c] -> Y fp32 [b][c][hw]
// =====================================================================
__global__ void gn_relu_tr_kernel(const bhalf* __restrict__ convC, const float* __restrict__ stats,
    const float* __restrict__ gs, const float* __restrict__ gb, float* __restrict__ Y)
{
  __shared__ float tile[32][33];
  int b = blockIdx.z;
  int hw0 = blockIdx.x * 32, c0 = blockIdx.y * 32;
#pragma unroll
  for (int j = 0; j < 4; ++j) {
    int hwl = threadIdx.y + 8 * j;
    int c = c0 + threadIdx.x;
    int g = c >> 3;
    float v = (float)convC[((long long)b * 36864 + hw0 + hwl) * 256 + c];
    v = (v - stats[(b * 32 + g) * 2]) * stats[(b * 32 + g) * 2 + 1] * gs[c] + gb[c];
    tile[hwl][threadIdx.x] = fmaxf(v, 0.f);
  }
  __syncthreads();
#pragma unroll
  for (int j = 0; j < 4; ++j) {
    int cl = threadIdx.y + 8 * j;
    Y[((long long)b * 256 + c0 + cl) * 36864 + hw0 + threadIdx.x] = tile[threadIdx.x][cl];
  }
}

// =====================================================================
extern "C" void kernel_launch(void* const* d_in, const int* in_sizes, int n_in,
                              void* d_out, int out_size, void* d_ws, size_t ws_size,
                              hipStream_t stream)
{
  const float* res2 = (const float*)d_in[0];
  const float* res3 = (const float*)d_in[1];
  const float* res4 = (const float*)d_in[2];
  const float* res5 = (const float*)d_in[3];
  const float* pw[3]  = {(const float*)d_in[4],  (const float*)d_in[8],  (const float*)d_in[12]};
  const float* pb[3]  = {(const float*)d_in[5],  (const float*)d_in[9],  (const float*)d_in[13]};
  const float* gss[3] = {(const float*)d_in[6],  (const float*)d_in[10], (const float*)d_in[14]};
  const float* gbb[3] = {(const float*)d_in[7],  (const float*)d_in[11], (const float*)d_in[15]};
  const float* level_embed = (const float*)d_in[16];
  const float* off_w = (const float*)d_in[17];
  const float* off_b = (const float*)d_in[18];
  const float* aw_w  = (const float*)d_in[19];
  const float* aw_b  = (const float*)d_in[20];
  const float* val_w = (const float*)d_in[21];
  const float* val_b = (const float*)d_in[22];
  const float* out_w = (const float*)d_in[23];
  const float* out_b = (const float*)d_in[24];
  const float* ln1_s = (const float*)d_in[25];
  const float* ln1_b = (const float*)d_in[26];
  const float* ffn1_w = (const float*)d_in[27];
  const float* ffn1_b = (const float*)d_in[28];
  const float* ffn2_w = (const float*)d_in[29];
  const float* ffn2_b = (const float*)d_in[30];
  const float* ln2_s = (const float*)d_in[31];
  const float* ln2_b = (const float*)d_in[32];
  const float* lat_w = (const float*)d_in[33];
  const float* lat_gs = (const float*)d_in[34];
  const float* lat_gb = (const float*)d_in[35];
  const float* fpn_w = (const float*)d_in[36];
  const float* fpn_gs = (const float*)d_in[37];
  const float* fpn_gb = (const float*)d_in[38];

  char* W = (char*)d_ws;
  float* src   = (float*)(W + 0);
  float* pos   = (float*)(W + 24772608LL);
  float* tmp   = (float*)(W + 37158912LL);
  bhalf* srcb  = (bhalf*)(W + 61931520LL);
  bhalf* wreg  = (bhalf*)(W + 74317824LL);
  float* stats = (float*)(W + 86212608LL);     // 512 B
  float* part  = (float*)(W + 86213120LL);     // 64 KiB
  float* offaw_b = (float*)(W + 86278656LL);   // 6*288*4 = 6912 B (pad to 8K)
  char*  U     = W + 86286848LL;

  bhalf* valT   = wreg + 0;
  bhalf* offawT = wreg + 393216;    // 6 * 288*256
  bhalf* outT   = wreg + 835584;
  bhalf* f1T    = wreg + 1228800;
  bhalf* f2T    = wreg + 2801664;
  bhalf* pwb5   = wreg + 4374528;
  bhalf* pwb4   = wreg + 4898816;
  bhalf* pwb3   = wreg + 5160960;
  bhalf* latwb  = wreg + 5292032;
  bhalf* fpnT   = wreg + 5357568;

  bhalf* qb      = (bhalf*)(U + 0);
  bhalf* valueb  = (bhalf*)(U + 12386304LL);
  bhalf* sampb   = (bhalf*)(U + 24772608LL);
  float* offbuf  = (float*)(U + 37158912LL);   // [M][288] fp32 = 27.9 MB
  bhalf* hbuf    = (bhalf*)(U + 65028096LL);
  // BUGFIX (round 6): featT must NOT alias qb — gn_apply now writes qb during
  // the projection phase, and tfeat of levels 1/2 was clobbering it.
  // Place featT in the (projection-phase dead) sampb/offbuf region instead.
  bhalf* featT   = (bhalf*)(U + 24772608LL);   // <= 18.9 MB, dead before encoder
  bhalf* res2T   = (bhalf*)(U + 0);
  bhalf* latbf   = (bhalf*)(U + 37748736LL);
  bhalf* latb    = (bhalf*)(U + 75497472LL);

  float* Yout = (float*)d_out;
  float* out0 = Yout + 18874368LL;
  float* out1 = Yout + 19169280LL;
  float* out2 = Yout + 20348928LL;

  const int M = BB * NLEN;  // 24192

  // ---- weight prep ----
  twcvt_kernel<<<dim3(8, 8, 6), dim3(32, 8), 0, stream>>>(val_w, valT, 256, 256, 65536LL);
  twcvt_kernel<<<dim3(6, 8, 6), dim3(32, 8), 0, stream>>>(off_w, offawT, 256, 192, 73728LL);
  twcvt_kernel<<<dim3(3, 8, 6), dim3(32, 8), 0, stream>>>(aw_w, offawT + 192 * 256, 256, 96, 73728LL);
  twcvt_kernel<<<dim3(8, 8, 6), dim3(32, 8), 0, stream>>>(out_w, outT, 256, 256, 65536LL);
  twcvt_kernel<<<dim3(32, 8, 6), dim3(32, 8), 0, stream>>>(ffn1_w, f1T, 256, 1024, 262144LL);
  twcvt_kernel<<<dim3(8, 32, 6), dim3(32, 8), 0, stream>>>(ffn2_w, f2T, 1024, 256, 262144LL);
  biascat_kernel<<<dim3(6), dim3(288), 0, stream>>>(off_b, aw_b, offaw_b);
  cvt_kernel<<<dim3(2048), dim3(256), 0, stream>>>(pw[0], pwb5, 524288);
  cvt_kernel<<<dim3(1024), dim3(256), 0, stream>>>(pw[1], pwb4, 262144);
  cvt_kernel<<<dim3(512),  dim3(256), 0, stream>>>(pw[2], pwb3, 131072);
  cvt_kernel<<<dim3(256),  dim3(256), 0, stream>>>(lat_w, latwb, 65536);
  fpnw_kernel<<<dim3(2304), dim3(256), 0, stream>>>(fpn_w, fpnT);

  // ---- positional embedding ----
  pos_kernel<<<dim3(NLEN), dim3(256), 0, stream>>>(pos, level_embed);

  // ---- input projections + GN -> src/srcb/qb ----
  const float* feats[3] = {res5, res4, res3};
  const bhalf* pwbs[3] = {pwb5, pwb4, pwb3};
  const int cins[3] = {2048, 1024, 512};
  const int HWs[3] = {576, 2304, 9216};
  const int startsHost[3] = {0, 576, 2880};
  const int nchs[3] = {16, 64, 128};
  for (int lvl = 0; lvl < 3; ++lvl) {
    int HW = HWs[lvl], cin = cins[lvl], nch = nchs[lvl];
    tfeat_kernel<<<dim3(HW / 32, cin / 32, BB), dim3(32, 8), 0, stream>>>(feats[lvl], featT, cin, HW);
    bgemm_kernel<<<dim3(2, (HW + 127) / 128, BB), dim3(256), 0, stream>>>(
        featT, pwbs[lvl], pb[lvl], tmp, HW, 256, cin,
        (long long)HW * cin, 0LL, (long long)HW * 256, 0, 0);
    gn_part_kernel<<<dim3(nch, BB), dim3(256), 0, stream>>>(tmp, part, HW, 0, nch);
    gn_fin_kernel<<<dim3(64), dim3(64), 0, stream>>>(part, stats, nch, HW);
    gn_apply_rm_kernel<<<dim3(BB * HW), dim3(256), 0, stream>>>(
        tmp, stats, gss[lvl], gbb[lvl], src, srcb, qb, pos, HW, startsHost[lvl]);
  }

  // ---- 6 encoder layers ----
  for (int l = 0; l < 6; ++l) {
    bgemm_kernel<<<dim3(2, M / 128, 1), dim3(256), 0, stream>>>(
        srcb, valT + (long long)l * 65536, val_b + l * 256, valueb,
        M, 256, 256, 0LL, 0LL, 0LL, 1, 0);
    bgemm_kernel<<<dim3(3, M / 128, 1), dim3(256), 0, stream>>>(
        qb, offawT + (long long)l * 73728, offaw_b + l * 288, offbuf,
        M, 288, 256, 0LL, 0LL, 0LL, 0, 0);
    deform_kernel<<<dim3(M / 4), dim3(256), 0, stream>>>(valueb, offbuf, sampb);
    bgemm_kernel<<<dim3(2, M / 128, 1), dim3(256), 0, stream>>>(
        sampb, outT + (long long)l * 65536, out_b + l * 256, tmp,
        M, 256, 256, 0LL, 0LL, 0LL, 0, 0);
    ln_kernel<<<dim3(M), dim3(256), 0, stream>>>(src, tmp, ln1_s + l * 256, ln1_b + l * 256,
                                                 srcb, nullptr, nullptr);
    bgemm_kernel<<<dim3(8, M / 128, 1), dim3(256), 0, stream>>>(
        srcb, f1T + (long long)l * 262144, ffn1_b + l * 1024, hbuf,
        M, 1024, 256, 0LL, 0LL, 0LL, 1, 1);
    bgemm_kernel<<<dim3(2, M / 128, 1), dim3(256), 0, stream>>>(
        hbuf, f2T + (long long)l * 262144, ffn2_b + l * 256, tmp,
        M, 256, 1024, 0LL, 0LL, 0LL, 0, 0);
    ln_kernel<<<dim3(M), dim3(256), 0, stream>>>(src, tmp, ln2_s + l * 256, ln2_b + l * 256,
                                                 srcb, qb, pos);
  }

  // ---- output transposes ----
  float* outsPtr[3] = {out0, out1, out2};
  for (int lvl = 0; lvl < 3; ++lvl) {
    transpose_out_kernel<<<dim3(HWs[lvl] / 32, 8, BB), dim3(32, 8), 0, stream>>>(
        src, outsPtr[lvl], HWs[lvl], startsHost[lvl]);
  }

  // ---- FPN ----
  tfeat_kernel<<<dim3(1152, 8, BB), dim3(32, 8), 0, stream>>>(res2, res2T, 256, 36864);
  bgemm_kernel<<<dim3(2, 288, BB), dim3(256), 0, stream>>>(
      res2T, latwb, nullptr, latbf, 36864, 256, 256,
      36864LL * 256, 0LL, 36864LL * 256, 1, 0);
  gn_part_kernel<<<dim3(128, BB), dim3(256), 0, stream>>>(latbf, part, 36864, 1, 128);
  gn_fin_kernel<<<dim3(64), dim3(64), 0, stream>>>(part, stats, 128, 36864);
  zero16_kernel<<<dim3(9410), dim3(256), 0, stream>>>((uint4*)latb, 2408704LL);
  lat_finish_rm_kernel<<<dim3(73728), dim3(256), 0, stream>>>(latbf, stats, lat_gs, lat_gb, src, latb);
  bgemm_conv_kernel<<<dim3(2, 288, BB), dim3(256), 0, stream>>>(latb, fpnT, latbf);
  gn_part_kernel<<<dim3(128, BB), dim3(256), 0, stream>>>(latbf, part, 36864, 1, 128);
  gn_fin_kernel<<<dim3(64), dim3(64), 0, stream>>>(part, stats, 128, 36864);
  gn_relu_tr_kernel<<<dim3(1152, 8, BB), dim3(32, 8), 0, stream>>>(latbf, stats, fpn_gs, fpn_gb, Yout);
}

// Round 8
// 2280.398 us; speedup vs baseline: 3.5338x; 1.0195x over previous
//
#include <hip/hip_runtime.h>
#include <math.h>

#define NLEN 12096
#define BB 2

typedef __bf16 bhalf;
typedef bhalf bh8 __attribute__((ext_vector_type(8)));
typedef bhalf bh4 __attribute__((ext_vector_type(4)));
typedef float f32x4 __attribute__((ext_vector_type(4)));

// LDS 16B-slot swizzle: physical slot p holds logical k-group p^swz(row).
// swz(row)=(row>>1)&3 makes each 8-lane read pass cover all 8 (row-parity x
// slot) bank-quads exactly once -> conflict-free (round-7 fix: the old
// (row+(row>>2))&3 permuted lanes but not the address set -> no-op).
__device__ __forceinline__ int swz(int row) { return (row >> 1) & 3; }

// Bijective XCD-chunk swizzle (T1, m204): hardware id -> logical id so each
// XCD (id%8) processes a CONTIGUOUS chunk of logical blocks -> neighbor
// tiles share the per-XCD L2.
__device__ __forceinline__ int xcd_swz(int id, int nwg) {
  int q = nwg >> 3, r = nwg & 7;
  int xcd = id & 7, pos = id >> 3;
  int base = (xcd < r) ? xcd * (q + 1) : r * (q + 1) + (xcd - r) * q;
  return base + pos;
}

// =====================================================================
// bf16 MFMA GEMM: C[M,N] = A[M,K] @ Bt[N,K]^T  (+bias[n]) (+relu)
// Tile 128x128, BK=32, 4 waves (2x2), 16x16x32 MFMA, swizzled LDS.
// =====================================================================
__global__ __launch_bounds__(256) void bgemm_kernel(
    const bhalf* __restrict__ A, const bhalf* __restrict__ Bt,
    const float* __restrict__ bias, void* __restrict__ Cout,
    int M, int N, int K, long long sA, long long sB, long long sC,
    int outBf16, int relu)
{
  const int gx = gridDim.x, gy = gridDim.y;
  const int nwg = gx * gy * gridDim.z;
  int flat = (blockIdx.z * gy + blockIdx.y) * gx + blockIdx.x;
  int logical = xcd_swz(flat, nwg);
  const int bz = logical / (gx * gy);
  int rem = logical - bz * gx * gy;
  const int by = rem / gx;
  const int bx = rem - by * gx;

  A += bz * sA; Bt += bz * sB;
  const int m0 = by * 128, n0 = bx * 128;
  __shared__ __align__(16) bhalf As[128 * 32];
  __shared__ __align__(16) bhalf Bs[128 * 32];
  const int t = threadIdx.x;
  const int lane = t & 63;
  const int w = t >> 6;
  const int wm = (w >> 1) * 64, wn = (w & 1) * 64;
  const int fr = lane & 15, fg = lane >> 4;
  f32x4 acc[4][4] = {};
  for (int k0 = 0; k0 < K; k0 += 32) {
#pragma unroll
    for (int j = 0; j < 2; ++j) {
      int id = t + j * 256;
      int row = id >> 2, up = id & 3;
      int kcg = ((up ^ swz(row)) * 8);
      uint4 av = make_uint4(0u, 0u, 0u, 0u);
      int m = m0 + row;
      if (m < M) av = *(const uint4*)(A + (long long)m * K + k0 + kcg);
      *(uint4*)(As + row * 32 + up * 8) = av;
      uint4 bv = make_uint4(0u, 0u, 0u, 0u);
      int n = n0 + row;
      if (n < N) bv = *(const uint4*)(Bt + (long long)n * K + k0 + kcg);
      *(uint4*)(Bs + row * 32 + up * 8) = bv;
    }
    __syncthreads();
    bh8 af[4], bf[4];
#pragma unroll
    for (int mi = 0; mi < 4; ++mi) {
      int r = wm + mi * 16 + fr;
      af[mi] = *(const bh8*)(As + r * 32 + ((fg ^ swz(r)) * 8));
    }
#pragma unroll
    for (int ni = 0; ni < 4; ++ni) {
      int r = wn + ni * 16 + fr;
      bf[ni] = *(const bh8*)(Bs + r * 32 + ((fg ^ swz(r)) * 8));
    }
#pragma unroll
    for (int mi = 0; mi < 4; ++mi)
#pragma unroll
      for (int ni = 0; ni < 4; ++ni)
        acc[mi][ni] = __builtin_amdgcn_mfma_f32_16x16x32_bf16(af[mi], bf[ni], acc[mi][ni], 0, 0, 0);
    __syncthreads();
  }
  float* Cf = (float*)Cout + bz * sC;
  bhalf* Cb = (bhalf*)Cout + bz * sC;
#pragma unroll
  for (int mi = 0; mi < 4; ++mi) {
#pragma unroll
    for (int r = 0; r < 4; ++r) {
      int m = m0 + wm + mi * 16 + fg * 4 + r;
      if (m >= M) continue;
#pragma unroll
      for (int ni = 0; ni < 4; ++ni) {
        int n = n0 + wn + ni * 16 + fr;
        if (n >= N) continue;
        float v = acc[mi][ni][r];
        if (bias) v += bias[n];
        if (relu) v = fmaxf(v, 0.f);
        if (outBf16) Cb[(long long)m * N + n] = (bhalf)v;
        else         Cf[(long long)m * N + n] = v;
      }
    }
  }
}

// =====================================================================
// Implicit-GEMM 3x3 conv, K reordered ci_block-major / tap-inner.
// K-step s: cib = s/9, tap = s%9. Bt laid out to match (fpnw_kernel).
// =====================================================================
__global__ __launch_bounds__(256) void bgemm_conv_kernel(
    const bhalf* __restrict__ Ab, const bhalf* __restrict__ Bt,
    bhalf* __restrict__ Cout)
{
  const int gx = gridDim.x, gy = gridDim.y;
  const int nwg = gx * gy * gridDim.z;
  int flat = (blockIdx.z * gy + blockIdx.y) * gx + blockIdx.x;
  int logical = xcd_swz(flat, nwg);
  const int bz = logical / (gx * gy);
  int rem = logical - bz * gx * gy;
  const int by = rem / gx;
  const int bx = rem - by * gx;

  const bhalf* Apad = Ab + (long long)bz * 37636 * 256;
  const int m0 = by * 128, n0 = bx * 128;
  __shared__ __align__(16) bhalf As[128 * 32];
  __shared__ __align__(16) bhalf Bs[128 * 32];
  const int t = threadIdx.x;
  const int lane = t & 63;
  const int w = t >> 6;
  const int wm = (w >> 1) * 64, wn = (w & 1) * 64;
  const int fr = lane & 15, fg = lane >> 4;
  int rowA[2], py[2], px[2];
#pragma unroll
  for (int j = 0; j < 2; ++j) {
    int id = t + j * 256;
    rowA[j] = id >> 2;
    int m = m0 + rowA[j];
    py[j] = m / 192; px[j] = m % 192;
  }
  f32x4 acc[4][4] = {};
  for (int s = 0; s < 72; ++s) {
    const int cib = s / 9, tap = s % 9;
    const int ty = tap / 3, tx = tap % 3;
#pragma unroll
    for (int j = 0; j < 2; ++j) {
      int id = t + j * 256;
      int row = rowA[j], up = id & 3;
      int kcg = ((up ^ swz(row)) * 8);
      uint4 av = *(const uint4*)(Apad + ((long long)(py[j] + ty) * 194 + px[j] + tx) * 256 + cib * 32 + kcg);
      *(uint4*)(As + row * 32 + up * 8) = av;
      uint4 bv = *(const uint4*)(Bt + (long long)(n0 + row) * 2304 + s * 32 + kcg);
      *(uint4*)(Bs + row * 32 + up * 8) = bv;
    }
    __syncthreads();
    bh8 af[4], bf[4];
#pragma unroll
    for (int mi = 0; mi < 4; ++mi) {
      int r = wm + mi * 16 + fr;
      af[mi] = *(const bh8*)(As + r * 32 + ((fg ^ swz(r)) * 8));
    }
#pragma unroll
    for (int ni = 0; ni < 4; ++ni) {
      int r = wn + ni * 16 + fr;
      bf[ni] = *(const bh8*)(Bs + r * 32 + ((fg ^ swz(r)) * 8));
    }
#pragma unroll
    for (int mi = 0; mi < 4; ++mi)
#pragma unroll
      for (int ni = 0; ni < 4; ++ni)
        acc[mi][ni] = __builtin_amdgcn_mfma_f32_16x16x32_bf16(af[mi], bf[ni], acc[mi][ni], 0, 0, 0);
    __syncthreads();
  }
  bhalf* Cb = Cout + (long long)bz * 36864 * 256;
#pragma unroll
  for (int mi = 0; mi < 4; ++mi)
#pragma unroll
    for (int r = 0; r < 4; ++r) {
      int m = m0 + wm + mi * 16 + fg * 4 + r;
#pragma unroll
      for (int ni = 0; ni < 4; ++ni) {
        int n = n0 + wn + ni * 16 + fr;
        Cb[(long long)m * 256 + n] = (bhalf)acc[mi][ni][r];
      }
    }
}

// =====================================================================
// Weight transpose+convert: W [z][Kd][Nd] fp32 -> out [z (zdst stride)][Nd][Kd] bf16
// =====================================================================
__global__ void twcvt_kernel(const float* __restrict__ Wsrc, bhalf* __restrict__ out,
                             int Kd, int Nd, long long zdst)
{
  __shared__ float tile[32][33];
  long long zi = (long long)blockIdx.z * Kd * Nd;
  long long zo = (long long)blockIdx.z * zdst;
  int n0 = blockIdx.x * 32, k0 = blockIdx.y * 32;
#pragma unroll
  for (int j = 0; j < 4; ++j) {
    int kk = threadIdx.y + 8 * j;
    tile[kk][threadIdx.x] = Wsrc[zi + (long long)(k0 + kk) * Nd + n0 + threadIdx.x];
  }
  __syncthreads();
#pragma unroll
  for (int j = 0; j < 4; ++j) {
    int nn = threadIdx.y + 8 * j;
    out[zo + (long long)(n0 + nn) * Kd + k0 + threadIdx.x] = (bhalf)tile[threadIdx.x][nn];
  }
}

__global__ void tfeat_kernel(const float* __restrict__ Fsrc, bhalf* __restrict__ out,
                             int Ci, int HW)
{
  __shared__ float tile[32][33];
  long long zo = (long long)blockIdx.z * Ci * HW;
  int hw0 = blockIdx.x * 32, c0 = blockIdx.y * 32;
#pragma unroll
  for (int j = 0; j < 4; ++j) {
    int cc = threadIdx.y + 8 * j;
    tile[cc][threadIdx.x] = Fsrc[zo + (long long)(c0 + cc) * HW + hw0 + threadIdx.x];
  }
  __syncthreads();
#pragma unroll
  for (int j = 0; j < 4; ++j) {
    int hh = threadIdx.y + 8 * j;
    out[zo + (long long)(hw0 + hh) * Ci + c0 + threadIdx.x] = (bhalf)tile[threadIdx.x][hh];
  }
}

__global__ void cvt_kernel(const float* __restrict__ in, bhalf* __restrict__ out, int n)
{
  int i = blockIdx.x * 256 + threadIdx.x;
  if (i < n) out[i] = (bhalf)in[i];
}

// fpn_w [co][ci][9] -> fpnT[co][cib*288 + tap*32 + cil]
__global__ void fpnw_kernel(const float* __restrict__ Wsrc, bhalf* __restrict__ out)
{
  int o = blockIdx.x * 256 + threadIdx.x;
  if (o >= 256 * 2304) return;
  int co = o / 2304, r = o % 2304;
  int cib = r / 288, rr = r % 288, tap = rr >> 5, cil = rr & 31;
  int ci = cib * 32 + cil;
  out[o] = (bhalf)Wsrc[(co * 256 + ci) * 9 + tap];
}

// concat off/aw biases -> [l][288]
__global__ void biascat_kernel(const float* __restrict__ ob, const float* __restrict__ ab,
                               float* __restrict__ out)
{
  int l = blockIdx.x, t = threadIdx.x;
  if (t < 288) out[l * 288 + t] = (t < 192) ? ob[l * 192 + t] : ab[l * 96 + t - 192];
}

__global__ void zero16_kernel(uint4* __restrict__ p, long long n16)
{
  long long i = (long long)blockIdx.x * 256 + threadIdx.x;
  if (i < n16) p[i] = make_uint4(0u, 0u, 0u, 0u);
}

// =====================================================================
// Sine positional embedding + level embed
// =====================================================================
__global__ void pos_kernel(float* __restrict__ pos, const float* __restrict__ level_embed)
{
  int i = blockIdx.x, c = threadIdx.x;
  int lvl, Wq, loc;
  if (i < 576)       { lvl = 0; Wq = 24; loc = i; }
  else if (i < 2880) { lvl = 1; Wq = 48; loc = i - 576; }
  else               { lvl = 2; Wq = 96; loc = i - 2880; }
  int h = loc / Wq, wcol = loc % Wq;
  int cc = c & 127;
  float coord = (c < 128) ? (float)(h + 1) : (float)(wcol + 1);
  float denom = (float)Wq + 1e-6f;
  float v = coord / denom * 6.28318530717958647692f;
  float tp = powf(10000.0f, (float)(cc & ~1) * (1.0f / 128.0f));
  float ang = v / tp;
  float val = (cc & 1) ? cosf(ang) : sinf(ang);
  pos[(long long)i * 256 + c] = val + level_embed[lvl * 256 + c];
}

// =====================================================================
// GN stats, two-pass, coalesced.
// =====================================================================
__global__ __launch_bounds__(256) void gn_part_kernel(const void* __restrict__ X,
    float* __restrict__ part, int HW, int isBf16, int nch)
{
  const int b = blockIdx.y, ch = blockIdx.x;
  const int rows = (HW + nch - 1) / nch;
  const int r0 = ch * rows;
  const int r1 = min(r0 + rows, HW);
  const int cg = threadIdx.x & 31;
  const int ro = threadIdx.x >> 5;
  float s = 0.f, s2 = 0.f;
  if (isBf16) {
    const bhalf* p = (const bhalf*)X + (long long)b * HW * 256 + cg * 8;
    for (int r = r0 + ro; r < r1; r += 8) {
      bh8 v = *(const bh8*)(p + (long long)r * 256);
#pragma unroll
      for (int j = 0; j < 8; ++j) { float f = (float)v[j]; s += f; s2 = fmaf(f, f, s2); }
    }
  } else {
    const float* p = (const float*)X + (long long)b * HW * 256 + cg * 8;
    for (int r = r0 + ro; r < r1; r += 8) {
      f32x4 v0 = *(const f32x4*)(p + (long long)r * 256);
      f32x4 v1 = *(const f32x4*)(p + (long long)r * 256 + 4);
#pragma unroll
      for (int j = 0; j < 4; ++j) { s += v0[j]; s2 = fmaf(v0[j], v0[j], s2); }
#pragma unroll
      for (int j = 0; j < 4; ++j) { s += v1[j]; s2 = fmaf(v1[j], v1[j], s2); }
    }
  }
  __shared__ float sh[2][8][32];
  sh[0][ro][cg] = s; sh[1][ro][cg] = s2;
  __syncthreads();
  if (threadIdx.x < 32) {
    float S = 0.f, S2 = 0.f;
#pragma unroll
    for (int k = 0; k < 8; ++k) { S += sh[0][k][threadIdx.x]; S2 += sh[1][k][threadIdx.x]; }
    long long o = ((long long)(b * 32 + threadIdx.x) * nch + ch) * 2;
    part[o] = S; part[o + 1] = S2;
  }
}

__global__ __launch_bounds__(64) void gn_fin_kernel(const float* __restrict__ part,
    float* __restrict__ stats, int nch, int HW)
{
  const int bg = blockIdx.x;
  float s = 0.f, s2 = 0.f;
  for (int i = threadIdx.x; i < nch; i += 64) {
    long long o = ((long long)bg * nch + i) * 2;
    s += part[o]; s2 += part[o + 1];
  }
#pragma unroll
  for (int o = 32; o > 0; o >>= 1) { s += __shfl_down(s, o); s2 += __shfl_down(s2, o); }
  if (threadIdx.x == 0) {
    float inv = 1.f / (float)(HW * 8);
    float mean = s * inv;
    float var = s2 * inv - mean * mean;
    stats[bg * 2] = mean;
    stats[bg * 2 + 1] = rsqrtf(var + 1e-5f);
  }
}

// =====================================================================
// GN apply -> src fp32 + srcb bf16 + qb bf16 (src+pos)
// =====================================================================
__global__ void gn_apply_rm_kernel(const float* __restrict__ T, const float* __restrict__ stats,
    const float* __restrict__ gs, const float* __restrict__ gb,
    float* __restrict__ src, bhalf* __restrict__ srcb, bhalf* __restrict__ qb,
    const float* __restrict__ pos, int HW, int startRow)
{
  long long idx = (long long)blockIdx.x * 256 + threadIdx.x;
  int c = threadIdx.x & 255;
  long long row = idx >> 8;
  int b = (int)(row / HW);
  long long hw = row - (long long)b * HW;
  int g = c >> 3;
  float v = T[idx];
  v = (v - stats[(b * 32 + g) * 2]) * stats[(b * 32 + g) * 2 + 1] * gs[c] + gb[c];
  long long pr = (startRow + hw) * 256 + c;
  long long o = (long long)b * NLEN * 256 + pr;
  src[o] = v;
  srcb[o] = (bhalf)v;
  qb[o] = (bhalf)(v + pos[pr]);
}

// =====================================================================
// src = LayerNorm(src + resid); writes srcb bf16, optional qb=y+pos
// =====================================================================
__global__ __launch_bounds__(256) void ln_kernel(float* __restrict__ src,
    const float* __restrict__ resid, const float* __restrict__ s, const float* __restrict__ bsh,
    bhalf* __restrict__ srcb, bhalf* __restrict__ qbOut, const float* __restrict__ pos)
{
  long long r = blockIdx.x;
  int c = threadIdx.x;
  float v = src[r * 256 + c] + resid[r * 256 + c];
  float sum = v, sq = v * v;
#pragma unroll
  for (int o = 32; o > 0; o >>= 1) { sum += __shfl_down(sum, o); sq += __shfl_down(sq, o); }
  __shared__ float sh[2][4];
  int lane = c & 63, wv = c >> 6;
  if (lane == 0) { sh[0][wv] = sum; sh[1][wv] = sq; }
  __syncthreads();
  float S  = sh[0][0] + sh[0][1] + sh[0][2] + sh[0][3];
  float S2 = sh[1][0] + sh[1][1] + sh[1][2] + sh[1][3];
  float mean = S * (1.f / 256.f);
  float var = S2 * (1.f / 256.f) - mean * mean;
  float rstd = rsqrtf(var + 1e-5f);
  float y = (v - mean) * rstd * s[c] + bsh[c];
  src[r * 256 + c] = y;
  srcb[r * 256 + c] = (bhalf)y;
  if (qbOut) {
    int pr = (int)(r % NLEN);
    qbOut[r * 256 + c] = (bhalf)(y + pos[(long long)pr * 256 + c]);
  }
}

// =====================================================================
// MSDeformAttn sampling, wave-per-query, 4 ch/lane, fused softmax.
// offaw fp32 [B*LEN][288]: cols 0..191 offsets, 192..287 aw logits.
// =====================================================================
__global__ __launch_bounds__(256) void deform_kernel(const bhalf* __restrict__ value,
    const float* __restrict__ offaw, bhalf* __restrict__ out)
{
  const int wv = threadIdx.x >> 6;
  const int lane = threadIdx.x & 63;
  const int bi = blockIdx.x * 4 + wv;
  const int i = bi % NLEN;
  const int bbase = bi - i;
  const int c0 = lane * 4;
  const int head = lane >> 3;
  int loc, Wq;
  if (i < 576)       { Wq = 24; loc = i; }
  else if (i < 2880) { Wq = 48; loc = i - 576; }
  else               { Wq = 96; loc = i - 2880; }
  const float rx = ((loc % Wq) + 0.5f) / (float)Wq;
  const float ry = ((loc / Wq) + 0.5f) / (float)Wq;
  const float* offp = offaw + (long long)bi * 288 + head * 24;
  const float* awp  = offaw + (long long)bi * 288 + 192 + head * 12;
  float aw[12]; float mx = -1e30f;
#pragma unroll
  for (int j = 0; j < 12; ++j) { aw[j] = awp[j]; mx = fmaxf(mx, aw[j]); }
  float ssum = 0.f;
#pragma unroll
  for (int j = 0; j < 12; ++j) { aw[j] = __expf(aw[j] - mx); ssum += aw[j]; }
  const float sinv = 1.f / ssum;
  float acc0 = 0.f, acc1 = 0.f, acc2 = 0.f, acc3 = 0.f;
  const int starts[3] = {0, 576, 2880};
  const int Ls[3] = {24, 48, 96};
#pragma unroll
  for (int l = 0; l < 3; ++l) {
    const int Wl = Ls[l];
    const float fW = (float)Wl;
    const bhalf* vb = value + (long long)(bbase + starts[l]) * 256 + c0;
#pragma unroll
    for (int p = 0; p < 4; ++p) {
      const float ox = offp[l * 8 + p * 2], oy = offp[l * 8 + p * 2 + 1];
      const float a = aw[l * 4 + p] * sinv;
      const float x = (rx + ox / fW) * fW - 0.5f;
      const float y = (ry + oy / fW) * fW - 0.5f;
      const float x0f = floorf(x), y0f = floorf(y);
      const float wx = x - x0f, wy = y - y0f;
      const int x0 = (int)x0f, y0 = (int)y0f;
      const int x1 = x0 + 1, y1 = y0 + 1;
      const bool xv0 = (x0 >= 0) & (x0 < Wl);
      const bool xv1 = (x1 >= 0) & (x1 < Wl);
      const bool yv0 = (y0 >= 0) & (y0 < Wl);
      const bool yv1 = (y1 >= 0) & (y1 < Wl);
      const int cx0 = min(max(x0, 0), Wl - 1), cx1 = min(max(x1, 0), Wl - 1);
      const int cy0 = min(max(y0, 0), Wl - 1), cy1 = min(max(y1, 0), Wl - 1);
      const float w00 = (xv0 && yv0) ? (1.f - wx) * (1.f - wy) * a : 0.f;
      const float w01 = (xv1 && yv0) ? wx * (1.f - wy) * a : 0.f;
      const float w10 = (xv0 && yv1) ? (1.f - wx) * wy * a : 0.f;
      const float w11 = (xv1 && yv1) ? wx * wy * a : 0.f;
      const bh4 g00 = *(const bh4*)(vb + (cy0 * Wl + cx0) * 256);
      const bh4 g01 = *(const bh4*)(vb + (cy0 * Wl + cx1) * 256);
      const bh4 g10 = *(const bh4*)(vb + (cy1 * Wl + cx0) * 256);
      const bh4 g11 = *(const bh4*)(vb + (cy1 * Wl + cx1) * 256);
      acc0 = fmaf(w00, (float)g00[0], fmaf(w01, (float)g01[0], fmaf(w10, (float)g10[0], fmaf(w11, (float)g11[0], acc0))));
      acc1 = fmaf(w00, (float)g00[1], fmaf(w01, (float)g01[1], fmaf(w10, (float)g10[1], fmaf(w11, (float)g11[1], acc1))));
      acc2 = fmaf(w00, (float)g00[2], fmaf(w01, (float)g01[2], fmaf(w10, (float)g10[2], fmaf(w11, (float)g11[2], acc2))));
      acc3 = fmaf(w00, (float)g00[3], fmaf(w01, (float)g01[3], fmaf(w10, (float)g10[3], fmaf(w11, (float)g11[3], acc3))));
    }
  }
  bh4 o;
  o[0] = (bhalf)acc0; o[1] = (bhalf)acc1; o[2] = (bhalf)acc2; o[3] = (bhalf)acc3;
  *(bh4*)(out + (long long)bi * 256 + c0) = o;
}

// =====================================================================
// src[b][startRow+hw][c] -> out[b][c][hw]
// =====================================================================
__global__ void transpose_out_kernel(const float* __restrict__ src, float* __restrict__ out,
    int HW, int startRow)
{
  __shared__ float tile[32][33];
  int b = blockIdx.z;
  int w0 = blockIdx.x * 32, c0 = blockIdx.y * 32;
#pragma unroll
  for (int j = 0; j < 4; ++j) {
    int wl = threadIdx.y + 8 * j;
    tile[wl][threadIdx.x] = src[((long long)b * NLEN + startRow + w0 + wl) * 256 + c0 + threadIdx.x];
  }
  __syncthreads();
#pragma unroll
  for (int j = 0; j < 4; ++j) {
    int cl = threadIdx.y + 8 * j;
    out[((long long)b * 256 + c0 + cl) * HW + w0 + threadIdx.x] = tile[threadIdx.x][cl];
  }
}

// =====================================================================
// latb = GN(lat) + upsample2x(src lvl2), zero-padded layout
// =====================================================================
__global__ void lat_finish_rm_kernel(const bhalf* __restrict__ lat, const float* __restrict__ stats,
    const float* __restrict__ gs, const float* __restrict__ gb,
    const float* __restrict__ src, bhalf* __restrict__ latb)
{
  long long idx = (long long)blockIdx.x * 256 + threadIdx.x;
  int c = threadIdx.x & 255;
  long long row = idx >> 8;
  int b = (int)(row / 36864);
  int p = (int)(row - (long long)b * 36864);
  int y = p / 192, x = p % 192;
  int g = c >> 3;
  float v = (float)lat[idx];
  v = (v - stats[(b * 32 + g) * 2]) * stats[(b * 32 + g) * 2 + 1] * gs[c] + gb[c];
  float ys = fmaxf(y * 0.5f - 0.25f, 0.f);
  float xs = fmaxf(x * 0.5f - 0.25f, 0.f);
  int y0 = (int)ys; float wy = ys - (float)y0; int y1 = min(y0 + 1, 95);
  int x0 = (int)xs; float wx = xs - (float)x0; int x1 = min(x0 + 1, 95);
  const float* sp = src + ((long long)b * NLEN + 2880) * 256 + c;
  float r0 = sp[(long long)(y0 * 96 + x0) * 256] * (1.f - wx) + sp[(long long)(y0 * 96 + x1) * 256] * wx;
  float r1 = sp[(long long)(y1 * 96 + x0) * 256] * (1.f - wx) + sp[(long long)(y1 * 96 + x1) * 256] * wx;
  latb[((long long)b * 37636 + (long long)(y + 1) * 194 + (x + 1)) * 256 + c]
      = (bhalf)(v + r0 * (1.f - wy) + r1 * wy);
}

// =====================================================================
// Final GN+ReLU+transpose: convC bf16 [b][hw][c] -> Y fp32 [b][c][hw]
// =====================================================================
__global__ void gn_relu_tr_kernel(const bhalf* __restrict__ convC, const float* __restrict__ stats,
    const float* __restrict__ gs, const float* __restrict__ gb, float* __restrict__ Y)
{
  __shared__ float tile[32][33];
  int b = blockIdx.z;
  int hw0 = blockIdx.x * 32, c0 = blockIdx.y * 32;
#pragma unroll
  for (int j = 0; j < 4; ++j) {
    int hwl = threadIdx.y + 8 * j;
    int c = c0 + threadIdx.x;
    int g = c >> 3;
    float v = (float)convC[((long long)b * 36864 + hw0 + hwl) * 256 + c];
    v = (v - stats[(b * 32 + g) * 2]) * stats[(b * 32 + g) * 2 + 1] * gs[c] + gb[c];
    tile[hwl][threadIdx.x] = fmaxf(v, 0.f);
  }
  __syncthreads();
#pragma unroll
  for (int j = 0; j < 4; ++j) {
    int cl = threadIdx.y + 8 * j;
    Y[((long long)b * 256 + c0 + cl) * 36864 + hw0 + threadIdx.x] = tile[threadIdx.x][cl];
  }
}

// =====================================================================
extern "C" void kernel_launch(void* const* d_in, const int* in_sizes, int n_in,
                              void* d_out, int out_size, void* d_ws, size_t ws_size,
                              hipStream_t stream)
{
  const float* res2 = (const float*)d_in[0];
  const float* res3 = (const float*)d_in[1];
  const float* res4 = (const float*)d_in[2];
  const float* res5 = (const float*)d_in[3];
  const float* pw[3]  = {(const float*)d_in[4],  (const float*)d_in[8],  (const float*)d_in[12]};
  const float* pb[3]  = {(const float*)d_in[5],  (const float*)d_in[9],  (const float*)d_in[13]};
  const float* gss[3] = {(const float*)d_in[6],  (const float*)d_in[10], (const float*)d_in[14]};
  const float* gbb[3] = {(const float*)d_in[7],  (const float*)d_in[11], (const float*)d_in[15]};
  const float* level_embed = (const float*)d_in[16];
  const float* off_w = (const float*)d_in[17];
  const float* off_b = (const float*)d_in[18];
  const float* aw_w  = (const float*)d_in[19];
  const float* aw_b  = (const float*)d_in[20];
  const float* val_w = (const float*)d_in[21];
  const float* val_b = (const float*)d_in[22];
  const float* out_w = (const float*)d_in[23];
  const float* out_b = (const float*)d_in[24];
  const float* ln1_s = (const float*)d_in[25];
  const float* ln1_b = (const float*)d_in[26];
  const float* ffn1_w = (const float*)d_in[27];
  const float* ffn1_b = (const float*)d_in[28];
  const float* ffn2_w = (const float*)d_in[29];
  const float* ffn2_b = (const float*)d_in[30];
  const float* ln2_s = (const float*)d_in[31];
  const float* ln2_b = (const float*)d_in[32];
  const float* lat_w = (const float*)d_in[33];
  const float* lat_gs = (const float*)d_in[34];
  const float* lat_gb = (const float*)d_in[35];
  const float* fpn_w = (const float*)d_in[36];
  const float* fpn_gs = (const float*)d_in[37];
  const float* fpn_gb = (const float*)d_in[38];

  char* W = (char*)d_ws;
  float* src   = (float*)(W + 0);
  float* pos   = (float*)(W + 24772608LL);
  float* tmp   = (float*)(W + 37158912LL);
  bhalf* srcb  = (bhalf*)(W + 61931520LL);
  bhalf* wreg  = (bhalf*)(W + 74317824LL);
  float* stats = (float*)(W + 86212608LL);     // 512 B
  float* part  = (float*)(W + 86213120LL);     // 64 KiB
  float* offaw_b = (float*)(W + 86278656LL);   // 6*288*4 = 6912 B (pad to 8K)
  char*  U     = W + 86286848LL;

  bhalf* valT   = wreg + 0;
  bhalf* offawT = wreg + 393216;    // 6 * 288*256
  bhalf* outT   = wreg + 835584;
  bhalf* f1T    = wreg + 1228800;
  bhalf* f2T    = wreg + 2801664;
  bhalf* pwb5   = wreg + 4374528;
  bhalf* pwb4   = wreg + 4898816;
  bhalf* pwb3   = wreg + 5160960;
  bhalf* latwb  = wreg + 5292032;
  bhalf* fpnT   = wreg + 5357568;

  bhalf* qb      = (bhalf*)(U + 0);
  bhalf* valueb  = (bhalf*)(U + 12386304LL);
  bhalf* sampb   = (bhalf*)(U + 24772608LL);
  float* offbuf  = (float*)(U + 37158912LL);   // [M][288] fp32 = 27.9 MB
  bhalf* hbuf    = (bhalf*)(U + 65028096LL);
  bhalf* featT   = (bhalf*)(U + 24772608LL);   // projection-phase only (dead before encoder)
  bhalf* res2T   = (bhalf*)(U + 0);
  bhalf* latbf   = (bhalf*)(U + 37748736LL);
  bhalf* latb    = (bhalf*)(U + 75497472LL);

  float* Yout = (float*)d_out;
  float* out0 = Yout + 18874368LL;
  float* out1 = Yout + 19169280LL;
  float* out2 = Yout + 20348928LL;

  const int M = BB * NLEN;  // 24192

  // ---- weight prep ----
  twcvt_kernel<<<dim3(8, 8, 6), dim3(32, 8), 0, stream>>>(val_w, valT, 256, 256, 65536LL);
  twcvt_kernel<<<dim3(6, 8, 6), dim3(32, 8), 0, stream>>>(off_w, offawT, 256, 192, 73728LL);
  twcvt_kernel<<<dim3(3, 8, 6), dim3(32, 8), 0, stream>>>(aw_w, offawT + 192 * 256, 256, 96, 73728LL);
  twcvt_kernel<<<dim3(8, 8, 6), dim3(32, 8), 0, stream>>>(out_w, outT, 256, 256, 65536LL);
  twcvt_kernel<<<dim3(32, 8, 6), dim3(32, 8), 0, stream>>>(ffn1_w, f1T, 256, 1024, 262144LL);
  twcvt_kernel<<<dim3(8, 32, 6), dim3(32, 8), 0, stream>>>(ffn2_w, f2T, 1024, 256, 262144LL);
  biascat_kernel<<<dim3(6), dim3(288), 0, stream>>>(off_b, aw_b, offaw_b);
  cvt_kernel<<<dim3(2048), dim3(256), 0, stream>>>(pw[0], pwb5, 524288);
  cvt_kernel<<<dim3(1024), dim3(256), 0, stream>>>(pw[1], pwb4, 262144);
  cvt_kernel<<<dim3(512),  dim3(256), 0, stream>>>(pw[2], pwb3, 131072);
  cvt_kernel<<<dim3(256),  dim3(256), 0, stream>>>(lat_w, latwb, 65536);
  fpnw_kernel<<<dim3(2304), dim3(256), 0, stream>>>(fpn_w, fpnT);

  // ---- positional embedding ----
  pos_kernel<<<dim3(NLEN), dim3(256), 0, stream>>>(pos, level_embed);

  // ---- input projections + GN -> src/srcb/qb ----
  const float* feats[3] = {res5, res4, res3};
  const bhalf* pwbs[3] = {pwb5, pwb4, pwb3};
  const int cins[3] = {2048, 1024, 512};
  const int HWs[3] = {576, 2304, 9216};
  const int startsHost[3] = {0, 576, 2880};
  const int nchs[3] = {16, 64, 128};
  for (int lvl = 0; lvl < 3; ++lvl) {
    int HW = HWs[lvl], cin = cins[lvl], nch = nchs[lvl];
    tfeat_kernel<<<dim3(HW / 32, cin / 32, BB), dim3(32, 8), 0, stream>>>(feats[lvl], featT, cin, HW);
    bgemm_kernel<<<dim3(2, (HW + 127) / 128, BB), dim3(256), 0, stream>>>(
        featT, pwbs[lvl], pb[lvl], tmp, HW, 256, cin,
        (long long)HW * cin, 0LL, (long long)HW * 256, 0, 0);
    gn_part_kernel<<<dim3(nch, BB), dim3(256), 0, stream>>>(tmp, part, HW, 0, nch);
    gn_fin_kernel<<<dim3(64), dim3(64), 0, stream>>>(part, stats, nch, HW);
    gn_apply_rm_kernel<<<dim3(BB * HW), dim3(256), 0, stream>>>(
        tmp, stats, gss[lvl], gbb[lvl], src, srcb, qb, pos, HW, startsHost[lvl]);
  }

  // ---- 6 encoder layers ----
  for (int l = 0; l < 6; ++l) {
    bgemm_kernel<<<dim3(2, M / 128, 1), dim3(256), 0, stream>>>(
        srcb, valT + (long long)l * 65536, val_b + l * 256, valueb,
        M, 256, 256, 0LL, 0LL, 0LL, 1, 0);
    bgemm_kernel<<<dim3(3, M / 128, 1), dim3(256), 0, stream>>>(
        qb, offawT + (long long)l * 73728, offaw_b + l * 288, offbuf,
        M, 288, 256, 0LL, 0LL, 0LL, 0, 0);
    deform_kernel<<<dim3(M / 4), dim3(256), 0, stream>>>(valueb, offbuf, sampb);
    bgemm_kernel<<<dim3(2, M / 128, 1), dim3(256), 0, stream>>>(
        sampb, outT + (long long)l * 65536, out_b + l * 256, tmp,
        M, 256, 256, 0LL, 0LL, 0LL, 0, 0);
    ln_kernel<<<dim3(M), dim3(256), 0, stream>>>(src, tmp, ln1_s + l * 256, ln1_b + l * 256,
                                                 srcb, nullptr, nullptr);
    bgemm_kernel<<<dim3(8, M / 128, 1), dim3(256), 0, stream>>>(
        srcb, f1T + (long long)l * 262144, ffn1_b + l * 1024, hbuf,
        M, 1024, 256, 0LL, 0LL, 0LL, 1, 1);
    bgemm_kernel<<<dim3(2, M / 128, 1), dim3(256), 0, stream>>>(
        hbuf, f2T + (long long)l * 262144, ffn2_b + l * 256, tmp,
        M, 256, 1024, 0LL, 0LL, 0LL, 0, 0);
    ln_kernel<<<dim3(M), dim3(256), 0, stream>>>(src, tmp, ln2_s + l * 256, ln2_b + l * 256,
                                                 srcb, qb, pos);
  }

  // ---- output transposes ----
  float* outsPtr[3] = {out0, out1, out2};
  for (int lvl = 0; lvl < 3; ++lvl) {
    transpose_out_kernel<<<dim3(HWs[lvl] / 32, 8, BB), dim3(32, 8), 0, stream>>>(
        src, outsPtr[lvl], HWs[lvl], startsHost[lvl]);
  }

  // ---- FPN ----
  tfeat_kernel<<<dim3(1152, 8, BB), dim3(32, 8), 0, stream>>>(res2, res2T, 256, 36864);
  bgemm_kernel<<<dim3(2, 288, BB), dim3(256), 0, stream>>>(
      res2T, latwb, nullptr, latbf, 36864, 256, 256,
      36864LL * 256, 0LL, 36864LL * 256, 1, 0);
  gn_part_kernel<<<dim3(128, BB), dim3(256), 0, stream>>>(latbf, part, 36864, 1, 128);
  gn_fin_kernel<<<dim3(64), dim3(64), 0, stream>>>(part, stats, 128, 36864);
  zero16_kernel<<<dim3(9410), dim3(256), 0, stream>>>((uint4*)latb, 2408704LL);
  lat_finish_rm_kernel<<<dim3(73728), dim3(256), 0, stream>>>(latbf, stats, lat_gs, lat_gb, src, latb);
  bgemm_conv_kernel<<<dim3(2, 288, BB), dim3(256), 0, stream>>>(latb, fpnT, latbf);
  gn_part_kernel<<<dim3(128, BB), dim3(256), 0, stream>>>(latbf, part, 36864, 1, 128);
  gn_fin_kernel<<<dim3(64), dim3(64), 0, stream>>>(part, stats, 128, 36864);
  gn_relu_tr_kernel<<<dim3(1152, 8, BB), dim3(32, 8), 0, stream>>>(latbf, stats, fpn_gs, fpn_gb, Yout);
}

// Round 9
// 2040.623 us; speedup vs baseline: 3.9491x; 1.1175x over previous
//
#include <hip/hip_runtime.h>
#include <math.h>

#define NLEN 12096
#define BB 2

typedef __bf16 bhalf;
typedef bhalf bh8 __attribute__((ext_vector_type(8)));
typedef bhalf bh4 __attribute__((ext_vector_type(4)));
typedef float f32x4 __attribute__((ext_vector_type(4)));

// LDS 16B-slot swizzle: physical slot p holds logical k-group p^swz(row).
// swz(row)=(row>>1)&3 -> each 8-lane read pass covers all 8 (row-parity x
// slot) bank-quads once -> conflict-free (verified round 8: conflicts -> 0).
__device__ __forceinline__ int swz(int row) { return (row >> 1) & 3; }

// Bijective XCD-chunk swizzle (T1, m204).
__device__ __forceinline__ int xcd_swz(int id, int nwg) {
  int q = nwg >> 3, r = nwg & 7;
  int xcd = id & 7, pos = id >> 3;
  int base = (xcd < r) ? xcd * (q + 1) : r * (q + 1) + (xcd - r) * q;
  return base + pos;
}

#define GLOAD_LDS16(g, l) \
  __builtin_amdgcn_global_load_lds( \
      (const __attribute__((address_space(1))) unsigned int*)(g), \
      (__attribute__((address_space(3))) unsigned int*)(l), 16, 0, 0)

// =====================================================================
// bf16 MFMA GEMM: C[M,N] = A[M,K] @ Bt[N,K]^T  (+bias[n]) (+relu)
// Tile 128x128, BK=32, 4 waves (2x2), 16x16x32 MFMA.
// Staging: global_load_lds dwordx4, linear LDS dest (lane-ordered),
// swizzle applied on the GLOBAL source column (m173 pattern).
// OOB m/n rows are clamped: garbage affects only discarded outputs.
// =====================================================================
__global__ __launch_bounds__(256) void bgemm_kernel(
    const bhalf* __restrict__ A, const bhalf* __restrict__ Bt,
    const float* __restrict__ bias, void* __restrict__ Cout,
    int M, int N, int K, long long sA, long long sB, long long sC,
    int outBf16, int relu)
{
  const int gx = gridDim.x, gy = gridDim.y;
  const int nwg = gx * gy * gridDim.z;
  int flat = (blockIdx.z * gy + blockIdx.y) * gx + blockIdx.x;
  int logical = xcd_swz(flat, nwg);
  const int bz = logical / (gx * gy);
  int rem = logical - bz * gx * gy;
  const int by = rem / gx;
  const int bx = rem - by * gx;

  A += bz * sA; Bt += bz * sB;
  const int m0 = by * 128, n0 = bx * 128;
  __shared__ __align__(16) bhalf As[128 * 32];
  __shared__ __align__(16) bhalf Bs[128 * 32];
  const int t = threadIdx.x;
  const int lane = t & 63;
  const int w = t >> 6;
  const int wbase = t & 192;           // w*64, wave-uniform
  const int wm = (w >> 1) * 64, wn = (w & 1) * 64;
  const int fr = lane & 15, fg = lane >> 4;
  f32x4 acc[4][4] = {};
  for (int k0 = 0; k0 < K; k0 += 32) {
#pragma unroll
    for (int j = 0; j < 2; ++j) {
      int id = t + j * 256;
      int row = id >> 2, up = id & 3;
      int kcg = ((up ^ swz(row)) * 8);
      int m = m0 + row; m = (m < M) ? m : (M - 1);
      GLOAD_LDS16(A + (long long)m * K + k0 + kcg, As + (wbase + j * 256) * 8);
      int n = n0 + row; n = (n < N) ? n : (N - 1);
      GLOAD_LDS16(Bt + (long long)n * K + k0 + kcg, Bs + (wbase + j * 256) * 8);
    }
    __syncthreads();
    bh8 af[4], bf[4];
#pragma unroll
    for (int mi = 0; mi < 4; ++mi) {
      int r = wm + mi * 16 + fr;
      af[mi] = *(const bh8*)(As + r * 32 + ((fg ^ swz(r)) * 8));
    }
#pragma unroll
    for (int ni = 0; ni < 4; ++ni) {
      int r = wn + ni * 16 + fr;
      bf[ni] = *(const bh8*)(Bs + r * 32 + ((fg ^ swz(r)) * 8));
    }
#pragma unroll
    for (int mi = 0; mi < 4; ++mi)
#pragma unroll
      for (int ni = 0; ni < 4; ++ni)
        acc[mi][ni] = __builtin_amdgcn_mfma_f32_16x16x32_bf16(af[mi], bf[ni], acc[mi][ni], 0, 0, 0);
    __syncthreads();
  }
  float* Cf = (float*)Cout + bz * sC;
  bhalf* Cb = (bhalf*)Cout + bz * sC;
#pragma unroll
  for (int mi = 0; mi < 4; ++mi) {
#pragma unroll
    for (int r = 0; r < 4; ++r) {
      int m = m0 + wm + mi * 16 + fg * 4 + r;
      if (m >= M) continue;
#pragma unroll
      for (int ni = 0; ni < 4; ++ni) {
        int n = n0 + wn + ni * 16 + fr;
        if (n >= N) continue;
        float v = acc[mi][ni][r];
        if (bias) v += bias[n];
        if (relu) v = fmaxf(v, 0.f);
        if (outBf16) Cb[(long long)m * N + n] = (bhalf)v;
        else         Cf[(long long)m * N + n] = v;
      }
    }
  }
}

// =====================================================================
// Implicit-GEMM 3x3 conv, K reordered ci_block-major / tap-inner,
// global_load_lds staging.
// =====================================================================
__global__ __launch_bounds__(256) void bgemm_conv_kernel(
    const bhalf* __restrict__ Ab, const bhalf* __restrict__ Bt,
    bhalf* __restrict__ Cout)
{
  const int gx = gridDim.x, gy = gridDim.y;
  const int nwg = gx * gy * gridDim.z;
  int flat = (blockIdx.z * gy + blockIdx.y) * gx + blockIdx.x;
  int logical = xcd_swz(flat, nwg);
  const int bz = logical / (gx * gy);
  int rem = logical - bz * gx * gy;
  const int by = rem / gx;
  const int bx = rem - by * gx;

  const bhalf* Apad = Ab + (long long)bz * 37636 * 256;
  const int m0 = by * 128, n0 = bx * 128;
  __shared__ __align__(16) bhalf As[128 * 32];
  __shared__ __align__(16) bhalf Bs[128 * 32];
  const int t = threadIdx.x;
  const int lane = t & 63;
  const int w = t >> 6;
  const int wbase = t & 192;
  const int wm = (w >> 1) * 64, wn = (w & 1) * 64;
  const int fr = lane & 15, fg = lane >> 4;
  int rowA[2], py[2], px[2], kcg[2];
#pragma unroll
  for (int j = 0; j < 2; ++j) {
    int id = t + j * 256;
    rowA[j] = id >> 2;
    kcg[j] = (((id & 3) ^ swz(rowA[j])) * 8);
    int m = m0 + rowA[j];
    py[j] = m / 192; px[j] = m % 192;
  }
  f32x4 acc[4][4] = {};
  for (int s = 0; s < 72; ++s) {
    const int cib = s / 9, tap = s % 9;
    const int ty = tap / 3, tx = tap % 3;
#pragma unroll
    for (int j = 0; j < 2; ++j) {
      GLOAD_LDS16(Apad + ((long long)(py[j] + ty) * 194 + px[j] + tx) * 256 + cib * 32 + kcg[j],
                  As + (wbase + j * 256) * 8);
      GLOAD_LDS16(Bt + (long long)(n0 + rowA[j]) * 2304 + s * 32 + kcg[j],
                  Bs + (wbase + j * 256) * 8);
    }
    __syncthreads();
    bh8 af[4], bf[4];
#pragma unroll
    for (int mi = 0; mi < 4; ++mi) {
      int r = wm + mi * 16 + fr;
      af[mi] = *(const bh8*)(As + r * 32 + ((fg ^ swz(r)) * 8));
    }
#pragma unroll
    for (int ni = 0; ni < 4; ++ni) {
      int r = wn + ni * 16 + fr;
      bf[ni] = *(const bh8*)(Bs + r * 32 + ((fg ^ swz(r)) * 8));
    }
#pragma unroll
    for (int mi = 0; mi < 4; ++mi)
#pragma unroll
      for (int ni = 0; ni < 4; ++ni)
        acc[mi][ni] = __builtin_amdgcn_mfma_f32_16x16x32_bf16(af[mi], bf[ni], acc[mi][ni], 0, 0, 0);
    __syncthreads();
  }
  bhalf* Cb = Cout + (long long)bz * 36864 * 256;
#pragma unroll
  for (int mi = 0; mi < 4; ++mi)
#pragma unroll
    for (int r = 0; r < 4; ++r) {
      int m = m0 + wm + mi * 16 + fg * 4 + r;
#pragma unroll
      for (int ni = 0; ni < 4; ++ni) {
        int n = n0 + wn + ni * 16 + fr;
        Cb[(long long)m * 256 + n] = (bhalf)acc[mi][ni][r];
      }
    }
}

// =====================================================================
// Weight transpose+convert: W [z][Kd][Nd] fp32 -> out [z (zdst stride)][Nd][Kd] bf16
// =====================================================================
__global__ void twcvt_kernel(const float* __restrict__ Wsrc, bhalf* __restrict__ out,
                             int Kd, int Nd, long long zdst)
{
  __shared__ float tile[32][33];
  long long zi = (long long)blockIdx.z * Kd * Nd;
  long long zo = (long long)blockIdx.z * zdst;
  int n0 = blockIdx.x * 32, k0 = blockIdx.y * 32;
#pragma unroll
  for (int j = 0; j < 4; ++j) {
    int kk = threadIdx.y + 8 * j;
    tile[kk][threadIdx.x] = Wsrc[zi + (long long)(k0 + kk) * Nd + n0 + threadIdx.x];
  }
  __syncthreads();
#pragma unroll
  for (int j = 0; j < 4; ++j) {
    int nn = threadIdx.y + 8 * j;
    out[zo + (long long)(n0 + nn) * Kd + k0 + threadIdx.x] = (bhalf)tile[threadIdx.x][nn];
  }
}

__global__ void tfeat_kernel(const float* __restrict__ Fsrc, bhalf* __restrict__ out,
                             int Ci, int HW)
{
  __shared__ float tile[32][33];
  long long zo = (long long)blockIdx.z * Ci * HW;
  int hw0 = blockIdx.x * 32, c0 = blockIdx.y * 32;
#pragma unroll
  for (int j = 0; j < 4; ++j) {
    int cc = threadIdx.y + 8 * j;
    tile[cc][threadIdx.x] = Fsrc[zo + (long long)(c0 + cc) * HW + hw0 + threadIdx.x];
  }
  __syncthreads();
#pragma unroll
  for (int j = 0; j < 4; ++j) {
    int hh = threadIdx.y + 8 * j;
    out[zo + (long long)(hw0 + hh) * Ci + c0 + threadIdx.x] = (bhalf)tile[threadIdx.x][hh];
  }
}

__global__ void cvt_kernel(const float* __restrict__ in, bhalf* __restrict__ out, int n)
{
  int i = blockIdx.x * 256 + threadIdx.x;
  if (i < n) out[i] = (bhalf)in[i];
}

// fpn_w [co][ci][9] -> fpnT[co][cib*288 + tap*32 + cil]
__global__ void fpnw_kernel(const float* __restrict__ Wsrc, bhalf* __restrict__ out)
{
  int o = blockIdx.x * 256 + threadIdx.x;
  if (o >= 256 * 2304) return;
  int co = o / 2304, r = o % 2304;
  int cib = r / 288, rr = r % 288, tap = rr >> 5, cil = rr & 31;
  int ci = cib * 32 + cil;
  out[o] = (bhalf)Wsrc[(co * 256 + ci) * 9 + tap];
}

// concat off/aw biases -> [l][288]
__global__ void biascat_kernel(const float* __restrict__ ob, const float* __restrict__ ab,
                               float* __restrict__ out)
{
  int l = blockIdx.x, t = threadIdx.x;
  if (t < 288) out[l * 288 + t] = (t < 192) ? ob[l * 192 + t] : ab[l * 96 + t - 192];
}

__global__ void zero16_kernel(uint4* __restrict__ p, long long n16)
{
  long long i = (long long)blockIdx.x * 256 + threadIdx.x;
  if (i < n16) p[i] = make_uint4(0u, 0u, 0u, 0u);
}

// =====================================================================
// Sine positional embedding + level embed
// =====================================================================
__global__ void pos_kernel(float* __restrict__ pos, const float* __restrict__ level_embed)
{
  int i = blockIdx.x, c = threadIdx.x;
  int lvl, Wq, loc;
  if (i < 576)       { lvl = 0; Wq = 24; loc = i; }
  else if (i < 2880) { lvl = 1; Wq = 48; loc = i - 576; }
  else               { lvl = 2; Wq = 96; loc = i - 2880; }
  int h = loc / Wq, wcol = loc % Wq;
  int cc = c & 127;
  float coord = (c < 128) ? (float)(h + 1) : (float)(wcol + 1);
  float denom = (float)Wq + 1e-6f;
  float v = coord / denom * 6.28318530717958647692f;
  float tp = powf(10000.0f, (float)(cc & ~1) * (1.0f / 128.0f));
  float ang = v / tp;
  float val = (cc & 1) ? cosf(ang) : sinf(ang);
  pos[(long long)i * 256 + c] = val + level_embed[lvl * 256 + c];
}

// =====================================================================
// GN stats, two-pass, coalesced.
// =====================================================================
__global__ __launch_bounds__(256) void gn_part_kernel(const void* __restrict__ X,
    float* __restrict__ part, int HW, int isBf16, int nch)
{
  const int b = blockIdx.y, ch = blockIdx.x;
  const int rows = (HW + nch - 1) / nch;
  const int r0 = ch * rows;
  const int r1 = min(r0 + rows, HW);
  const int cg = threadIdx.x & 31;
  const int ro = threadIdx.x >> 5;
  float s = 0.f, s2 = 0.f;
  if (isBf16) {
    const bhalf* p = (const bhalf*)X + (long long)b * HW * 256 + cg * 8;
    for (int r = r0 + ro; r < r1; r += 8) {
      bh8 v = *(const bh8*)(p + (long long)r * 256);
#pragma unroll
      for (int j = 0; j < 8; ++j) { float f = (float)v[j]; s += f; s2 = fmaf(f, f, s2); }
    }
  } else {
    const float* p = (const float*)X + (long long)b * HW * 256 + cg * 8;
    for (int r = r0 + ro; r < r1; r += 8) {
      f32x4 v0 = *(const f32x4*)(p + (long long)r * 256);
      f32x4 v1 = *(const f32x4*)(p + (long long)r * 256 + 4);
#pragma unroll
      for (int j = 0; j < 4; ++j) { s += v0[j]; s2 = fmaf(v0[j], v0[j], s2); }
#pragma unroll
      for (int j = 0; j < 4; ++j) { s += v1[j]; s2 = fmaf(v1[j], v1[j], s2); }
    }
  }
  __shared__ float sh[2][8][32];
  sh[0][ro][cg] = s; sh[1][ro][cg] = s2;
  __syncthreads();
  if (threadIdx.x < 32) {
    float S = 0.f, S2 = 0.f;
#pragma unroll
    for (int k = 0; k < 8; ++k) { S += sh[0][k][threadIdx.x]; S2 += sh[1][k][threadIdx.x]; }
    long long o = ((long long)(b * 32 + threadIdx.x) * nch + ch) * 2;
    part[o] = S; part[o + 1] = S2;
  }
}

__global__ __launch_bounds__(64) void gn_fin_kernel(const float* __restrict__ part,
    float* __restrict__ stats, int nch, int HW)
{
  const int bg = blockIdx.x;
  float s = 0.f, s2 = 0.f;
  for (int i = threadIdx.x; i < nch; i += 64) {
    long long o = ((long long)bg * nch + i) * 2;
    s += part[o]; s2 += part[o + 1];
  }
#pragma unroll
  for (int o = 32; o > 0; o >>= 1) { s += __shfl_down(s, o); s2 += __shfl_down(s2, o); }
  if (threadIdx.x == 0) {
    float inv = 1.f / (float)(HW * 8);
    float mean = s * inv;
    float var = s2 * inv - mean * mean;
    stats[bg * 2] = mean;
    stats[bg * 2 + 1] = rsqrtf(var + 1e-5f);
  }
}

// =====================================================================
// GN apply -> src fp32 + srcb bf16 + qb bf16 (src+pos)
// =====================================================================
__global__ void gn_apply_rm_kernel(const float* __restrict__ T, const float* __restrict__ stats,
    const float* __restrict__ gs, const float* __restrict__ gb,
    float* __restrict__ src, bhalf* __restrict__ srcb, bhalf* __restrict__ qb,
    const float* __restrict__ pos, int HW, int startRow)
{
  long long idx = (long long)blockIdx.x * 256 + threadIdx.x;
  int c = threadIdx.x & 255;
  long long row = idx >> 8;
  int b = (int)(row / HW);
  long long hw = row - (long long)b * HW;
  int g = c >> 3;
  float v = T[idx];
  v = (v - stats[(b * 32 + g) * 2]) * stats[(b * 32 + g) * 2 + 1] * gs[c] + gb[c];
  long long pr = (startRow + hw) * 256 + c;
  long long o = (long long)b * NLEN * 256 + pr;
  src[o] = v;
  srcb[o] = (bhalf)v;
  qb[o] = (bhalf)(v + pos[pr]);
}

// =====================================================================
// src = LayerNorm(src + resid); writes srcb bf16, optional qb=y+pos
// =====================================================================
__global__ __launch_bounds__(256) void ln_kernel(float* __restrict__ src,
    const float* __restrict__ resid, const float* __restrict__ s, const float* __restrict__ bsh,
    bhalf* __restrict__ srcb, bhalf* __restrict__ qbOut, const float* __restrict__ pos)
{
  long long r = blockIdx.x;
  int c = threadIdx.x;
  float v = src[r * 256 + c] + resid[r * 256 + c];
  float sum = v, sq = v * v;
#pragma unroll
  for (int o = 32; o > 0; o >>= 1) { sum += __shfl_down(sum, o); sq += __shfl_down(sq, o); }
  __shared__ float sh[2][4];
  int lane = c & 63, wv = c >> 6;
  if (lane == 0) { sh[0][wv] = sum; sh[1][wv] = sq; }
  __syncthreads();
  float S  = sh[0][0] + sh[0][1] + sh[0][2] + sh[0][3];
  float S2 = sh[1][0] + sh[1][1] + sh[1][2] + sh[1][3];
  float mean = S * (1.f / 256.f);
  float var = S2 * (1.f / 256.f) - mean * mean;
  float rstd = rsqrtf(var + 1e-5f);
  float y = (v - mean) * rstd * s[c] + bsh[c];
  src[r * 256 + c] = y;
  srcb[r * 256 + c] = (bhalf)y;
  if (qbOut) {
    int pr = (int)(r % NLEN);
    qbOut[r * 256 + c] = (bhalf)(y + pos[(long long)pr * 256 + c]);
  }
}

// =====================================================================
// MSDeformAttn sampling: 8 channels/lane (16B gathers), 32 lanes/query,
// 2 queries/wave, 8 queries/block. Fused softmax over 12 logits.
// offaw fp32 [B*LEN][288]: cols 0..191 offsets, 192..287 aw logits.
// =====================================================================
__global__ __launch_bounds__(256) void deform_kernel(const bhalf* __restrict__ value,
    const float* __restrict__ offaw, bhalf* __restrict__ out)
{
  const int t = threadIdx.x;
  const int q = t >> 5;            // query slot in block, 0..7
  const int sub = t & 31;          // lane within query
  const int bi = blockIdx.x * 8 + q;
  const int i = bi % NLEN;
  const int bbase = bi - i;
  const int c0 = sub * 8;          // 8 channels per lane
  const int head = sub >> 2;       // 4 lanes per head
  int loc, Wq;
  if (i < 576)       { Wq = 24; loc = i; }
  else if (i < 2880) { Wq = 48; loc = i - 576; }
  else               { Wq = 96; loc = i - 2880; }
  const float rx = ((loc % Wq) + 0.5f) / (float)Wq;
  const float ry = ((loc / Wq) + 0.5f) / (float)Wq;
  const float* offp = offaw + (long long)bi * 288 + head * 24;
  const float* awp  = offaw + (long long)bi * 288 + 192 + head * 12;
  float aw[12]; float mx = -1e30f;
#pragma unroll
  for (int j = 0; j < 12; ++j) { aw[j] = awp[j]; mx = fmaxf(mx, aw[j]); }
  float ssum = 0.f;
#pragma unroll
  for (int j = 0; j < 12; ++j) { aw[j] = __expf(aw[j] - mx); ssum += aw[j]; }
  const float sinv = 1.f / ssum;
  float acc[8] = {};
  const int starts[3] = {0, 576, 2880};
  const int Ls[3] = {24, 48, 96};
#pragma unroll
  for (int l = 0; l < 3; ++l) {
    const int Wl = Ls[l];
    const float fW = (float)Wl;
    const bhalf* vb = value + (long long)(bbase + starts[l]) * 256 + c0;
#pragma unroll
    for (int p = 0; p < 4; ++p) {
      const float ox = offp[l * 8 + p * 2], oy = offp[l * 8 + p * 2 + 1];
      const float a = aw[l * 4 + p] * sinv;
      const float x = (rx + ox / fW) * fW - 0.5f;
      const float y = (ry + oy / fW) * fW - 0.5f;
      const float x0f = floorf(x), y0f = floorf(y);
      const float wx = x - x0f, wy = y - y0f;
      const int x0 = (int)x0f, y0 = (int)y0f;
      const int x1 = x0 + 1, y1 = y0 + 1;
      const bool xv0 = (x0 >= 0) & (x0 < Wl);
      const bool xv1 = (x1 >= 0) & (x1 < Wl);
      const bool yv0 = (y0 >= 0) & (y0 < Wl);
      const bool yv1 = (y1 >= 0) & (y1 < Wl);
      const int cx0 = min(max(x0, 0), Wl - 1), cx1 = min(max(x1, 0), Wl - 1);
      const int cy0 = min(max(y0, 0), Wl - 1), cy1 = min(max(y1, 0), Wl - 1);
      const float w00 = (xv0 && yv0) ? (1.f - wx) * (1.f - wy) * a : 0.f;
      const float w01 = (xv1 && yv0) ? wx * (1.f - wy) * a : 0.f;
      const float w10 = (xv0 && yv1) ? (1.f - wx) * wy * a : 0.f;
      const float w11 = (xv1 && yv1) ? wx * wy * a : 0.f;
      const bh8 g00 = *(const bh8*)(vb + (cy0 * Wl + cx0) * 256);
      const bh8 g01 = *(const bh8*)(vb + (cy0 * Wl + cx1) * 256);
      const bh8 g10 = *(const bh8*)(vb + (cy1 * Wl + cx0) * 256);
      const bh8 g11 = *(const bh8*)(vb + (cy1 * Wl + cx1) * 256);
#pragma unroll
      for (int e = 0; e < 8; ++e)
        acc[e] = fmaf(w00, (float)g00[e], fmaf(w01, (float)g01[e],
                 fmaf(w10, (float)g10[e], fmaf(w11, (float)g11[e], acc[e]))));
    }
  }
  bh8 o;
#pragma unroll
  for (int e = 0; e < 8; ++e) o[e] = (bhalf)acc[e];
  *(bh8*)(out + (long long)bi * 256 + c0) = o;
}

// =====================================================================
// src[b][startRow+hw][c] -> out[b][c][hw]
// =====================================================================
__global__ void transpose_out_kernel(const float* __restrict__ src, float* __restrict__ out,
    int HW, int startRow)
{
  __shared__ float tile[32][33];
  int b = blockIdx.z;
  int w0 = blockIdx.x * 32, c0 = blockIdx.y * 32;
#pragma unroll
  for (int j = 0; j < 4; ++j) {
    int wl = threadIdx.y + 8 * j;
    tile[wl][threadIdx.x] = src[((long long)b * NLEN + startRow + w0 + wl) * 256 + c0 + threadIdx.x];
  }
  __syncthreads();
#pragma unroll
  for (int j = 0; j < 4; ++j) {
    int cl = threadIdx.y + 8 * j;
    out[((long long)b * 256 + c0 + cl) * HW + w0 + threadIdx.x] = tile[threadIdx.x][cl];
  }
}

// =====================================================================
// latb = GN(lat) + upsample2x(src lvl2), zero-padded layout
// =====================================================================
__global__ void lat_finish_rm_kernel(const bhalf* __restrict__ lat, const float* __restrict__ stats,
    const float* __restrict__ gs, const float* __restrict__ gb,
    const float* __restrict__ src, bhalf* __restrict__ latb)
{
  long long idx = (long long)blockIdx.x * 256 + threadIdx.x;
  int c = threadIdx.x & 255;
  long long row = idx >> 8;
  int b = (int)(row / 36864);
  int p = (int)(row - (long long)b * 36864);
  int y = p / 192, x = p % 192;
  int g = c >> 3;
  float v = (float)lat[idx];
  v = (v - stats[(b * 32 + g) * 2]) * stats[(b * 32 + g) * 2 + 1] * gs[c] + gb[c];
  float ys = fmaxf(y * 0.5f - 0.25f, 0.f);
  float xs = fmaxf(x * 0.5f - 0.25f, 0.f);
  int y0 = (int)ys; float wy = ys - (float)y0; int y1 = min(y0 + 1, 95);
  int x0 = (int)xs; float wx = xs - (float)x0; int x1 = min(x0 + 1, 95);
  const float* sp = src + ((long long)b * NLEN + 2880) * 256 + c;
  float r0 = sp[(long long)(y0 * 96 + x0) * 256] * (1.f - wx) + sp[(long long)(y0 * 96 + x1) * 256] * wx;
  float r1 = sp[(long long)(y1 * 96 + x0) * 256] * (1.f - wx) + sp[(long long)(y1 * 96 + x1) * 256] * wx;
  latb[((long long)b * 37636 + (long long)(y + 1) * 194 + (x + 1)) * 256 + c]
      = (bhalf)(v + r0 * (1.f - wy) + r1 * wy);
}

// =====================================================================
// Final GN+ReLU+transpose: convC bf16 [b][hw][c] -> Y fp32 [b][c][hw]
// =====================================================================
__global__ void gn_relu_tr_kernel(const bhalf* __restrict__ convC, const float* __restrict__ stats,
    const float* __restrict__ gs, const float* __restrict__ gb, float* __restrict__ Y)
{
  __shared__ float tile[32][33];
  int b = blockIdx.z;
  int hw0 = blockIdx.x * 32, c0 = blockIdx.y * 32;
#pragma unroll
  for (int j = 0; j < 4; ++j) {
    int hwl = threadIdx.y + 8 * j;
    int c = c0 + threadIdx.x;
    int g = c >> 3;
    float v = (float)convC[((long long)b * 36864 + hw0 + hwl) * 256 + c];
    v = (v - stats[(b * 32 + g) * 2]) * stats[(b * 32 + g) * 2 + 1] * gs[c] + gb[c];
    tile[hwl][threadIdx.x] = fmaxf(v, 0.f);
  }
  __syncthreads();
#pragma unroll
  for (int j = 0; j < 4; ++j) {
    int cl = threadIdx.y + 8 * j;
    Y[((long long)b * 256 + c0 + cl) * 36864 + hw0 + threadIdx.x] = tile[threadIdx.x][cl];
  }
}

// =====================================================================
extern "C" void kernel_launch(void* const* d_in, const int* in_sizes, int n_in,
                              void* d_out, int out_size, void* d_ws, size_t ws_size,
                              hipStream_t stream)
{
  const float* res2 = (const float*)d_in[0];
  const float* res3 = (const float*)d_in[1];
  const float* res4 = (const float*)d_in[2];
  const float* res5 = (const float*)d_in[3];
  const float* pw[3]  = {(const float*)d_in[4],  (const float*)d_in[8],  (const float*)d_in[12]};
  const float* pb[3]  = {(const float*)d_in[5],  (const float*)d_in[9],  (const float*)d_in[13]};
  const float* gss[3] = {(const float*)d_in[6],  (const float*)d_in[10], (const float*)d_in[14]};
  const float* gbb[3] = {(const float*)d_in[7],  (const float*)d_in[11], (const float*)d_in[15]};
  const float* level_embed = (const float*)d_in[16];
  const float* off_w = (const float*)d_in[17];
  const float* off_b = (const float*)d_in[18];
  const float* aw_w  = (const float*)d_in[19];
  const float* aw_b  = (const float*)d_in[20];
  const float* val_w = (const float*)d_in[21];
  const float* val_b = (const float*)d_in[22];
  const float* out_w = (const float*)d_in[23];
  const float* out_b = (const float*)d_in[24];
  const float* ln1_s = (const float*)d_in[25];
  const float* ln1_b = (const float*)d_in[26];
  const float* ffn1_w = (const float*)d_in[27];
  const float* ffn1_b = (const float*)d_in[28];
  const float* ffn2_w = (const float*)d_in[29];
  const float* ffn2_b = (const float*)d_in[30];
  const float* ln2_s = (const float*)d_in[31];
  const float* ln2_b = (const float*)d_in[32];
  const float* lat_w = (const float*)d_in[33];
  const float* lat_gs = (const float*)d_in[34];
  const float* lat_gb = (const float*)d_in[35];
  const float* fpn_w = (const float*)d_in[36];
  const float* fpn_gs = (const float*)d_in[37];
  const float* fpn_gb = (const float*)d_in[38];

  char* W = (char*)d_ws;
  float* src   = (float*)(W + 0);
  float* pos   = (float*)(W + 24772608LL);
  float* tmp   = (float*)(W + 37158912LL);
  bhalf* srcb  = (bhalf*)(W + 61931520LL);
  bhalf* wreg  = (bhalf*)(W + 74317824LL);
  float* stats = (float*)(W + 86212608LL);
  float* part  = (float*)(W + 86213120LL);
  float* offaw_b = (float*)(W + 86278656LL);
  char*  U     = W + 86286848LL;

  bhalf* valT   = wreg + 0;
  bhalf* offawT = wreg + 393216;
  bhalf* outT   = wreg + 835584;
  bhalf* f1T    = wreg + 1228800;
  bhalf* f2T    = wreg + 2801664;
  bhalf* pwb5   = wreg + 4374528;
  bhalf* pwb4   = wreg + 4898816;
  bhalf* pwb3   = wreg + 5160960;
  bhalf* latwb  = wreg + 5292032;
  bhalf* fpnT   = wreg + 5357568;

  bhalf* qb      = (bhalf*)(U + 0);
  bhalf* valueb  = (bhalf*)(U + 12386304LL);
  bhalf* sampb   = (bhalf*)(U + 24772608LL);
  float* offbuf  = (float*)(U + 37158912LL);
  bhalf* hbuf    = (bhalf*)(U + 65028096LL);
  bhalf* featT   = (bhalf*)(U + 24772608LL);   // projection-phase only
  bhalf* res2T   = (bhalf*)(U + 0);
  bhalf* latbf   = (bhalf*)(U + 37748736LL);
  bhalf* latb    = (bhalf*)(U + 75497472LL);

  float* Yout = (float*)d_out;
  float* out0 = Yout + 18874368LL;
  float* out1 = Yout + 19169280LL;
  float* out2 = Yout + 20348928LL;

  const int M = BB * NLEN;  // 24192

  // ---- weight prep ----
  twcvt_kernel<<<dim3(8, 8, 6), dim3(32, 8), 0, stream>>>(val_w, valT, 256, 256, 65536LL);
  twcvt_kernel<<<dim3(6, 8, 6), dim3(32, 8), 0, stream>>>(off_w, offawT, 256, 192, 73728LL);
  twcvt_kernel<<<dim3(3, 8, 6), dim3(32, 8), 0, stream>>>(aw_w, offawT + 192 * 256, 256, 96, 73728LL);
  twcvt_kernel<<<dim3(8, 8, 6), dim3(32, 8), 0, stream>>>(out_w, outT, 256, 256, 65536LL);
  twcvt_kernel<<<dim3(32, 8, 6), dim3(32, 8), 0, stream>>>(ffn1_w, f1T, 256, 1024, 262144LL);
  twcvt_kernel<<<dim3(8, 32, 6), dim3(32, 8), 0, stream>>>(ffn2_w, f2T, 1024, 256, 262144LL);
  biascat_kernel<<<dim3(6), dim3(288), 0, stream>>>(off_b, aw_b, offaw_b);
  cvt_kernel<<<dim3(2048), dim3(256), 0, stream>>>(pw[0], pwb5, 524288);
  cvt_kernel<<<dim3(1024), dim3(256), 0, stream>>>(pw[1], pwb4, 262144);
  cvt_kernel<<<dim3(512),  dim3(256), 0, stream>>>(pw[2], pwb3, 131072);
  cvt_kernel<<<dim3(256),  dim3(256), 0, stream>>>(lat_w, latwb, 65536);
  fpnw_kernel<<<dim3(2304), dim3(256), 0, stream>>>(fpn_w, fpnT);

  // ---- positional embedding ----
  pos_kernel<<<dim3(NLEN), dim3(256), 0, stream>>>(pos, level_embed);

  // ---- input projections + GN -> src/srcb/qb ----
  const float* feats[3] = {res5, res4, res3};
  const bhalf* pwbs[3] = {pwb5, pwb4, pwb3};
  const int cins[3] = {2048, 1024, 512};
  const int HWs[3] = {576, 2304, 9216};
  const int startsHost[3] = {0, 576, 2880};
  const int nchs[3] = {16, 64, 128};
  for (int lvl = 0; lvl < 3; ++lvl) {
    int HW = HWs[lvl], cin = cins[lvl], nch = nchs[lvl];
    tfeat_kernel<<<dim3(HW / 32, cin / 32, BB), dim3(32, 8), 0, stream>>>(feats[lvl], featT, cin, HW);
    bgemm_kernel<<<dim3(2, (HW + 127) / 128, BB), dim3(256), 0, stream>>>(
        featT, pwbs[lvl], pb[lvl], tmp, HW, 256, cin,
        (long long)HW * cin, 0LL, (long long)HW * 256, 0, 0);
    gn_part_kernel<<<dim3(nch, BB), dim3(256), 0, stream>>>(tmp, part, HW, 0, nch);
    gn_fin_kernel<<<dim3(64), dim3(64), 0, stream>>>(part, stats, nch, HW);
    gn_apply_rm_kernel<<<dim3(BB * HW), dim3(256), 0, stream>>>(
        tmp, stats, gss[lvl], gbb[lvl], src, srcb, qb, pos, HW, startsHost[lvl]);
  }

  // ---- 6 encoder layers ----
  for (int l = 0; l < 6; ++l) {
    bgemm_kernel<<<dim3(2, M / 128, 1), dim3(256), 0, stream>>>(
        srcb, valT + (long long)l * 65536, val_b + l * 256, valueb,
        M, 256, 256, 0LL, 0LL, 0LL, 1, 0);
    bgemm_kernel<<<dim3(3, M / 128, 1), dim3(256), 0, stream>>>(
        qb, offawT + (long long)l * 73728, offaw_b + l * 288, offbuf,
        M, 288, 256, 0LL, 0LL, 0LL, 0, 0);
    deform_kernel<<<dim3(M / 8), dim3(256), 0, stream>>>(valueb, offbuf, sampb);
    bgemm_kernel<<<dim3(2, M / 128, 1), dim3(256), 0, stream>>>(
        sampb, outT + (long long)l * 65536, out_b + l * 256, tmp,
        M, 256, 256, 0LL, 0LL, 0LL, 0, 0);
    ln_kernel<<<dim3(M), dim3(256), 0, stream>>>(src, tmp, ln1_s + l * 256, ln1_b + l * 256,
                                                 srcb, nullptr, nullptr);
    bgemm_kernel<<<dim3(8, M / 128, 1), dim3(256), 0, stream>>>(
        srcb, f1T + (long long)l * 262144, ffn1_b + l * 1024, hbuf,
        M, 1024, 256, 0LL, 0LL, 0LL, 1, 1);
    bgemm_kernel<<<dim3(2, M / 128, 1), dim3(256), 0, stream>>>(
        hbuf, f2T + (long long)l * 262144, ffn2_b + l * 256, tmp,
        M, 256, 1024, 0LL, 0LL, 0LL, 0, 0);
    ln_kernel<<<dim3(M), dim3(256), 0, stream>>>(src, tmp, ln2_s + l * 256, ln2_b + l * 256,
                                                 srcb, qb, pos);
  }

  // ---- output transposes ----
  float* outsPtr[3] = {out0, out1, out2};
  for (int lvl = 0; lvl < 3; ++lvl) {
    transpose_out_kernel<<<dim3(HWs[lvl] / 32, 8, BB), dim3(32, 8), 0, stream>>>(
        src, outsPtr[lvl], HWs[lvl], startsHost[lvl]);
  }

  // ---- FPN ----
  tfeat_kernel<<<dim3(1152, 8, BB), dim3(32, 8), 0, stream>>>(res2, res2T, 256, 36864);
  bgemm_kernel<<<dim3(2, 288, BB), dim3(256), 0, stream>>>(
      res2T, latwb, nullptr, latbf, 36864, 256, 256,
      36864LL * 256, 0LL, 36864LL * 256, 1, 0);
  gn_part_kernel<<<dim3(128, BB), dim3(256), 0, stream>>>(latbf, part, 36864, 1, 128);
  gn_fin_kernel<<<dim3(64), dim3(64), 0, stream>>>(part, stats, 128, 36864);
  zero16_kernel<<<dim3(9410), dim3(256), 0, stream>>>((uint4*)latb, 2408704LL);
  lat_finish_rm_kernel<<<dim3(73728), dim3(256), 0, stream>>>(latbf, stats, lat_gs, lat_gb, src, latb);
  bgemm_conv_kernel<<<dim3(2, 288, BB), dim3(256), 0, stream>>>(latb, fpnT, latbf);
  gn_part_kernel<<<dim3(128, BB), dim3(256), 0, stream>>>(latbf, part, 36864, 1, 128);
  gn_fin_kernel<<<dim3(64), dim3(64), 0, stream>>>(part, stats, 128, 36864);
  gn_relu_tr_kernel<<<dim3(1152, 8, BB), dim3(32, 8), 0, stream>>>(latbf, stats, fpn_gs, fpn_gb, Yout);
}

// Round 10
// 1781.370 us; speedup vs baseline: 4.5238x; 1.1455x over previous
//
#include <hip/hip_runtime.h>
#include <math.h>

#define NLEN 12096
#define BB 2

typedef __bf16 bhalf;
typedef bhalf bh8 __attribute__((ext_vector_type(8)));
typedef bhalf bh4 __attribute__((ext_vector_type(4)));
typedef float f32x4 __attribute__((ext_vector_type(4)));

// LDS 16B-slot swizzle (verified round 8: bank conflicts -> 0).
__device__ __forceinline__ int swz(int row) { return (row >> 1) & 3; }

// Bijective XCD-chunk swizzle (T1, m204).
__device__ __forceinline__ int xcd_swz(int id, int nwg) {
  int q = nwg >> 3, r = nwg & 7;
  int xcd = id & 7, pos = id >> 3;
  int base = (xcd < r) ? xcd * (q + 1) : r * (q + 1) + (xcd - r) * q;
  return base + pos;
}

#define GLOAD_LDS16(g, l) \
  __builtin_amdgcn_global_load_lds( \
      (const __attribute__((address_space(1))) unsigned int*)(g), \
      (__attribute__((address_space(3))) unsigned int*)(l), 16, 0, 0)

// =====================================================================
// bf16 MFMA GEMM: C[M,N] = A[M,K] @ Bt[N,K]^T  (+bias[n]) (+relu)
// Tile 128x128, BK=32, 4 waves, global_load_lds staging.
// =====================================================================
__global__ __launch_bounds__(256) void bgemm_kernel(
    const bhalf* __restrict__ A, const bhalf* __restrict__ Bt,
    const float* __restrict__ bias, void* __restrict__ Cout,
    int M, int N, int K, long long sA, long long sB, long long sC,
    int outBf16, int relu)
{
  const int gx = gridDim.x, gy = gridDim.y;
  const int nwg = gx * gy * gridDim.z;
  int flat = (blockIdx.z * gy + blockIdx.y) * gx + blockIdx.x;
  int logical = xcd_swz(flat, nwg);
  const int bz = logical / (gx * gy);
  int rem = logical - bz * gx * gy;
  const int by = rem / gx;
  const int bx = rem - by * gx;

  A += bz * sA; Bt += bz * sB;
  const int m0 = by * 128, n0 = bx * 128;
  __shared__ __align__(16) bhalf As[128 * 32];
  __shared__ __align__(16) bhalf Bs[128 * 32];
  const int t = threadIdx.x;
  const int lane = t & 63;
  const int w = t >> 6;
  const int wbase = t & 192;
  const int wm = (w >> 1) * 64, wn = (w & 1) * 64;
  const int fr = lane & 15, fg = lane >> 4;
  f32x4 acc[4][4] = {};
  for (int k0 = 0; k0 < K; k0 += 32) {
#pragma unroll
    for (int j = 0; j < 2; ++j) {
      int id = t + j * 256;
      int row = id >> 2, up = id & 3;
      int kcg = ((up ^ swz(row)) * 8);
      int m = m0 + row; m = (m < M) ? m : (M - 1);
      GLOAD_LDS16(A + (long long)m * K + k0 + kcg, As + (wbase + j * 256) * 8);
      int n = n0 + row; n = (n < N) ? n : (N - 1);
      GLOAD_LDS16(Bt + (long long)n * K + k0 + kcg, Bs + (wbase + j * 256) * 8);
    }
    __syncthreads();
    bh8 af[4], bf[4];
#pragma unroll
    for (int mi = 0; mi < 4; ++mi) {
      int r = wm + mi * 16 + fr;
      af[mi] = *(const bh8*)(As + r * 32 + ((fg ^ swz(r)) * 8));
    }
#pragma unroll
    for (int ni = 0; ni < 4; ++ni) {
      int r = wn + ni * 16 + fr;
      bf[ni] = *(const bh8*)(Bs + r * 32 + ((fg ^ swz(r)) * 8));
    }
#pragma unroll
    for (int mi = 0; mi < 4; ++mi)
#pragma unroll
      for (int ni = 0; ni < 4; ++ni)
        acc[mi][ni] = __builtin_amdgcn_mfma_f32_16x16x32_bf16(af[mi], bf[ni], acc[mi][ni], 0, 0, 0);
    __syncthreads();
  }
  float* Cf = (float*)Cout + bz * sC;
  bhalf* Cb = (bhalf*)Cout + bz * sC;
#pragma unroll
  for (int mi = 0; mi < 4; ++mi) {
#pragma unroll
    for (int r = 0; r < 4; ++r) {
      int m = m0 + wm + mi * 16 + fg * 4 + r;
      if (m >= M) continue;
#pragma unroll
      for (int ni = 0; ni < 4; ++ni) {
        int n = n0 + wn + ni * 16 + fr;
        if (n >= N) continue;
        float v = acc[mi][ni][r];
        if (bias) v += bias[n];
        if (relu) v = fmaxf(v, 0.f);
        if (outBf16) Cb[(long long)m * N + n] = (bhalf)v;
        else         Cf[(long long)m * N + n] = v;
      }
    }
  }
}

// =====================================================================
// Fused GEMM + bias + residual + LayerNorm. N fixed = 256 (full row in
// tile). Tile 64x256, 4 waves (2 row-halves x 2 col-halves).
// y = LN(src + A@Bt^T + bias); writes src fp32, srcb bf16, qb = y+pos.
// M must be divisible by 64.
// =====================================================================
__global__ __launch_bounds__(256) void bgemm_ln_kernel(
    const bhalf* __restrict__ A, const bhalf* __restrict__ Bt,
    const float* __restrict__ bias,
    float* __restrict__ src, bhalf* __restrict__ srcb,
    bhalf* __restrict__ qbOut, const float* __restrict__ pos,
    const float* __restrict__ ls, const float* __restrict__ lb,
    int M, int K)
{
  const int nwg = gridDim.x;
  const int bid = xcd_swz(blockIdx.x, nwg);
  const int m0 = bid * 64;
  // combined staging: rows 0..63 = A-tile, rows 64..319 = Bt (all 256)
  __shared__ __align__(16) bhalf Ls[320 * 32];
  bhalf* AsL = Ls;
  bhalf* BsL = Ls + 64 * 32;
  __shared__ float shS[64][2], shQ[64][2];
  const int t = threadIdx.x;
  const int lane = t & 63;
  const int w = t >> 6;
  const int wbase = t & 192;
  const int wm = (w >> 1) * 32, wn = (w & 1) * 128;
  const int fr = lane & 15, fg = lane >> 4;
  f32x4 acc[2][8] = {};
  for (int k0 = 0; k0 < K; k0 += 32) {
#pragma unroll
    for (int j = 0; j < 5; ++j) {
      int id = t + j * 256;
      int row = id >> 2, up = id & 3;
      int kcg = ((up ^ swz(row)) * 8);
      const bhalf* gsrc = (row < 64)
          ? (A + (long long)(m0 + row) * K + k0 + kcg)
          : (Bt + (long long)(row - 64) * K + k0 + kcg);
      GLOAD_LDS16(gsrc, Ls + (wbase + j * 256) * 8);
    }
    __syncthreads();
    bh8 af[2], bf[8];
#pragma unroll
    for (int mi = 0; mi < 2; ++mi) {
      int r = wm + mi * 16 + fr;
      af[mi] = *(const bh8*)(AsL + r * 32 + ((fg ^ swz(r)) * 8));
    }
#pragma unroll
    for (int ni = 0; ni < 8; ++ni) {
      int r = wn + ni * 16 + fr;
      bf[ni] = *(const bh8*)(BsL + r * 32 + ((fg ^ swz(r)) * 8));
    }
#pragma unroll
    for (int mi = 0; mi < 2; ++mi)
#pragma unroll
      for (int ni = 0; ni < 8; ++ni)
        acc[mi][ni] = __builtin_amdgcn_mfma_f32_16x16x32_bf16(af[mi], bf[ni], acc[mi][ni], 0, 0, 0);
    __syncthreads();
  }
  // epilogue: v = acc + bias + src (residual); per-row stats
#pragma unroll
  for (int mi = 0; mi < 2; ++mi) {
#pragma unroll
    for (int r = 0; r < 4; ++r) {
      int rt = wm + mi * 16 + fg * 4 + r;          // row in tile 0..63
      long long gm = m0 + rt;
      float s = 0.f, q = 0.f;
#pragma unroll
      for (int ni = 0; ni < 8; ++ni) {
        int col = wn + ni * 16 + fr;
        float v = acc[mi][ni][r] + bias[col] + src[gm * 256 + col];
        acc[mi][ni][r] = v;
        s += v; q = fmaf(v, v, q);
      }
#pragma unroll
      for (int o = 1; o < 16; o <<= 1) { s += __shfl_xor(s, o); q += __shfl_xor(q, o); }
      if (fr == 0) { shS[rt][w & 1] = s; shQ[rt][w & 1] = q; }
    }
  }
  __syncthreads();
#pragma unroll
  for (int mi = 0; mi < 2; ++mi) {
#pragma unroll
    for (int r = 0; r < 4; ++r) {
      int rt = wm + mi * 16 + fg * 4 + r;
      long long gm = m0 + rt;
      float S = shS[rt][0] + shS[rt][1];
      float Q = shQ[rt][0] + shQ[rt][1];
      float mean = S * (1.f / 256.f);
      float var = Q * (1.f / 256.f) - mean * mean;
      float rstd = rsqrtf(var + 1e-5f);
      int prow = (int)(gm % NLEN);
#pragma unroll
      for (int ni = 0; ni < 8; ++ni) {
        int col = wn + ni * 16 + fr;
        float y = (acc[mi][ni][r] - mean) * rstd * ls[col] + lb[col];
        src[gm * 256 + col] = y;
        srcb[gm * 256 + col] = (bhalf)y;
        if (qbOut) qbOut[gm * 256 + col] = (bhalf)(y + pos[(long long)prow * 256 + col]);
      }
    }
  }
}

// =====================================================================
// Implicit-GEMM 3x3 conv, ci_block-major / tap-inner, gload_lds staging.
// =====================================================================
__global__ __launch_bounds__(256) void bgemm_conv_kernel(
    const bhalf* __restrict__ Ab, const bhalf* __restrict__ Bt,
    bhalf* __restrict__ Cout)
{
  const int gx = gridDim.x, gy = gridDim.y;
  const int nwg = gx * gy * gridDim.z;
  int flat = (blockIdx.z * gy + blockIdx.y) * gx + blockIdx.x;
  int logical = xcd_swz(flat, nwg);
  const int bz = logical / (gx * gy);
  int rem = logical - bz * gx * gy;
  const int by = rem / gx;
  const int bx = rem - by * gx;

  const bhalf* Apad = Ab + (long long)bz * 37636 * 256;
  const int m0 = by * 128, n0 = bx * 128;
  __shared__ __align__(16) bhalf As[128 * 32];
  __shared__ __align__(16) bhalf Bs[128 * 32];
  const int t = threadIdx.x;
  const int lane = t & 63;
  const int w = t >> 6;
  const int wbase = t & 192;
  const int wm = (w >> 1) * 64, wn = (w & 1) * 64;
  const int fr = lane & 15, fg = lane >> 4;
  int rowA[2], py[2], px[2], kcg[2];
#pragma unroll
  for (int j = 0; j < 2; ++j) {
    int id = t + j * 256;
    rowA[j] = id >> 2;
    kcg[j] = (((id & 3) ^ swz(rowA[j])) * 8);
    int m = m0 + rowA[j];
    py[j] = m / 192; px[j] = m % 192;
  }
  f32x4 acc[4][4] = {};
  for (int s = 0; s < 72; ++s) {
    const int cib = s / 9, tap = s % 9;
    const int ty = tap / 3, tx = tap % 3;
#pragma unroll
    for (int j = 0; j < 2; ++j) {
      GLOAD_LDS16(Apad + ((long long)(py[j] + ty) * 194 + px[j] + tx) * 256 + cib * 32 + kcg[j],
                  As + (wbase + j * 256) * 8);
      GLOAD_LDS16(Bt + (long long)(n0 + rowA[j]) * 2304 + s * 32 + kcg[j],
                  Bs + (wbase + j * 256) * 8);
    }
    __syncthreads();
    bh8 af[4], bf[4];
#pragma unroll
    for (int mi = 0; mi < 4; ++mi) {
      int r = wm + mi * 16 + fr;
      af[mi] = *(const bh8*)(As + r * 32 + ((fg ^ swz(r)) * 8));
    }
#pragma unroll
    for (int ni = 0; ni < 4; ++ni) {
      int r = wn + ni * 16 + fr;
      bf[ni] = *(const bh8*)(Bs + r * 32 + ((fg ^ swz(r)) * 8));
    }
#pragma unroll
    for (int mi = 0; mi < 4; ++mi)
#pragma unroll
      for (int ni = 0; ni < 4; ++ni)
        acc[mi][ni] = __builtin_amdgcn_mfma_f32_16x16x32_bf16(af[mi], bf[ni], acc[mi][ni], 0, 0, 0);
    __syncthreads();
  }
  bhalf* Cb = Cout + (long long)bz * 36864 * 256;
#pragma unroll
  for (int mi = 0; mi < 4; ++mi)
#pragma unroll
    for (int r = 0; r < 4; ++r) {
      int m = m0 + wm + mi * 16 + fg * 4 + r;
#pragma unroll
      for (int ni = 0; ni < 4; ++ni) {
        int n = n0 + wn + ni * 16 + fr;
        Cb[(long long)m * 256 + n] = (bhalf)acc[mi][ni][r];
      }
    }
}

// =====================================================================
// Weight transpose+convert
// =====================================================================
__global__ void twcvt_kernel(const float* __restrict__ Wsrc, bhalf* __restrict__ out,
                             int Kd, int Nd, long long zdst)
{
  __shared__ float tile[32][33];
  long long zi = (long long)blockIdx.z * Kd * Nd;
  long long zo = (long long)blockIdx.z * zdst;
  int n0 = blockIdx.x * 32, k0 = blockIdx.y * 32;
#pragma unroll
  for (int j = 0; j < 4; ++j) {
    int kk = threadIdx.y + 8 * j;
    tile[kk][threadIdx.x] = Wsrc[zi + (long long)(k0 + kk) * Nd + n0 + threadIdx.x];
  }
  __syncthreads();
#pragma unroll
  for (int j = 0; j < 4; ++j) {
    int nn = threadIdx.y + 8 * j;
    out[zo + (long long)(n0 + nn) * Kd + k0 + threadIdx.x] = (bhalf)tile[threadIdx.x][nn];
  }
}

__global__ void tfeat_kernel(const float* __restrict__ Fsrc, bhalf* __restrict__ out,
                             int Ci, int HW)
{
  __shared__ float tile[32][33];
  long long zo = (long long)blockIdx.z * Ci * HW;
  int hw0 = blockIdx.x * 32, c0 = blockIdx.y * 32;
#pragma unroll
  for (int j = 0; j < 4; ++j) {
    int cc = threadIdx.y + 8 * j;
    tile[cc][threadIdx.x] = Fsrc[zo + (long long)(c0 + cc) * HW + hw0 + threadIdx.x];
  }
  __syncthreads();
#pragma unroll
  for (int j = 0; j < 4; ++j) {
    int hh = threadIdx.y + 8 * j;
    out[zo + (long long)(hw0 + hh) * Ci + c0 + threadIdx.x] = (bhalf)tile[threadIdx.x][hh];
  }
}

__global__ void cvt_kernel(const float* __restrict__ in, bhalf* __restrict__ out, int n)
{
  int i = blockIdx.x * 256 + threadIdx.x;
  if (i < n) out[i] = (bhalf)in[i];
}

__global__ void fpnw_kernel(const float* __restrict__ Wsrc, bhalf* __restrict__ out)
{
  int o = blockIdx.x * 256 + threadIdx.x;
  if (o >= 256 * 2304) return;
  int co = o / 2304, r = o % 2304;
  int cib = r / 288, rr = r % 288, tap = rr >> 5, cil = rr & 31;
  int ci = cib * 32 + cil;
  out[o] = (bhalf)Wsrc[(co * 256 + ci) * 9 + tap];
}

__global__ void biascat_kernel(const float* __restrict__ ob, const float* __restrict__ ab,
                               float* __restrict__ out)
{
  int l = blockIdx.x, t = threadIdx.x;
  if (t < 288) out[l * 288 + t] = (t < 192) ? ob[l * 192 + t] : ab[l * 96 + t - 192];
}

__global__ void zero16_kernel(uint4* __restrict__ p, long long n16)
{
  long long i = (long long)blockIdx.x * 256 + threadIdx.x;
  if (i < n16) p[i] = make_uint4(0u, 0u, 0u, 0u);
}

// =====================================================================
// Sine positional embedding + level embed
// =====================================================================
__global__ void pos_kernel(float* __restrict__ pos, const float* __restrict__ level_embed)
{
  int i = blockIdx.x, c = threadIdx.x;
  int lvl, Wq, loc;
  if (i < 576)       { lvl = 0; Wq = 24; loc = i; }
  else if (i < 2880) { lvl = 1; Wq = 48; loc = i - 576; }
  else               { lvl = 2; Wq = 96; loc = i - 2880; }
  int h = loc / Wq, wcol = loc % Wq;
  int cc = c & 127;
  float coord = (c < 128) ? (float)(h + 1) : (float)(wcol + 1);
  float denom = (float)Wq + 1e-6f;
  float v = coord / denom * 6.28318530717958647692f;
  float tp = powf(10000.0f, (float)(cc & ~1) * (1.0f / 128.0f));
  float ang = v / tp;
  float val = (cc & 1) ? cosf(ang) : sinf(ang);
  pos[(long long)i * 256 + c] = val + level_embed[lvl * 256 + c];
}

// =====================================================================
// GN stats, two-pass, coalesced.
// =====================================================================
__global__ __launch_bounds__(256) void gn_part_kernel(const void* __restrict__ X,
    float* __restrict__ part, int HW, int isBf16, int nch)
{
  const int b = blockIdx.y, ch = blockIdx.x;
  const int rows = (HW + nch - 1) / nch;
  const int r0 = ch * rows;
  const int r1 = min(r0 + rows, HW);
  const int cg = threadIdx.x & 31;
  const int ro = threadIdx.x >> 5;
  float s = 0.f, s2 = 0.f;
  if (isBf16) {
    const bhalf* p = (const bhalf*)X + (long long)b * HW * 256 + cg * 8;
    for (int r = r0 + ro; r < r1; r += 8) {
      bh8 v = *(const bh8*)(p + (long long)r * 256);
#pragma unroll
      for (int j = 0; j < 8; ++j) { float f = (float)v[j]; s += f; s2 = fmaf(f, f, s2); }
    }
  } else {
    const float* p = (const float*)X + (long long)b * HW * 256 + cg * 8;
    for (int r = r0 + ro; r < r1; r += 8) {
      f32x4 v0 = *(const f32x4*)(p + (long long)r * 256);
      f32x4 v1 = *(const f32x4*)(p + (long long)r * 256 + 4);
#pragma unroll
      for (int j = 0; j < 4; ++j) { s += v0[j]; s2 = fmaf(v0[j], v0[j], s2); }
#pragma unroll
      for (int j = 0; j < 4; ++j) { s += v1[j]; s2 = fmaf(v1[j], v1[j], s2); }
    }
  }
  __shared__ float sh[2][8][32];
  sh[0][ro][cg] = s; sh[1][ro][cg] = s2;
  __syncthreads();
  if (threadIdx.x < 32) {
    float S = 0.f, S2 = 0.f;
#pragma unroll
    for (int k = 0; k < 8; ++k) { S += sh[0][k][threadIdx.x]; S2 += sh[1][k][threadIdx.x]; }
    long long o = ((long long)(b * 32 + threadIdx.x) * nch + ch) * 2;
    part[o] = S; part[o + 1] = S2;
  }
}

__global__ __launch_bounds__(64) void gn_fin_kernel(const float* __restrict__ part,
    float* __restrict__ stats, int nch, int HW)
{
  const int bg = blockIdx.x;
  float s = 0.f, s2 = 0.f;
  for (int i = threadIdx.x; i < nch; i += 64) {
    long long o = ((long long)bg * nch + i) * 2;
    s += part[o]; s2 += part[o + 1];
  }
#pragma unroll
  for (int o = 32; o > 0; o >>= 1) { s += __shfl_down(s, o); s2 += __shfl_down(s2, o); }
  if (threadIdx.x == 0) {
    float inv = 1.f / (float)(HW * 8);
    float mean = s * inv;
    float var = s2 * inv - mean * mean;
    stats[bg * 2] = mean;
    stats[bg * 2 + 1] = rsqrtf(var + 1e-5f);
  }
}

// =====================================================================
// GN apply -> src fp32 + srcb bf16 + qb bf16 (src+pos)
// =====================================================================
__global__ void gn_apply_rm_kernel(const float* __restrict__ T, const float* __restrict__ stats,
    const float* __restrict__ gs, const float* __restrict__ gb,
    float* __restrict__ src, bhalf* __restrict__ srcb, bhalf* __restrict__ qb,
    const float* __restrict__ pos, int HW, int startRow)
{
  long long idx = (long long)blockIdx.x * 256 + threadIdx.x;
  int c = threadIdx.x & 255;
  long long row = idx >> 8;
  int b = (int)(row / HW);
  long long hw = row - (long long)b * HW;
  int g = c >> 3;
  float v = T[idx];
  v = (v - stats[(b * 32 + g) * 2]) * stats[(b * 32 + g) * 2 + 1] * gs[c] + gb[c];
  long long pr = (startRow + hw) * 256 + c;
  long long o = (long long)b * NLEN * 256 + pr;
  src[o] = v;
  srcb[o] = (bhalf)v;
  qb[o] = (bhalf)(v + pos[pr]);
}

// =====================================================================
// MSDeformAttn sampling: 8 ch/lane (16B gathers), 32 lanes/query,
// fused softmax over 12 logits.
// =====================================================================
__global__ __launch_bounds__(256) void deform_kernel(const bhalf* __restrict__ value,
    const float* __restrict__ offaw, bhalf* __restrict__ out)
{
  const int t = threadIdx.x;
  const int q = t >> 5;
  const int sub = t & 31;
  const int bi = blockIdx.x * 8 + q;
  const int i = bi % NLEN;
  const int bbase = bi - i;
  const int c0 = sub * 8;
  const int head = sub >> 2;
  int loc, Wq;
  if (i < 576)       { Wq = 24; loc = i; }
  else if (i < 2880) { Wq = 48; loc = i - 576; }
  else               { Wq = 96; loc = i - 2880; }
  const float rx = ((loc % Wq) + 0.5f) / (float)Wq;
  const float ry = ((loc / Wq) + 0.5f) / (float)Wq;
  const float* offp = offaw + (long long)bi * 288 + head * 24;
  const float* awp  = offaw + (long long)bi * 288 + 192 + head * 12;
  float aw[12]; float mx = -1e30f;
#pragma unroll
  for (int j = 0; j < 12; ++j) { aw[j] = awp[j]; mx = fmaxf(mx, aw[j]); }
  float ssum = 0.f;
#pragma unroll
  for (int j = 0; j < 12; ++j) { aw[j] = __expf(aw[j] - mx); ssum += aw[j]; }
  const float sinv = 1.f / ssum;
  float acc[8] = {};
  const int starts[3] = {0, 576, 2880};
  const int Ls[3] = {24, 48, 96};
#pragma unroll
  for (int l = 0; l < 3; ++l) {
    const int Wl = Ls[l];
    const float fW = (float)Wl;
    const bhalf* vb = value + (long long)(bbase + starts[l]) * 256 + c0;
#pragma unroll
    for (int p = 0; p < 4; ++p) {
      const float ox = offp[l * 8 + p * 2], oy = offp[l * 8 + p * 2 + 1];
      const float a = aw[l * 4 + p] * sinv;
      const float x = (rx + ox / fW) * fW - 0.5f;
      const float y = (ry + oy / fW) * fW - 0.5f;
      const float x0f = floorf(x), y0f = floorf(y);
      const float wx = x - x0f, wy = y - y0f;
      const int x0 = (int)x0f, y0 = (int)y0f;
      const int x1 = x0 + 1, y1 = y0 + 1;
      const bool xv0 = (x0 >= 0) & (x0 < Wl);
      const bool xv1 = (x1 >= 0) & (x1 < Wl);
      const bool yv0 = (y0 >= 0) & (y0 < Wl);
      const bool yv1 = (y1 >= 0) & (y1 < Wl);
      const int cx0 = min(max(x0, 0), Wl - 1), cx1 = min(max(x1, 0), Wl - 1);
      const int cy0 = min(max(y0, 0), Wl - 1), cy1 = min(max(y1, 0), Wl - 1);
      const float w00 = (xv0 && yv0) ? (1.f - wx) * (1.f - wy) * a : 0.f;
      const float w01 = (xv1 && yv0) ? wx * (1.f - wy) * a : 0.f;
      const float w10 = (xv0 && yv1) ? (1.f - wx) * wy * a : 0.f;
      const float w11 = (xv1 && yv1) ? wx * wy * a : 0.f;
      const bh8 g00 = *(const bh8*)(vb + (cy0 * Wl + cx0) * 256);
      const bh8 g01 = *(const bh8*)(vb + (cy0 * Wl + cx1) * 256);
      const bh8 g10 = *(const bh8*)(vb + (cy1 * Wl + cx0) * 256);
      const bh8 g11 = *(const bh8*)(vb + (cy1 * Wl + cx1) * 256);
#pragma unroll
      for (int e = 0; e < 8; ++e)
        acc[e] = fmaf(w00, (float)g00[e], fmaf(w01, (float)g01[e],
                 fmaf(w10, (float)g10[e], fmaf(w11, (float)g11[e], acc[e]))));
    }
  }
  bh8 o;
#pragma unroll
  for (int e = 0; e < 8; ++e) o[e] = (bhalf)acc[e];
  *(bh8*)(out + (long long)bi * 256 + c0) = o;
}

// =====================================================================
// src[b][startRow+hw][c] -> out[b][c][hw]
// =====================================================================
__global__ void transpose_out_kernel(const float* __restrict__ src, float* __restrict__ out,
    int HW, int startRow)
{
  __shared__ float tile[32][33];
  int b = blockIdx.z;
  int w0 = blockIdx.x * 32, c0 = blockIdx.y * 32;
#pragma unroll
  for (int j = 0; j < 4; ++j) {
    int wl = threadIdx.y + 8 * j;
    tile[wl][threadIdx.x] = src[((long long)b * NLEN + startRow + w0 + wl) * 256 + c0 + threadIdx.x];
  }
  __syncthreads();
#pragma unroll
  for (int j = 0; j < 4; ++j) {
    int cl = threadIdx.y + 8 * j;
    out[((long long)b * 256 + c0 + cl) * HW + w0 + threadIdx.x] = tile[threadIdx.x][cl];
  }
}

// =====================================================================
// latb = GN(lat) + upsample2x(src lvl2), zero-padded layout
// =====================================================================
__global__ void lat_finish_rm_kernel(const bhalf* __restrict__ lat, const float* __restrict__ stats,
    const float* __restrict__ gs, const float* __restrict__ gb,
    const float* __restrict__ src, bhalf* __restrict__ latb)
{
  long long idx = (long long)blockIdx.x * 256 + threadIdx.x;
  int c = threadIdx.x & 255;
  long long row = idx >> 8;
  int b = (int)(row / 36864);
  int p = (int)(row - (long long)b * 36864);
  int y = p / 192, x = p % 192;
  int g = c >> 3;
  float v = (float)lat[idx];
  v = (v - stats[(b * 32 + g) * 2]) * stats[(b * 32 + g) * 2 + 1] * gs[c] + gb[c];
  float ys = fmaxf(y * 0.5f - 0.25f, 0.f);
  float xs = fmaxf(x * 0.5f - 0.25f, 0.f);
  int y0 = (int)ys; float wy = ys - (float)y0; int y1 = min(y0 + 1, 95);
  int x0 = (int)xs; float wx = xs - (float)x0; int x1 = min(x0 + 1, 95);
  const float* sp = src + ((long long)b * NLEN + 2880) * 256 + c;
  float r0 = sp[(long long)(y0 * 96 + x0) * 256] * (1.f - wx) + sp[(long long)(y0 * 96 + x1) * 256] * wx;
  float r1 = sp[(long long)(y1 * 96 + x0) * 256] * (1.f - wx) + sp[(long long)(y1 * 96 + x1) * 256] * wx;
  latb[((long long)b * 37636 + (long long)(y + 1) * 194 + (x + 1)) * 256 + c]
      = (bhalf)(v + r0 * (1.f - wy) + r1 * wy);
}

// =====================================================================
// Final GN+ReLU+transpose: convC bf16 [b][hw][c] -> Y fp32 [b][c][hw]
// =====================================================================
__global__ void gn_relu_tr_kernel(const bhalf* __restrict__ convC, const float* __restrict__ stats,
    const float* __restrict__ gs, const float* __restrict__ gb, float* __restrict__ Y)
{
  __shared__ float tile[32][33];
  int b = blockIdx.z;
  int hw0 = blockIdx.x * 32, c0 = blockIdx.y * 32;
#pragma unroll
  for (int j = 0; j < 4; ++j) {
    int hwl = threadIdx.y + 8 * j;
    int c = c0 + threadIdx.x;
    int g = c >> 3;
    float v = (float)convC[((long long)b * 36864 + hw0 + hwl) * 256 + c];
    v = (v - stats[(b * 32 + g) * 2]) * stats[(b * 32 + g) * 2 + 1] * gs[c] + gb[c];
    tile[hwl][threadIdx.x] = fmaxf(v, 0.f);
  }
  __syncthreads();
#pragma unroll
  for (int j = 0; j < 4; ++j) {
    int cl = threadIdx.y + 8 * j;
    Y[((long long)b * 256 + c0 + cl) * 36864 + hw0 + threadIdx.x] = tile[threadIdx.x][cl];
  }
}

// =====================================================================
extern "C" void kernel_launch(void* const* d_in, const int* in_sizes, int n_in,
                              void* d_out, int out_size, void* d_ws, size_t ws_size,
                              hipStream_t stream)
{
  const float* res2 = (const float*)d_in[0];
  const float* res3 = (const float*)d_in[1];
  const float* res4 = (const float*)d_in[2];
  const float* res5 = (const float*)d_in[3];
  const float* pw[3]  = {(const float*)d_in[4],  (const float*)d_in[8],  (const float*)d_in[12]};
  const float* pb[3]  = {(const float*)d_in[5],  (const float*)d_in[9],  (const float*)d_in[13]};
  const float* gss[3] = {(const float*)d_in[6],  (const float*)d_in[10], (const float*)d_in[14]};
  const float* gbb[3] = {(const float*)d_in[7],  (const float*)d_in[11], (const float*)d_in[15]};
  const float* level_embed = (const float*)d_in[16];
  const float* off_w = (const float*)d_in[17];
  const float* off_b = (const float*)d_in[18];
  const float* aw_w  = (const float*)d_in[19];
  const float* aw_b  = (const float*)d_in[20];
  const float* val_w = (const float*)d_in[21];
  const float* val_b = (const float*)d_in[22];
  const float* out_w = (const float*)d_in[23];
  const float* out_b = (const float*)d_in[24];
  const float* ln1_s = (const float*)d_in[25];
  const float* ln1_b = (const float*)d_in[26];
  const float* ffn1_w = (const float*)d_in[27];
  const float* ffn1_b = (const float*)d_in[28];
  const float* ffn2_w = (const float*)d_in[29];
  const float* ffn2_b = (const float*)d_in[30];
  const float* ln2_s = (const float*)d_in[31];
  const float* ln2_b = (const float*)d_in[32];
  const float* lat_w = (const float*)d_in[33];
  const float* lat_gs = (const float*)d_in[34];
  const float* lat_gb = (const float*)d_in[35];
  const float* fpn_w = (const float*)d_in[36];
  const float* fpn_gs = (const float*)d_in[37];
  const float* fpn_gb = (const float*)d_in[38];

  char* W = (char*)d_ws;
  float* src   = (float*)(W + 0);
  float* pos   = (float*)(W + 24772608LL);
  float* tmp   = (float*)(W + 37158912LL);
  bhalf* srcb  = (bhalf*)(W + 61931520LL);
  bhalf* wreg  = (bhalf*)(W + 74317824LL);
  float* stats = (float*)(W + 86212608LL);
  float* part  = (float*)(W + 86213120LL);
  float* offaw_b = (float*)(W + 86278656LL);
  char*  U     = W + 86286848LL;

  bhalf* valT   = wreg + 0;
  bhalf* offawT = wreg + 393216;
  bhalf* outT   = wreg + 835584;
  bhalf* f1T    = wreg + 1228800;
  bhalf* f2T    = wreg + 2801664;
  bhalf* pwb5   = wreg + 4374528;
  bhalf* pwb4   = wreg + 4898816;
  bhalf* pwb3   = wreg + 5160960;
  bhalf* latwb  = wreg + 5292032;
  bhalf* fpnT   = wreg + 5357568;

  bhalf* qb      = (bhalf*)(U + 0);
  bhalf* valueb  = (bhalf*)(U + 12386304LL);
  bhalf* sampb   = (bhalf*)(U + 24772608LL);
  float* offbuf  = (float*)(U + 37158912LL);
  bhalf* hbuf    = (bhalf*)(U + 65028096LL);
  bhalf* featT   = (bhalf*)(U + 24772608LL);   // projection-phase only
  bhalf* res2T   = (bhalf*)(U + 0);
  bhalf* latbf   = (bhalf*)(U + 37748736LL);
  bhalf* latb    = (bhalf*)(U + 75497472LL);

  float* Yout = (float*)d_out;
  float* out0 = Yout + 18874368LL;
  float* out1 = Yout + 19169280LL;
  float* out2 = Yout + 20348928LL;

  const int M = BB * NLEN;  // 24192

  // ---- weight prep ----
  twcvt_kernel<<<dim3(8, 8, 6), dim3(32, 8), 0, stream>>>(val_w, valT, 256, 256, 65536LL);
  twcvt_kernel<<<dim3(6, 8, 6), dim3(32, 8), 0, stream>>>(off_w, offawT, 256, 192, 73728LL);
  twcvt_kernel<<<dim3(3, 8, 6), dim3(32, 8), 0, stream>>>(aw_w, offawT + 192 * 256, 256, 96, 73728LL);
  twcvt_kernel<<<dim3(8, 8, 6), dim3(32, 8), 0, stream>>>(out_w, outT, 256, 256, 65536LL);
  twcvt_kernel<<<dim3(32, 8, 6), dim3(32, 8), 0, stream>>>(ffn1_w, f1T, 256, 1024, 262144LL);
  twcvt_kernel<<<dim3(8, 32, 6), dim3(32, 8), 0, stream>>>(ffn2_w, f2T, 1024, 256, 262144LL);
  biascat_kernel<<<dim3(6), dim3(288), 0, stream>>>(off_b, aw_b, offaw_b);
  cvt_kernel<<<dim3(2048), dim3(256), 0, stream>>>(pw[0], pwb5, 524288);
  cvt_kernel<<<dim3(1024), dim3(256), 0, stream>>>(pw[1], pwb4, 262144);
  cvt_kernel<<<dim3(512),  dim3(256), 0, stream>>>(pw[2], pwb3, 131072);
  cvt_kernel<<<dim3(256),  dim3(256), 0, stream>>>(lat_w, latwb, 65536);
  fpnw_kernel<<<dim3(2304), dim3(256), 0, stream>>>(fpn_w, fpnT);

  // ---- positional embedding ----
  pos_kernel<<<dim3(NLEN), dim3(256), 0, stream>>>(pos, level_embed);

  // ---- input projections + GN -> src/srcb/qb ----
  const float* feats[3] = {res5, res4, res3};
  const bhalf* pwbs[3] = {pwb5, pwb4, pwb3};
  const int cins[3] = {2048, 1024, 512};
  const int HWs[3] = {576, 2304, 9216};
  const int startsHost[3] = {0, 576, 2880};
  const int nchs[3] = {16, 64, 128};
  for (int lvl = 0; lvl < 3; ++lvl) {
    int HW = HWs[lvl], cin = cins[lvl], nch = nchs[lvl];
    tfeat_kernel<<<dim3(HW / 32, cin / 32, BB), dim3(32, 8), 0, stream>>>(feats[lvl], featT, cin, HW);
    bgemm_kernel<<<dim3(2, (HW + 127) / 128, BB), dim3(256), 0, stream>>>(
        featT, pwbs[lvl], pb[lvl], tmp, HW, 256, cin,
        (long long)HW * cin, 0LL, (long long)HW * 256, 0, 0);
    gn_part_kernel<<<dim3(nch, BB), dim3(256), 0, stream>>>(tmp, part, HW, 0, nch);
    gn_fin_kernel<<<dim3(64), dim3(64), 0, stream>>>(part, stats, nch, HW);
    gn_apply_rm_kernel<<<dim3(BB * HW), dim3(256), 0, stream>>>(
        tmp, stats, gss[lvl], gbb[lvl], src, srcb, qb, pos, HW, startsHost[lvl]);
  }

  // ---- 6 encoder layers ----
  for (int l = 0; l < 6; ++l) {
    bgemm_kernel<<<dim3(2, M / 128, 1), dim3(256), 0, stream>>>(
        srcb, valT + (long long)l * 65536, val_b + l * 256, valueb,
        M, 256, 256, 0LL, 0LL, 0LL, 1, 0);
    bgemm_kernel<<<dim3(3, M / 128, 1), dim3(256), 0, stream>>>(
        qb, offawT + (long long)l * 73728, offaw_b + l * 288, offbuf,
        M, 288, 256, 0LL, 0LL, 0LL, 0, 0);
    deform_kernel<<<dim3(M / 8), dim3(256), 0, stream>>>(valueb, offbuf, sampb);
    // out-proj + residual + LN1 (fused)
    bgemm_ln_kernel<<<dim3(M / 64), dim3(256), 0, stream>>>(
        sampb, outT + (long long)l * 65536, out_b + l * 256,
        src, srcb, nullptr, pos, ln1_s + l * 256, ln1_b + l * 256, M, 256);
    bgemm_kernel<<<dim3(8, M / 128, 1), dim3(256), 0, stream>>>(
        srcb, f1T + (long long)l * 262144, ffn1_b + l * 1024, hbuf,
        M, 1024, 256, 0LL, 0LL, 0LL, 1, 1);
    // ffn2 + residual + LN2 (fused, also emits qb = y + pos)
    bgemm_ln_kernel<<<dim3(M / 64), dim3(256), 0, stream>>>(
        hbuf, f2T + (long long)l * 262144, ffn2_b + l * 256,
        src, srcb, qb, pos, ln2_s + l * 256, ln2_b + l * 256, M, 1024);
  }

  // ---- output transposes ----
  float* outsPtr[3] = {out0, out1, out2};
  for (int lvl = 0; lvl < 3; ++lvl) {
    transpose_out_kernel<<<dim3(HWs[lvl] / 32, 8, BB), dim3(32, 8), 0, stream>>>(
        src, outsPtr[lvl], HWs[lvl], startsHost[lvl]);
  }

  // ---- FPN ----
  tfeat_kernel<<<dim3(1152, 8, BB), dim3(32, 8), 0, stream>>>(res2, res2T, 256, 36864);
  bgemm_kernel<<<dim3(2, 288, BB), dim3(256), 0, stream>>>(
      res2T, latwb, nullptr, latbf, 36864, 256, 256,
      36864LL * 256, 0LL, 36864LL * 256, 1, 0);
  gn_part_kernel<<<dim3(128, BB), dim3(256), 0, stream>>>(latbf, part, 36864, 1, 128);
  gn_fin_kernel<<<dim3(64), dim3(64), 0, stream>>>(part, stats, 128, 36864);
  zero16_kernel<<<dim3(9410), dim3(256), 0, stream>>>((uint4*)latb, 2408704LL);
  lat_finish_rm_kernel<<<dim3(73728), dim3(256), 0, stream>>>(latbf, stats, lat_gs, lat_gb, src, latb);
  bgemm_conv_kernel<<<dim3(2, 288, BB), dim3(256), 0, stream>>>(latb, fpnT, latbf);
  gn_part_kernel<<<dim3(128, BB), dim3(256), 0, stream>>>(latbf, part, 36864, 1, 128);
  gn_fin_kernel<<<dim3(64), dim3(64), 0, stream>>>(part, stats, 128, 36864);
  gn_relu_tr_kernel<<<dim3(1152, 8, BB), dim3(32, 8), 0, stream>>>(latbf, stats, fpn_gs, fpn_gb, Yout);
}